// Round 27
// baseline (408.375 us; speedup 1.0000x reference)
//
#include <hip/hip_runtime.h>
#include <math.h>

// G2GDecoder forward: TreeGRU over line graph + topology/label heads.
// R2: CSR gathers. R5: bf16 MFMA. R11: MFMA label-CE. R15-R21: persistent-W
// E-GEMMs, T14 split staging, XOR-swizzled A-rings. R24: tail fusion.
// R25/R26: active-set sparsification (S1/S2, ~5-10% of E).
// R27: attn2 occupancy. 64-thread blocks = 1 wave/block hit the per-CU
// workgroup-slot limit (~16 waves/CU, Occupancy 45%, VALUBusy 10%,
// BW 2.35 TB/s latency-bound). Pack 4 graphs/block (256 thr, wave=graph,
// LDS [4][..]); grid 2B -> 2B/4. B%4==0 so blocks are uniformly T or G.

using bf16x8 = __attribute__((ext_vector_type(8))) short;
using f32x4  = __attribute__((ext_vector_type(4))) float;

#define MFMA __builtin_amdgcn_mfma_f32_16x16x32_bf16

__device__ inline float wave_sum64(float v){
  #pragma unroll
  for (int m = 32; m; m >>= 1) v += __shfl_xor(v, m, 64);
  return v;
}
__device__ inline float wave_max64(float v){
  #pragma unroll
  for (int m = 32; m; m >>= 1) v = fmaxf(v, __shfl_xor(v, m, 64));
  return v;
}
__device__ inline float sigmoidf_(float x){ return 1.f / (1.f + __expf(-x)); }
__device__ inline float tanh_fast(float x){
  x = fminf(fmaxf(x, -15.f), 15.f);
  float e = __expf(2.f * x);
  return (e - 1.f) / (e + 1.f);
}
__device__ inline float logsigf_(float x){
  return (x >= 0.f) ? -log1pf(__expf(-x)) : (x - log1pf(__expf(x)));
}
__device__ inline unsigned short f2bf(float f){
  union { float f; unsigned u; } v; v.f = f;
  const unsigned r = v.u + 0x7FFF + ((v.u >> 16) & 1);   // RNE
  return (unsigned short)(r >> 16);
}
__device__ inline float bf2f(unsigned short u){
  union { unsigned u; float f; } v; v.u = ((unsigned)u) << 16; return v.f;
}
__device__ inline unsigned pk2(unsigned short a, unsigned short b){
  return (unsigned)a | ((unsigned)b << 16);
}
__device__ inline uint4 cvt8v(float4 x0, float4 x1){
  uint4 o;
  o.x = pk2(f2bf(x0.x), f2bf(x0.y)); o.y = pk2(f2bf(x0.z), f2bf(x0.w));
  o.z = pk2(f2bf(x1.x), f2bf(x1.y)); o.w = pk2(f2bf(x1.z), f2bf(x1.w));
  return o;
}
__device__ inline uint4 cvt8(const float* __restrict__ p){
  return cvt8v(*(const float4*)(p), *(const float4*)(p + 4));
}
__device__ inline void acc8(float* a, uint4 v){
  a[0] += bf2f(v.x & 0xffff); a[1] += bf2f(v.x >> 16);
  a[2] += bf2f(v.y & 0xffff); a[3] += bf2f(v.y >> 16);
  a[4] += bf2f(v.z & 0xffff); a[5] += bf2f(v.z >> 16);
  a[6] += bf2f(v.w & 0xffff); a[7] += bf2f(v.w >> 16);
}
__device__ inline uint4 pack8(const float* a){
  uint4 o;
  o.x = pk2(f2bf(a[0]), f2bf(a[1])); o.y = pk2(f2bf(a[2]), f2bf(a[3]));
  o.z = pk2(f2bf(a[4]), f2bf(a[5])); o.w = pk2(f2bf(a[6]), f2bf(a[7]));
  return o;
}

enum { EPI_NONE = 0, EPI_SIGMOID = 1, EPI_RELU = 2 };

// ------- weight prep: f32 [k][col] -> bf16 fragment granule layout ---------
// blockIdx.y in [0,10): gate/head panels -> wt. blockIdx.y == 10: u_l -> wt_ul.
__global__ __launch_bounds__(256) void wprep_kernel(
    const float* wr, const float* ur, const float* wz, const float* uz,
    const float* w,  const float* u,  const float* w_d1, const float* w_d2,
    const float* a_dT, const float* a_dG, const float* a_lT, const float* a_lG,
    const float* w_d3, const float* w_d4, const float* w_l1, const float* w_l2,
    unsigned short* __restrict__ wt,
    const float* __restrict__ u_l, unsigned short* __restrict__ wt_ul, int V)
{
  const int m = blockIdx.y;
  const int tid = blockIdx.x * 256 + threadIdx.x;
  if (m == 10){
    if (tid >= 16 * V) return;
    const int col = tid % V, k8 = tid / V;
    unsigned short v[8];
    #pragma unroll
    for (int i = 0; i < 8; ++i)
      v[i] = f2bf(u_l[(size_t)(k8 * 8 + i) * V + col]);
    uint4 pk;
    pk.x = pk2(v[0], v[1]); pk.y = pk2(v[2], v[3]);
    pk.z = pk2(v[4], v[5]); pk.w = pk2(v[6], v[7]);
    *(uint4*)&wt_ul[((size_t)k8 * V + col) * 8] = pk;
    return;
  }
  const float* s1; const float* s2; int K1, Ktot; size_t off;
  switch (m){
    case 0: s1 = wr;   s2 = ur;   K1 = 128; Ktot = 256; off = 0;      break;
    case 1: s1 = wz;   s2 = uz;   K1 = 128; Ktot = 256; off = 32768;  break;
    case 2: s1 = w;    s2 = u;    K1 = 128; Ktot = 256; off = 65536;  break;
    case 3: s1 = w_d1; s2 = w_d2; K1 = 128; Ktot = 256; off = 98304;  break;
    case 4: s1 = a_dT; s2 = nullptr; K1 = 128; Ktot = 128; off = 131072; break;
    case 5: s1 = a_dG; s2 = nullptr; K1 = 128; Ktot = 128; off = 147456; break;
    case 6: s1 = a_lT; s2 = nullptr; K1 = 128; Ktot = 128; off = 163840; break;
    case 7: s1 = a_lG; s2 = nullptr; K1 = 128; Ktot = 128; off = 180224; break;
    case 8: s1 = w_d3; s2 = w_d4; K1 = 128; Ktot = 384; off = 196608; break;
    default:s1 = w_l1; s2 = w_l2; K1 = 128; Ktot = 384; off = 245760; break;
  }
  if (tid >= 16 * Ktot) return;
  const int col = tid & 127, k8 = tid >> 7;
  unsigned short v[8];
  #pragma unroll
  for (int i = 0; i < 8; ++i){
    const int k = k8 * 8 + i;
    const float* s = (k < K1) ? (s1 + (size_t)k * 128 + col)
                              : (s2 + (size_t)(k - K1) * 128 + col);
    v[i] = f2bf(*s);
  }
  uint4 pk;
  pk.x = pk2(v[0], v[1]); pk.y = pk2(v[2], v[3]);
  pk.z = pk2(v[4], v[5]); pk.w = pk2(v[6], v[7]);
  *(uint4*)&wt[off + ((size_t)k8 * 128 + col) * 8] = pk;
}

// ---------------- active-set construction ----------------
__global__ __launch_bounds__(256) void mark1_kernel(
    const int* __restrict__ eids, int B,
    const int* __restrict__ offsets, const int* __restrict__ csr_src,
    int* __restrict__ flag1)
{
  const int b = blockIdx.x * 256 + threadIdx.x;
  if (b >= B) return;
  const int e = eids[b];
  flag1[e] = 1;
  const int beg = offsets[e], end = offsets[e + 1];
  for (int j = beg; j < end; ++j) flag1[csr_src[j]] = 1;
}

__global__ __launch_bounds__(256) void compact_kernel(
    const int* __restrict__ flag, int E,
    int* __restrict__ list, int* __restrict__ rank, int* __restrict__ cnt)
{
  const int v = blockIdx.x * 256 + threadIdx.x;
  if (v >= E || !flag[v]) return;
  const int pos = atomicAdd(cnt, 1);
  list[pos] = v;
  rank[v] = pos;
}

__global__ __launch_bounds__(256) void mark2_kernel(
    const int* __restrict__ cnt1p, const int* __restrict__ S1list,
    const int* __restrict__ offsets, const int* __restrict__ csr_src,
    int* __restrict__ flag2)
{
  const int n = *cnt1p;
  for (int i = blockIdx.x * 256 + threadIdx.x; i < n; i += gridDim.x * 256){
    const int v = S1list[i];
    const int beg = offsets[v], end = offsets[v + 1];
    for (int j = beg; j < end; ++j) flag2[csr_src[j]] = 1;
  }
}

// pad counts up to tile multiples (S1: 128, S2: 64), filling with list[0]
__global__ void pad_kernel(int* cnt1, int* S1list, int* cnt2, int* S2list)
{
  if (threadIdx.x == 0 && blockIdx.x == 0){
    int c1 = *cnt1;
    if (c1 > 0){
      const int p1 = (c1 + 127) & ~127;
      for (int i = c1; i < p1; ++i) S1list[i] = S1list[0];
      *cnt1 = p1;
    }
    int c2 = *cnt2;
    if (c2 > 0){
      const int p2 = (c2 + 63) & ~63;
      for (int i = c2; i < p2; ++i) S2list[i] = S2list[0];
      *cnt2 = p2;
    }
  }
}

// ---------------- persistent-W R-GEMM over S2 (compacted rows) -------------
// 64-row tiles, K-chunk 64; T14 split staging, ring-2 XOR-swizzled.
__global__ __launch_bounds__(512, 2) void gemm_r_kernel(
    const int* __restrict__ cnt2p, const int* __restrict__ S2list,
    const float* __restrict__ A1f,     // f_dst
    const float* __restrict__ A2f,     // msg
    const unsigned short* __restrict__ Wt,
    const float* __restrict__ bias,
    unsigned short* __restrict__ out,  // R16c (compacted)
    unsigned short* __restrict__ out2) // msg16c (compacted)
{
  __shared__ unsigned short Wl[32768];   // 64KB persistent W panel
  __shared__ unsigned short Ar[2][4096]; // 8KB slots: 64 rows x 8 granules (swz)
  const int t = threadIdx.x;
  const int lane = t & 63, wid = t >> 6;
  const int l15 = lane & 15, l4 = lane >> 4;
  const int wr = wid >> 1, wc = wid & 1;   // 4 row-grp x 2 col-grp

  const int tiles = (*cnt2p) >> 6;
  const int nT = (tiles - (int)blockIdx.x + (int)gridDim.x - 1) / (int)gridDim.x;
  if (nT <= 0) return;

  #pragma unroll
  for (int i = 0; i < 8; ++i)
    ((uint4*)Wl)[i * 512 + t] = ((const uint4*)Wt)[i * 512 + t];

  const int totalG = nT * 4;   // 4 K-chunks per tile

  float4 ra, rb;   // in-flight staged data (raw f32, all 512 threads)

  auto loadA = [&](int gs){
    const int tile = (int)blockIdx.x + (gs >> 2) * (int)gridDim.x;
    const int cs = gs & 3;
    const size_t grow = (size_t)S2list[tile * 64 + (t >> 3)];
    const int q8 = (t & 7) * 8;
    const float* src = (cs < 2) ? (A1f + grow * 128 + cs * 64 + q8)
                                : (A2f + grow * 128 + (cs - 2) * 64 + q8);
    ra = *(const float4*)(src);
    rb = *(const float4*)(src + 4);
  };
  auto writeA = [&](int slot, int gs){
    const uint4 o = cvt8v(ra, rb);
    const int rrow = t >> 3, qq = t & 7;
    *(uint4*)&Ar[slot][((rrow << 3) | (qq ^ (rrow & 7))) * 8] = o;
    const int cs = gs & 3;
    if (cs >= 2){
      const int tile = (int)blockIdx.x + (gs >> 2) * (int)gridDim.x;
      const size_t crow = (size_t)tile * 64 + rrow;
      *(uint4*)&out2[crow * 128 + (cs - 2) * 64 + qq * 8] = o;
    }
  };

  loadA(0); writeA(0, 0);
  if (totalG > 1) loadA(1);

  for (int m = 0; m < nT; ++m){
    const int tile = (int)blockIdx.x + m * (int)gridDim.x;
    f32x4 acc[4];
    #pragma unroll
    for (int cf = 0; cf < 4; ++cf) acc[cf] = (f32x4){0.f,0.f,0.f,0.f};
    #pragma unroll
    for (int cs = 0; cs < 4; ++cs){
      const int g = m * 4 + cs;
      __syncthreads();
      if (g + 1 < totalG) writeA((g + 1) & 1, g + 1);  // regs from prev load
      if (g + 2 < totalG) loadA(g + 2);                // issue ahead
      const unsigned short* S = Ar[g & 1];
      const int arow = wr * 16 + l15;
      #pragma unroll
      for (int kk = 0; kk < 2; ++kk){
        const int qq = (kk * 4 + l4) ^ (arow & 7);
        const bf16x8 a = *(const bf16x8*)&S[((arow << 3) | qq) * 8];
        #pragma unroll
        for (int cf = 0; cf < 4; ++cf){
          const int wg = (((cs * 2 + kk) * 4 + l4) * 128 + wc * 64 + cf * 16 + l15) * 8;
          acc[cf] = MFMA(a, *(const bf16x8*)&Wl[wg], acc[cf], 0, 0, 0);
        }
      }
    }
    int growv[4];
    #pragma unroll
    for (int i = 0; i < 4; ++i)
      growv[i] = S2list[tile * 64 + wr * 16 + l4 * 4 + i];
    #pragma unroll
    for (int cf = 0; cf < 4; ++cf){
      const int col = wc * 64 + cf * 16 + l15;
      const float bv = bias[col];
      #pragma unroll
      for (int i = 0; i < 4; ++i){
        const size_t oc = ((size_t)tile * 64 + wr * 16 + l4 * 4 + i) * 128 + col;
        out[oc] = f2bf(sigmoidf_(acc[cf][i] + bv) * A2f[(size_t)growv[i] * 128 + col]);
      }
    }
  }
}

// ---------------- persistent-W merged Z+H GEMM over S1 (compacted) ---------
// 128-row tiles. LDS: 128KB W + 2x16KB ring = 160KB.
__global__ __launch_bounds__(512, 2) void gemm_zh_kernel(
    const int* __restrict__ cnt1p, const int* __restrict__ S1list,
    const float* __restrict__ fsrc,
    const unsigned short* __restrict__ s16,    // compacted
    const unsigned short* __restrict__ srh16,  // compacted
    const unsigned short* __restrict__ Wz,
    const unsigned short* __restrict__ Wh,
    const float* __restrict__ bz, const float* __restrict__ bh,
    unsigned short* __restrict__ out)          // mn16c compacted
{
  __shared__ unsigned short Wl[65536];   // Wz | Wh, 128KB persistent
  __shared__ unsigned short Ar[2][8192]; // 16KB slots: [0:4096)=z, [4096:8192)=h
  const int t = threadIdx.x;
  const int lane = t & 63, wid = t >> 6;
  const int l15 = lane & 15, l4 = lane >> 4;
  const int wr = wid >> 1, wc = wid & 1;

  const int tiles = (*cnt1p) >> 7;
  const int nT = (tiles - (int)blockIdx.x + (int)gridDim.x - 1) / (int)gridDim.x;
  if (nT <= 0) return;

  #pragma unroll
  for (int i = 0; i < 8; ++i){
    ((uint4*)Wl)[i * 512 + t]        = ((const uint4*)Wz)[i * 512 + t];
    ((uint4*)Wl)[4096 + i * 512 + t] = ((const uint4*)Wh)[i * 512 + t];
  }

  const int totalG = nT * 8;

  float4 ra, rb;   // phase1: raw f32; phase2: ra=s16 bits, rb=srh16 bits

  auto loadA = [&](int gs){
    const int tile = (int)blockIdx.x + (gs >> 3) * (int)gridDim.x;
    const int ks = gs & 7;
    const int crow = tile * 128 + (t >> 2);
    const int q8 = (t & 3) * 8;
    if (ks < 4){
      const size_t grow = (size_t)S1list[crow];
      const float* src = fsrc + grow * 128 + ks * 32 + q8;
      ra = *(const float4*)(src);
      rb = *(const float4*)(src + 4);
    } else {
      const uint4 v1 = *(const uint4*)&s16[(size_t)crow * 128 + (ks - 4) * 32 + q8];
      const uint4 v2 = *(const uint4*)&srh16[(size_t)crow * 128 + (ks - 4) * 32 + q8];
      ra = *(const float4*)&v1;
      rb = *(const float4*)&v2;
    }
  };
  auto writeA = [&](int slot, int gs){
    const int ks = gs & 7;
    const int rrow = t >> 2, qq = t & 3;
    const int gsw = ((rrow << 2) | (qq ^ ((rrow >> 1) & 3))) * 8;
    if (ks < 4){
      *(uint4*)&Ar[slot][gsw] = cvt8v(ra, rb);
    } else {
      *(uint4*)&Ar[slot][gsw]        = *(const uint4*)&ra;
      *(uint4*)&Ar[slot][4096 + gsw] = *(const uint4*)&rb;
    }
  };

  loadA(0); writeA(0, 0);
  if (totalG > 1) loadA(1);

  for (int m = 0; m < nT; ++m){
    const int tile = (int)blockIdx.x + m * (int)gridDim.x;
    f32x4 az0[4], az1[4], ah0[4], ah1[4];
    #pragma unroll
    for (int cf = 0; cf < 4; ++cf){
      az0[cf] = (f32x4){0.f,0.f,0.f,0.f}; az1[cf] = (f32x4){0.f,0.f,0.f,0.f};
      ah0[cf] = (f32x4){0.f,0.f,0.f,0.f}; ah1[cf] = (f32x4){0.f,0.f,0.f,0.f};
    }
    #pragma unroll
    for (int ks = 0; ks < 8; ++ks){
      const int g = m * 8 + ks;
      __syncthreads();
      if (g + 1 < totalG) writeA((g + 1) & 1, g + 1);
      if (g + 2 < totalG) loadA(g + 2);
      const unsigned short* S = Ar[g & 1];
      const int r0 = wr * 32 + l15, r1 = wr * 32 + 16 + l15;
      const int ag0 = ((r0 << 2) | (l4 ^ ((r0 >> 1) & 3))) * 8;
      const int ag1 = ((r1 << 2) | (l4 ^ ((r1 >> 1) & 3))) * 8;
      const bf16x8 az_a0 = *(const bf16x8*)&S[ag0];
      const bf16x8 az_a1 = *(const bf16x8*)&S[ag1];
      const bf16x8 ah_a0 = (ks < 4) ? az_a0 : *(const bf16x8*)&S[4096 + ag0];
      const bf16x8 ah_a1 = (ks < 4) ? az_a1 : *(const bf16x8*)&S[4096 + ag1];
      #pragma unroll
      for (int cf = 0; cf < 4; ++cf){
        const int wg = ((ks * 4 + l4) * 128 + wc * 64 + cf * 16 + l15) * 8;
        const bf16x8 w1 = *(const bf16x8*)&Wl[wg];
        const bf16x8 w2 = *(const bf16x8*)&Wl[32768 + wg];
        az0[cf] = MFMA(az_a0, w1, az0[cf], 0, 0, 0);
        az1[cf] = MFMA(az_a1, w1, az1[cf], 0, 0, 0);
        ah0[cf] = MFMA(ah_a0, w2, ah0[cf], 0, 0, 0);
        ah1[cf] = MFMA(ah_a1, w2, ah1[cf], 0, 0, 0);
      }
    }
    #pragma unroll
    for (int cf = 0; cf < 4; ++cf){
      const int col = wc * 64 + cf * 16 + l15;
      const float bvz = bz[col], bvh = bh[col];
      #pragma unroll
      for (int rf = 0; rf < 2; ++rf){
        const f32x4 zc = rf ? az1[cf] : az0[cf];
        const f32x4 hc = rf ? ah1[cf] : ah0[cf];
        #pragma unroll
        for (int i = 0; i < 4; ++i){
          const size_t o = ((size_t)tile * 128 + wr * 32 + rf * 16 + l4 * 4 + i) * 128 + col;
          const float z = sigmoidf_(zc[i] + bvz);
          const float h = tanh_fast(hc[i] + bvh);
          out[o] = f2bf((1.f - z) * bf2f(s16[o]) + z * h);
        }
      }
    }
  }
}

// ---------------- B-path GEMMs (register-W, small) ----------------
template<int KS1, int KS2, int EPI, bool OB16>
__global__ __launch_bounds__(512) void gemm1_kernel(
    int tiles,
    const unsigned short* __restrict__ A1,
    const unsigned short* __restrict__ A2,
    const unsigned short* __restrict__ Wt,
    const float* __restrict__ bias,
    void* __restrict__ outv)
{
  const int t = threadIdx.x, wv = t >> 6, lane = t & 63;
  const int l15 = lane & 15, l4 = lane >> 4;
  constexpr int KS = KS1 + KS2;
  bf16x8 Wr[KS];
  #pragma unroll
  for (int ks = 0; ks < KS; ++ks)
    Wr[ks] = *(const bf16x8*)&Wt[((size_t)(ks * 4 + l4) * 128 + wv * 16 + l15) * 8];
  for (int tile = blockIdx.x; tile < tiles; tile += gridDim.x){
    const int rw = tile * 32;
    bf16x8 ar[KS][2];
    #pragma unroll
    for (int ks = 0; ks < KS1; ++ks)
      #pragma unroll
      for (int rf = 0; rf < 2; ++rf)
        ar[ks][rf] = *(const bf16x8*)&A1[(size_t)(rw + rf * 16 + l15) * (KS1 * 32) + ks * 32 + l4 * 8];
    #pragma unroll
    for (int ks = 0; ks < KS2; ++ks)
      #pragma unroll
      for (int rf = 0; rf < 2; ++rf)
        ar[KS1 + ks][rf] = *(const bf16x8*)&A2[(size_t)(rw + rf * 16 + l15) * (KS2 * 32) + ks * 32 + l4 * 8];
    f32x4 acc0 = {0.f,0.f,0.f,0.f}, acc1 = {0.f,0.f,0.f,0.f};
    #pragma unroll
    for (int ks = 0; ks < KS; ++ks){
      acc0 = MFMA(ar[ks][0], Wr[ks], acc0, 0, 0, 0);
      acc1 = MFMA(ar[ks][1], Wr[ks], acc1, 0, 0, 0);
    }
    const int col = wv * 16 + l15;
    const float bv = bias ? bias[col] : 0.f;
    #pragma unroll
    for (int rf = 0; rf < 2; ++rf){
      const f32x4 ac = rf ? acc1 : acc0;
      #pragma unroll
      for (int i = 0; i < 4; ++i){
        const size_t o = (size_t)(rw + rf * 16 + l4 * 4 + i) * 128 + col;
        float v = ac[i] + bv;
        if (EPI == EPI_RELU)         v = fmaxf(v, 0.f);
        else if (EPI == EPI_SIGMOID) v = sigmoidf_(v);
        if (OB16) ((unsigned short*)outv)[o] = f2bf(v);
        else      ((float*)outv)[o] = v;
      }
    }
  }
}

// Fused z_d + z_l: blocks [0,tiles) -> side a (f32 out), [tiles,2*tiles) -> b (bf16).
__global__ __launch_bounds__(512) void gemm1_dual_kernel(
    int tiles,
    const unsigned short* __restrict__ A1a, const unsigned short* __restrict__ A2a,
    const unsigned short* __restrict__ Wta, const float* __restrict__ ba,
    float* __restrict__ outa,
    const unsigned short* __restrict__ A1b, const unsigned short* __restrict__ A2b,
    const unsigned short* __restrict__ Wtb, const float* __restrict__ bb,
    unsigned short* __restrict__ outb)
{
  const int t = threadIdx.x, wv = t >> 6, lane = t & 63;
  const int l15 = lane & 15, l4 = lane >> 4;
  const bool sb = ((int)blockIdx.x >= tiles);
  const int tile = (int)blockIdx.x - (sb ? tiles : 0);
  const unsigned short* A1 = sb ? A1b : A1a;
  const unsigned short* A2 = sb ? A2b : A2a;
  const unsigned short* Wt = sb ? Wtb : Wta;
  const float* bias = sb ? bb : ba;
  bf16x8 Wr[12];
  #pragma unroll
  for (int ks = 0; ks < 12; ++ks)
    Wr[ks] = *(const bf16x8*)&Wt[((size_t)(ks * 4 + l4) * 128 + wv * 16 + l15) * 8];
  const int rw = tile * 32;
  bf16x8 ar[12][2];
  #pragma unroll
  for (int ks = 0; ks < 4; ++ks)
    #pragma unroll
    for (int rf = 0; rf < 2; ++rf)
      ar[ks][rf] = *(const bf16x8*)&A1[(size_t)(rw + rf * 16 + l15) * 128 + ks * 32 + l4 * 8];
  #pragma unroll
  for (int ks = 0; ks < 8; ++ks)
    #pragma unroll
    for (int rf = 0; rf < 2; ++rf)
      ar[4 + ks][rf] = *(const bf16x8*)&A2[(size_t)(rw + rf * 16 + l15) * 256 + ks * 32 + l4 * 8];
  f32x4 acc0 = {0.f,0.f,0.f,0.f}, acc1 = {0.f,0.f,0.f,0.f};
  #pragma unroll
  for (int ks = 0; ks < 12; ++ks){
    acc0 = MFMA(ar[ks][0], Wr[ks], acc0, 0, 0, 0);
    acc1 = MFMA(ar[ks][1], Wr[ks], acc1, 0, 0, 0);
  }
  const int col = wv * 16 + l15;
  const float bv = bias[col];
  #pragma unroll
  for (int rf = 0; rf < 2; ++rf){
    const f32x4 ac = rf ? acc1 : acc0;
    #pragma unroll
    for (int i = 0; i < 4; ++i){
      const size_t o = (size_t)(rw + rf * 16 + l4 * 4 + i) * 128 + col;
      const float v = fmaxf(ac[i] + bv, 0.f);
      if (sb) outb[o] = f2bf(v);
      else    outa[o] = v;
    }
  }
}

// Fused 4-way attention projection: blocks [0,tiles) -> topology head
// (ht16 @ a_dT|a_dG), [tiles,2*tiles) -> label head (me16 @ a_lT|a_lG).
__global__ __launch_bounds__(512) void gemm_proj4_kernel(
    int tiles,
    const unsigned short* __restrict__ Ad, const unsigned short* __restrict__ Al,
    const unsigned short* __restrict__ WdT, const unsigned short* __restrict__ WdG,
    const unsigned short* __restrict__ WlT, const unsigned short* __restrict__ WlG,
    float* __restrict__ oTd, float* __restrict__ oGd,
    float* __restrict__ oTl, float* __restrict__ oGl)
{
  const int t = threadIdx.x, wv = t >> 6, lane = t & 63;
  const int l15 = lane & 15, l4 = lane >> 4;
  const bool lab = ((int)blockIdx.x >= tiles);
  const int tile = (int)blockIdx.x - (lab ? tiles : 0);
  const unsigned short* A1  = lab ? Al  : Ad;
  const unsigned short* W1t = lab ? WlT : WdT;
  const unsigned short* W2t = lab ? WlG : WdG;
  float* out1 = lab ? oTl : oTd;
  float* out2 = lab ? oGl : oGd;
  bf16x8 W1r[4], W2r[4];
  #pragma unroll
  for (int ks = 0; ks < 4; ++ks){
    const size_t fo = ((size_t)(ks * 4 + l4) * 128 + wv * 16 + l15) * 8;
    W1r[ks] = *(const bf16x8*)&W1t[fo];
    W2r[ks] = *(const bf16x8*)&W2t[fo];
  }
  const int rw = tile * 32;
  bf16x8 a[4][2];
  #pragma unroll
  for (int ks = 0; ks < 4; ++ks)
    #pragma unroll
    for (int rf = 0; rf < 2; ++rf)
      a[ks][rf] = *(const bf16x8*)&A1[(size_t)(rw + rf * 16 + l15) * 128 + ks * 32 + l4 * 8];
  f32x4 p10 = {0.f,0.f,0.f,0.f}, p11 = {0.f,0.f,0.f,0.f};
  f32x4 p20 = {0.f,0.f,0.f,0.f}, p21 = {0.f,0.f,0.f,0.f};
  #pragma unroll
  for (int ks = 0; ks < 4; ++ks){
    p10 = MFMA(a[ks][0], W1r[ks], p10, 0, 0, 0);
    p20 = MFMA(a[ks][0], W2r[ks], p20, 0, 0, 0);
    p11 = MFMA(a[ks][1], W1r[ks], p11, 0, 0, 0);
    p21 = MFMA(a[ks][1], W2r[ks], p21, 0, 0, 0);
  }
  const int col = wv * 16 + l15;
  #pragma unroll
  for (int rf = 0; rf < 2; ++rf){
    const f32x4 c1 = rf ? p11 : p10;
    const f32x4 c2 = rf ? p21 : p20;
    #pragma unroll
    for (int i = 0; i < 4; ++i){
      const size_t o = (size_t)(rw + rf * 16 + l4 * 4 + i) * 128 + col;
      out1[o] = c1[i];
      out2[o] = c2[i];
    }
  }
}

// ---------------- CSR build (by lg_dst) ----------------

__global__ __launch_bounds__(256) void csr_count_kernel(
    const int* __restrict__ lg_dst, int ELG,
    int* __restrict__ cnt, int* __restrict__ ticket)
{
  const int e = blockIdx.x * 256 + threadIdx.x;
  if (e < ELG) ticket[e] = atomicAdd(&cnt[lg_dst[e]], 1);
}

#define SCAN_CHUNK 1024

__global__ __launch_bounds__(256) void scan_totals_kernel(
    const int* __restrict__ cnt, int n, int* __restrict__ bsum)
{
  __shared__ int red[256];
  const int base = blockIdx.x * SCAN_CHUNK;
  const int t = threadIdx.x;
  int s = 0;
  #pragma unroll
  for (int k = 0; k < 4; ++k){
    const int idx = base + t + k * 256;
    if (idx < n) s += cnt[idx];
  }
  red[t] = s; __syncthreads();
  for (int g = 128; g; g >>= 1){
    if (t < g) red[t] += red[t + g];
    __syncthreads();
  }
  if (t == 0) bsum[blockIdx.x] = red[0];
}

__global__ void scan_serial_kernel(int* bsum, int nb, int* offsets, int n)
{
  if (threadIdx.x == 0 && blockIdx.x == 0){
    int acc = 0;
    for (int i = 0; i < nb; ++i){ const int v = bsum[i]; bsum[i] = acc; acc += v; }
    offsets[n] = acc;
  }
}

__global__ __launch_bounds__(256) void scan_write_kernel(
    const int* __restrict__ cnt, int n,
    const int* __restrict__ bsum, int* __restrict__ offsets)
{
  __shared__ int wsum[4];
  const int base = blockIdx.x * SCAN_CHUNK;
  const int t = threadIdx.x;
  int v[4]; int lsum = 0;
  #pragma unroll
  for (int k = 0; k < 4; ++k){
    const int idx = base + t * 4 + k;
    v[k] = (idx < n) ? cnt[idx] : 0;
    lsum += v[k];
  }
  const int lane = t & 63, wv = t >> 6;
  int x = lsum;
  #pragma unroll
  for (int off = 1; off < 64; off <<= 1){
    const int y = __shfl_up(x, off, 64);
    if (lane >= off) x += y;
  }
  if (lane == 63) wsum[wv] = x;
  __syncthreads();
  int woff = 0;
  for (int i = 0; i < wv; ++i) woff += wsum[i];
  int run = x - lsum + woff + bsum[blockIdx.x];
  #pragma unroll
  for (int k = 0; k < 4; ++k){
    const int idx = base + t * 4 + k;
    if (idx < n) offsets[idx] = run;
    run += v[k];
  }
}

__global__ __launch_bounds__(256) void csr_fill_kernel(
    const int* __restrict__ lg_src, const int* __restrict__ lg_dst,
    const int* __restrict__ ticket, int ELG,
    const int* __restrict__ offsets, int* __restrict__ csr_src)
{
  const int e = blockIdx.x * 256 + threadIdx.x;
  if (e >= ELG) return;
  csr_src[offsets[lg_dst[e]] + ticket[e]] = lg_src[e];
}

// ---------------- CSR gathers (bf16 rows, f32 accumulate) ----------------

// compacted: s/srh at S1 rows only; sources via rank2 into compacted msg/R.
__global__ __launch_bounds__(256) void gather2_bf_kernel(
    const int* __restrict__ offsets, const int* __restrict__ csr_src,
    const int* __restrict__ cnt1p, const int* __restrict__ S1list,
    const int* __restrict__ rank2,
    const unsigned short* __restrict__ msg16c, const unsigned short* __restrict__ R16c,
    unsigned short* __restrict__ s16c, unsigned short* __restrict__ srh16c)
{
  const int total = (*cnt1p) * 16;
  for (int g = blockIdx.x * 256 + threadIdx.x; g < total; g += gridDim.x * 256){
    const int i = g >> 4, q = g & 15;
    const int v = S1list[i];
    const int beg = offsets[v], end = offsets[v + 1];
    float as[8] = {}, ar[8] = {};
    for (int j = beg; j < end; ++j){
      const int sc = rank2[csr_src[j]];
      acc8(as, *(const uint4*)&msg16c[(size_t)sc * 128 + q * 8]);
      acc8(ar, *(const uint4*)&R16c[(size_t)sc * 128 + q * 8]);
    }
    *(uint4*)&s16c[(size_t)i * 128 + q * 8] = pack8(as);
    *(uint4*)&srh16c[(size_t)i * 128 + q * 8] = pack8(ar);
  }
}

// eids gather: sum_h[eids] via CSR walk over compacted mn16c (rank1).
__global__ __launch_bounds__(256) void gather3_kernel(
    const int* __restrict__ eids, int B,
    const float* __restrict__ f_srcf, const unsigned short* __restrict__ mn16c,
    const int* __restrict__ rank1,
    const int* __restrict__ offsets, const int* __restrict__ csr_src,
    unsigned short* __restrict__ fs_e, unsigned short* __restrict__ sh_e,
    unsigned short* __restrict__ m_e)
{
  const int g = blockIdx.x * 256 + threadIdx.x;
  const int bI = g >> 4, q = g & 15;
  if (bI >= B) return;
  const int e = eids[bI];
  *(uint4*)&fs_e[(size_t)bI * 128 + q * 8] = cvt8(f_srcf + (size_t)e * 128 + q * 8);
  *(uint4*)&m_e [(size_t)bI * 128 + q * 8] =
      *(const uint4*)&mn16c[(size_t)rank1[e] * 128 + q * 8];
  const int beg = offsets[e], end = offsets[e + 1];
  float a[8] = {};
  for (int j = beg; j < end; ++j){
    const int sc = rank1[csr_src[j]];
    acc8(a, *(const uint4*)&mn16c[(size_t)sc * 128 + q * 8]);
  }
  *(uint4*)&sh_e[(size_t)bI * 128 + q * 8] = pack8(a);
}

// Fused per-graph attention, 4 graphs/block (one wave each). Global graph
// index g in [0,2B): g<B -> x_T (cols [0,128)), else x_G (cols [128,256)).
// B%4==0 so each block is uniformly T or G.
__global__ __launch_bounds__(256) void attn2_kernel(
    const float* __restrict__ xT, int nTn,
    const float* __restrict__ xG, int nGn,
    const float* __restrict__ haTd, const float* __restrict__ haGd,
    const float* __restrict__ haTl, const float* __restrict__ haGl,
    unsigned short* __restrict__ out_d, unsigned short* __restrict__ out_l, int B)
{
  const int w = threadIdx.x >> 6, l = threadIdx.x & 63;
  int g = blockIdx.x * 4 + w;
  const bool isG = (g >= B);
  const int b = isG ? g - B : g;
  const float* x  = isG ? xG : xT;
  const int n     = isG ? nGn : nTn;
  const float* ha_d = isG ? haGd : haTd;
  const float* ha_l = isG ? haGl : haTl;
  const int col_off = isG ? 128 : 0;
  __shared__ __align__(16) float hd[4][128], hl[4][128];
  __shared__ float pd[4][64], pl[4][64];
  hd[w][l]      = ha_d[(size_t)b * 128 + l];
  hd[w][l + 64] = ha_d[(size_t)b * 128 + 64 + l];
  hl[w][l]      = ha_l[(size_t)b * 128 + l];
  hl[w][l + 64] = ha_l[(size_t)b * 128 + 64 + l];
  __syncthreads();
  float ed = -1e30f, el = -1e30f;
  if (l < n){
    const float4* xr = (const float4*)(x + ((size_t)b * n + l) * 128);
    float sd = 0.f, sl = 0.f;
    #pragma unroll 8
    for (int k = 0; k < 32; ++k){
      const float4 xv = xr[k];
      const float4 hdv = *(const float4*)&hd[w][k * 4];
      const float4 hlv = *(const float4*)&hl[w][k * 4];
      sd += xv.x * hdv.x + xv.y * hdv.y + xv.z * hdv.z + xv.w * hdv.w;
      sl += xv.x * hlv.x + xv.y * hlv.y + xv.z * hlv.z + xv.w * hlv.w;
    }
    ed = sd; el = sl;
  }
  const float md = wave_max64(ed), ml = wave_max64(el);
  const float exd = (l < n) ? __expf(ed - md) : 0.f;
  const float exl = (l < n) ? __expf(el - ml) : 0.f;
  const float zd = wave_sum64(exd), zl = wave_sum64(exl);
  pd[w][l] = exd / zd;
  pl[w][l] = exl / zl;
  __syncthreads();
  float od0 = 0.f, od1 = 0.f, ol0 = 0.f, ol1 = 0.f;
  #pragma unroll 4
  for (int i = 0; i < n; ++i){
    const float* xr = x + ((size_t)b * n + i) * 128;
    const float x0 = xr[l], x1 = xr[l + 64];
    const float wd = pd[w][i], wl = pl[w][i];
    od0 += wd * x0; od1 += wd * x1;
    ol0 += wl * x0; ol1 += wl * x1;
  }
  const size_t o = (size_t)b * 256 + col_off;
  out_d[o + l] = f2bf(od0); out_d[o + 64 + l] = f2bf(od1);
  out_l[o + l] = f2bf(ol0); out_l[o + 64 + l] = f2bf(ol1);
}

__global__ __launch_bounds__(256) void ce_topo_kernel(
    const float* __restrict__ z_d, const float* __restrict__ u_d,
    const float* __restrict__ b_d3, const float* __restrict__ expand,
    float* __restrict__ out, int B)
{
  const int r = blockIdx.x * 4 + (threadIdx.x >> 6);
  const int l = threadIdx.x & 63;
  if (r >= B) return;
  const float* row = z_d + (size_t)r * 128;
  float s = row[l] * u_d[l] + row[l + 64] * u_d[l + 64];
  s = wave_sum64(s);
  if (l == 0){
    const float p = s + b_d3[0];
    const float t = expand[r];
    const float loss = -(t * logsigf_(p) + (1.f - t) * logsigf_(1.f - p));
    atomicAdd(out, loss / (float)B);
  }
}

// ---------------- label CE via MFMA: 32 rows/block, all V cols ----------------
__global__ __launch_bounds__(512) void ce_label_mfma_kernel(
    const unsigned short* __restrict__ zl16,
    const unsigned short* __restrict__ ul,    // granule layout k8*V + col
    const float* __restrict__ b_l2, const int* __restrict__ wid,
    float* __restrict__ out, int B, int V)
{
  const int NF = V >> 4;
  const int t = threadIdx.x, wv = t >> 6, lane = t & 63;
  const int l15 = lane & 15, l4 = lane >> 4;
  const int rw = blockIdx.x * 32;
  __shared__ float redm[32][8];
  __shared__ float reds[32][8];
  __shared__ float rowm[32];
  __shared__ float tgt[32];

  bf16x8 a[4][2];
  #pragma unroll
  for (int ks = 0; ks < 4; ++ks)
    #pragma unroll
    for (int rf = 0; rf < 2; ++rf)
      a[ks][rf] = *(const bf16x8*)&zl16[(size_t)(rw + rf * 16 + l15) * 128 + ks * 32 + l4 * 8];

  f32x4 acc[7][2];
  #pragma unroll
  for (int j = 0; j < 7; ++j){
    acc[j][0] = (f32x4){0.f,0.f,0.f,0.f};
    acc[j][1] = (f32x4){0.f,0.f,0.f,0.f};
  }
  #pragma unroll
  for (int j = 0; j < 7; ++j){
    const int cf = wv + 8 * j;
    if (cf < NF){
      #pragma unroll
      for (int ks = 0; ks < 4; ++ks){
        const bf16x8 bf = *(const bf16x8*)&ul[((size_t)(ks * 4 + l4) * V + cf * 16 + l15) * 8];
        acc[j][0] = MFMA(a[ks][0], bf, acc[j][0], 0, 0, 0);
        acc[j][1] = MFMA(a[ks][1], bf, acc[j][1], 0, 0, 0);
      }
    }
  }
  float mloc[8];
  #pragma unroll
  for (int k = 0; k < 8; ++k) mloc[k] = -1e30f;
  #pragma unroll
  for (int j = 0; j < 7; ++j){
    const int cf = wv + 8 * j;
    if (cf < NF){
      const float bv = b_l2[cf * 16 + l15];
      #pragma unroll
      for (int rf = 0; rf < 2; ++rf)
        #pragma unroll
        for (int i = 0; i < 4; ++i){
          const float v = acc[j][rf][i] + bv;
          acc[j][rf][i] = v;
          mloc[rf * 4 + i] = fmaxf(mloc[rf * 4 + i], v);
        }
    }
  }
  #pragma unroll
  for (int m = 1; m < 16; m <<= 1)
    #pragma unroll
    for (int k = 0; k < 8; ++k)
      mloc[k] = fmaxf(mloc[k], __shfl_xor(mloc[k], m, 64));
  if (l15 == 0){
    #pragma unroll
    for (int rf = 0; rf < 2; ++rf)
      #pragma unroll
      for (int i = 0; i < 4; ++i)
        redm[rf * 16 + l4 * 4 + i][wv] = mloc[rf * 4 + i];
  }
  __syncthreads();
  if (t < 32){
    float m = redm[t][0];
    #pragma unroll
    for (int k = 1; k < 8; ++k) m = fmaxf(m, redm[t][k]);
    rowm[t] = m;
  }
  __syncthreads();
  float sloc[8];
  #pragma unroll
  for (int k = 0; k < 8; ++k) sloc[k] = 0.f;
  #pragma unroll
  for (int j = 0; j < 7; ++j){
    const int cf = wv + 8 * j;
    if (cf < NF){
      #pragma unroll
      for (int rf = 0; rf < 2; ++rf)
        #pragma unroll
        for (int i = 0; i < 4; ++i){
          const int lr = rf * 16 + l4 * 4 + i;
          const float v = acc[j][rf][i];
          sloc[rf * 4 + i] += __expf(v - rowm[lr]);
          if (cf * 16 + l15 == wid[rw + lr]) tgt[lr] = v;
        }
    }
  }
  #pragma unroll
  for (int m = 1; m < 16; m <<= 1)
    #pragma unroll
    for (int k = 0; k < 8; ++k)
      sloc[k] += __shfl_xor(sloc[k], m, 64);
  if (l15 == 0){
    #pragma unroll
    for (int rf = 0; rf < 2; ++rf)
      #pragma unroll
      for (int i = 0; i < 4; ++i)
        reds[rf * 16 + l4 * 4 + i][wv] = sloc[rf * 4 + i];
  }
  __syncthreads();
  if (t < 32){
    float s = 0.f;
    #pragma unroll
    for (int k = 0; k < 8; ++k) s += reds[t][k];
    const float lp = tgt[t] - rowm[t] - __logf(s);
    atomicAdd(out + 1, -lp / (float)B);
  }
}

extern "C" void kernel_launch(void* const* d_in, const int* in_sizes, int n_in,
                              void* d_out, int out_size, void* d_ws, size_t ws_size,
                              hipStream_t stream)
{
  const float* msg    = (const float*)d_in[0];
  const float* f_src  = (const float*)d_in[1];
  const float* f_dst  = (const float*)d_in[2];
  const float* x_T    = (const float*)d_in[3];
  const float* x_G    = (const float*)d_in[4];
  const float* expand = (const float*)d_in[5];
  const float* wz = (const float*)d_in[6];
  const float* uz = (const float*)d_in[7];
  const float* bz = (const float*)d_in[8];
  const float* wr = (const float*)d_in[9];
  const float* ur = (const float*)d_in[10];
  const float* br = (const float*)d_in[11];
  const float* w  = (const float*)d_in[12];
  const float* u  = (const float*)d_in[13];
  const float* b  = (const float*)d_in[14];
  const float* w_d1 = (const float*)d_in[15];
  const float* w_d2 = (const float*)d_in[16];
  const float* b_d1 = (const float*)d_in[17];
  const float* a_dT = (const float*)d_in[18];
  const float* a_dG = (const float*)d_in[19];
  const float* w_d3 = (const float*)d_in[20];
  const float* w_d4 = (const float*)d_in[21];
  const float* b_d2 = (const float*)d_in[22];
  const float* u_d  = (const float*)d_in[23];
  const float* b_d3 = (const float*)d_in[24];
  const float* w_l1 = (const float*)d_in[25];
  const float* w_l2 = (const float*)d_in[26];
  const float* b_l1 = (const float*)d_in[27];
  const float* a_lT = (const float*)d_in[28];
  const float* a_lG = (const float*)d_in[29];
  const float* u_l  = (const float*)d_in[30];
  const float* b_l2 = (const float*)d_in[31];
  const int* lg_src = (const int*)d_in[32];
  const int* lg_dst = (const int*)d_in[33];
  const int* eids   = (const int*)d_in[34];
  const int* wid    = (const int*)d_in[35];

  const int d = 128;
  const int E   = in_sizes[0] / d;
  const int ELG = in_sizes[32];
  const int B   = in_sizes[34];
  const int V   = in_sizes[31];
  const int nT  = (in_sizes[3] / d) / B;
  const int nG  = (in_sizes[4] / d) / B;

  const size_t EH = (size_t)E * d * sizeof(unsigned short);
  const size_t BH = (size_t)B * d * sizeof(unsigned short);
  const size_t BF = (size_t)B * d * sizeof(float);
  char* p = (char*)d_ws;
  unsigned short* bufA = (unsigned short*)p; p += EH;  // R16c -> mn16c
  unsigned short* bufB = (unsigned short*)p; p += EH;  // s16c
  unsigned short* srh16 = (unsigned short*)p; p += EH; // srh16c
  unsigned short* msg16 = (unsigned short*)p; p += EH; // msg16c
  unsigned short* R16 = bufA, *mn16 = bufA;
  unsigned short* s16 = bufB;
  unsigned short* fse16 = (unsigned short*)p; p += BH;
  unsigned short* she16 = (unsigned short*)p; p += BH;
  unsigned short* me16  = (unsigned short*)p; p += BH;
  unsigned short* ht16  = (unsigned short*)p; p += BH;
  unsigned short* cd16  = (unsigned short*)p; p += 2 * BH;
  unsigned short* cl16  = (unsigned short*)p; p += 2 * BH;
  unsigned short* zl16  = (unsigned short*)p; p += BH;
  float* haTd = (float*)p; p += BF;
  float* haGd = (float*)p; p += BF;
  float* haTl = (float*)p; p += BF;
  float* haGl = (float*)p; p += BF;
  float* z_d  = (float*)p; p += BF;
  // CSR scratch
  int* cnt     = (int*)p; p += (size_t)E * sizeof(int);
  int* offsets = (int*)p; p += (size_t)(E + 1) * sizeof(int);
  int* ticket  = (int*)p; p += (size_t)ELG * sizeof(int);
  int* csr_src = (int*)p; p += (size_t)ELG * sizeof(int);
  int* bsum    = (int*)p; p += (size_t)((E + SCAN_CHUNK - 1) / SCAN_CHUNK + 1) * sizeof(int);
  // active-set scratch (R26)
  int* flag1  = (int*)p; p += (size_t)E * sizeof(int);
  int* flag2  = (int*)p; p += (size_t)E * sizeof(int);
  int* cnts   = (int*)p; p += 2 * sizeof(int);
  int* S1list = (int*)p; p += (size_t)(E + 128) * sizeof(int);
  int* S2list = (int*)p; p += (size_t)(E + 128) * sizeof(int);
  int* rank1  = (int*)p; p += (size_t)E * sizeof(int);
  int* rank2  = (int*)p; p += (size_t)E * sizeof(int);
  // bf16 fragment-layout weights
  p = (char*)(((size_t)p + 255) & ~(size_t)255);
  unsigned short* wt = (unsigned short*)p; p += 294912 * sizeof(unsigned short);
  p = (char*)(((size_t)p + 255) & ~(size_t)255);
  unsigned short* wt_ul = (unsigned short*)p; p += (size_t)128 * V * sizeof(unsigned short);

  hipMemsetAsync(cnt, 0, (size_t)E * sizeof(int), stream);
  hipMemsetAsync(flag1, 0, 2 * (size_t)E * sizeof(int), stream);  // flag1+flag2
  hipMemsetAsync(cnts, 0, 2 * sizeof(int), stream);
  hipMemsetAsync(d_out, 0, 2 * sizeof(float), stream);

  const int nb = (E + SCAN_CHUNK - 1) / SCAN_CHUNK;
  const int tilesB = B / 32;
  const int ublocks = (16 * V + 255) / 256;
  const int wblocks = (ublocks > 24) ? ublocks : 24;

  // weights -> bf16 fragment layout (y<10: panels; y==10: u_l)
  wprep_kernel<<<dim3(wblocks, 11), 256, 0, stream>>>(
      wr, ur, wz, uz, w, u, w_d1, w_d2, a_dT, a_dG, a_lT, a_lG,
      w_d3, w_d4, w_l1, w_l2, wt, u_l, wt_ul, V);

  // ---- CSR build (by lg_dst) ----
  csr_count_kernel<<<(ELG + 255) / 256, 256, 0, stream>>>(lg_dst, ELG, cnt, ticket);
  scan_totals_kernel<<<nb, 256, 0, stream>>>(cnt, E, bsum);
  scan_serial_kernel<<<1, 64, 0, stream>>>(bsum, nb, offsets, E);
  scan_write_kernel<<<nb, 256, 0, stream>>>(cnt, E, bsum, offsets);
  csr_fill_kernel<<<(ELG + 255) / 256, 256, 0, stream>>>(lg_src, lg_dst, ticket, ELG, offsets, csr_src);

  // ---- active sets: S1 = eids + their sources; S2 = sources of S1 ----
  mark1_kernel<<<(B + 255) / 256, 256, 0, stream>>>(eids, B, offsets, csr_src, flag1);
  compact_kernel<<<(E + 255) / 256, 256, 0, stream>>>(flag1, E, S1list, rank1, cnts + 0);
  mark2_kernel<<<512, 256, 0, stream>>>(cnts + 0, S1list, offsets, csr_src, flag2);
  compact_kernel<<<(E + 255) / 256, 256, 0, stream>>>(flag2, E, S2list, rank2, cnts + 1);
  pad_kernel<<<1, 64, 0, stream>>>(cnts + 0, S1list, cnts + 1, S2list);

  // R = sigmoid(f_dst@wr + msg@ur + br) * msg at S2 rows -> R16c, msg16c
  gemm_r_kernel<<<512, 512, 0, stream>>>(
      cnts + 1, S2list, f_dst, msg, wt + 0, br, R16, msg16);
  // s/srh segsums at S1 rows (compacted, sources via rank2)
  gather2_bf_kernel<<<2048, 256, 0, stream>>>(
      offsets, csr_src, cnts + 0, S1list, rank2, msg16, R16, s16, srh16);
  // msg_new at S1 rows -> mn16c
  gemm_zh_kernel<<<256, 512, 0, stream>>>(
      cnts + 0, S1list, f_src, s16, srh16, wt + 32768, wt + 65536, bz, b, mn16);
  // eids gathers incl. sum_h[eids] via CSR walk over mn16c
  gather3_kernel<<<(B * 16 + 255) / 256, 256, 0, stream>>>(
      eids, B, f_src, mn16, rank1, offsets, csr_src, fse16, she16, me16);
  // h_t = relu(fs_e@w_d1 + sh_e@w_d2 + b_d1)   -> ht16
  gemm1_kernel<4, 4, EPI_RELU, true><<<tilesB, 512, 0, stream>>>(
      tilesB, fse16, she16, wt + 98304, b_d1, ht16);
  // all four attention projections in one full-CU launch
  gemm_proj4_kernel<<<2 * tilesB, 512, 0, stream>>>(
      tilesB, ht16, me16,
      wt + 131072, wt + 147456, wt + 163840, wt + 180224,
      haTd, haGd, haTl, haGl);
  // fused attention: 4 graphs/block (R27), T+G in one launch
  attn2_kernel<<<(2 * B) / 4, 256, 0, stream>>>(
      x_T, nT, x_G, nG, haTd, haGd, haTl, haGl, cd16, cl16, B);
  // z_d (f32) + z_l (bf16) in one full-CU launch
  gemm1_dual_kernel<<<2 * tilesB, 512, 0, stream>>>(
      tilesB,
      ht16, cd16, wt + 196608, b_d2, z_d,
      me16, cl16, wt + 245760, b_l1, zl16);
  // losses
  ce_topo_kernel<<<(B + 3) / 4, 256, 0, stream>>>(z_d, u_d, b_d3, expand, (float*)d_out, B);
  ce_label_mfma_kernel<<<B / 32, 512, 0, stream>>>(zl16, wt_ul, b_l2, wid,
                                                   (float*)d_out, B, V);
}

// Round 28
// 389.867 us; speedup vs baseline: 1.0475x; 1.0475x over previous
//
#include <hip/hip_runtime.h>
#include <math.h>

// G2GDecoder forward: TreeGRU over line graph + topology/label heads.
// R2: CSR gathers. R5: bf16 MFMA. R11: MFMA label-CE. R15-R21: persistent-W
// E-GEMMs, T14 split staging, XOR-swizzled A-rings. R24: tail fusion.
// R25/R26: active-set sparsification (S1/S2, ~5-10% of E).
// R28: revert R27's 4-graph packing (occupancy did NOT rise: 41% vs 45%,
// slot-limit hypothesis falsified; FETCH +22MB locality loss). Back to
// 1 graph/block; instead halve pass-2 VMEM instr count: lane reads one
// float2 (cols 2l,2l+1; 512B contiguous/wave) and stores one packed u32.
// Same per-column accumulation order -> identical values.

using bf16x8 = __attribute__((ext_vector_type(8))) short;
using f32x4  = __attribute__((ext_vector_type(4))) float;

#define MFMA __builtin_amdgcn_mfma_f32_16x16x32_bf16

__device__ inline float wave_sum64(float v){
  #pragma unroll
  for (int m = 32; m; m >>= 1) v += __shfl_xor(v, m, 64);
  return v;
}
__device__ inline float wave_max64(float v){
  #pragma unroll
  for (int m = 32; m; m >>= 1) v = fmaxf(v, __shfl_xor(v, m, 64));
  return v;
}
__device__ inline float sigmoidf_(float x){ return 1.f / (1.f + __expf(-x)); }
__device__ inline float tanh_fast(float x){
  x = fminf(fmaxf(x, -15.f), 15.f);
  float e = __expf(2.f * x);
  return (e - 1.f) / (e + 1.f);
}
__device__ inline float logsigf_(float x){
  return (x >= 0.f) ? -log1pf(__expf(-x)) : (x - log1pf(__expf(x)));
}
__device__ inline unsigned short f2bf(float f){
  union { float f; unsigned u; } v; v.f = f;
  const unsigned r = v.u + 0x7FFF + ((v.u >> 16) & 1);   // RNE
  return (unsigned short)(r >> 16);
}
__device__ inline float bf2f(unsigned short u){
  union { unsigned u; float f; } v; v.u = ((unsigned)u) << 16; return v.f;
}
__device__ inline unsigned pk2(unsigned short a, unsigned short b){
  return (unsigned)a | ((unsigned)b << 16);
}
__device__ inline uint4 cvt8v(float4 x0, float4 x1){
  uint4 o;
  o.x = pk2(f2bf(x0.x), f2bf(x0.y)); o.y = pk2(f2bf(x0.z), f2bf(x0.w));
  o.z = pk2(f2bf(x1.x), f2bf(x1.y)); o.w = pk2(f2bf(x1.z), f2bf(x1.w));
  return o;
}
__device__ inline uint4 cvt8(const float* __restrict__ p){
  return cvt8v(*(const float4*)(p), *(const float4*)(p + 4));
}
__device__ inline void acc8(float* a, uint4 v){
  a[0] += bf2f(v.x & 0xffff); a[1] += bf2f(v.x >> 16);
  a[2] += bf2f(v.y & 0xffff); a[3] += bf2f(v.y >> 16);
  a[4] += bf2f(v.z & 0xffff); a[5] += bf2f(v.z >> 16);
  a[6] += bf2f(v.w & 0xffff); a[7] += bf2f(v.w >> 16);
}
__device__ inline uint4 pack8(const float* a){
  uint4 o;
  o.x = pk2(f2bf(a[0]), f2bf(a[1])); o.y = pk2(f2bf(a[2]), f2bf(a[3]));
  o.z = pk2(f2bf(a[4]), f2bf(a[5])); o.w = pk2(f2bf(a[6]), f2bf(a[7]));
  return o;
}

enum { EPI_NONE = 0, EPI_SIGMOID = 1, EPI_RELU = 2 };

// ------- weight prep: f32 [k][col] -> bf16 fragment granule layout ---------
// blockIdx.y in [0,10): gate/head panels -> wt. blockIdx.y == 10: u_l -> wt_ul.
__global__ __launch_bounds__(256) void wprep_kernel(
    const float* wr, const float* ur, const float* wz, const float* uz,
    const float* w,  const float* u,  const float* w_d1, const float* w_d2,
    const float* a_dT, const float* a_dG, const float* a_lT, const float* a_lG,
    const float* w_d3, const float* w_d4, const float* w_l1, const float* w_l2,
    unsigned short* __restrict__ wt,
    const float* __restrict__ u_l, unsigned short* __restrict__ wt_ul, int V)
{
  const int m = blockIdx.y;
  const int tid = blockIdx.x * 256 + threadIdx.x;
  if (m == 10){
    if (tid >= 16 * V) return;
    const int col = tid % V, k8 = tid / V;
    unsigned short v[8];
    #pragma unroll
    for (int i = 0; i < 8; ++i)
      v[i] = f2bf(u_l[(size_t)(k8 * 8 + i) * V + col]);
    uint4 pk;
    pk.x = pk2(v[0], v[1]); pk.y = pk2(v[2], v[3]);
    pk.z = pk2(v[4], v[5]); pk.w = pk2(v[6], v[7]);
    *(uint4*)&wt_ul[((size_t)k8 * V + col) * 8] = pk;
    return;
  }
  const float* s1; const float* s2; int K1, Ktot; size_t off;
  switch (m){
    case 0: s1 = wr;   s2 = ur;   K1 = 128; Ktot = 256; off = 0;      break;
    case 1: s1 = wz;   s2 = uz;   K1 = 128; Ktot = 256; off = 32768;  break;
    case 2: s1 = w;    s2 = u;    K1 = 128; Ktot = 256; off = 65536;  break;
    case 3: s1 = w_d1; s2 = w_d2; K1 = 128; Ktot = 256; off = 98304;  break;
    case 4: s1 = a_dT; s2 = nullptr; K1 = 128; Ktot = 128; off = 131072; break;
    case 5: s1 = a_dG; s2 = nullptr; K1 = 128; Ktot = 128; off = 147456; break;
    case 6: s1 = a_lT; s2 = nullptr; K1 = 128; Ktot = 128; off = 163840; break;
    case 7: s1 = a_lG; s2 = nullptr; K1 = 128; Ktot = 128; off = 180224; break;
    case 8: s1 = w_d3; s2 = w_d4; K1 = 128; Ktot = 384; off = 196608; break;
    default:s1 = w_l1; s2 = w_l2; K1 = 128; Ktot = 384; off = 245760; break;
  }
  if (tid >= 16 * Ktot) return;
  const int col = tid & 127, k8 = tid >> 7;
  unsigned short v[8];
  #pragma unroll
  for (int i = 0; i < 8; ++i){
    const int k = k8 * 8 + i;
    const float* s = (k < K1) ? (s1 + (size_t)k * 128 + col)
                              : (s2 + (size_t)(k - K1) * 128 + col);
    v[i] = f2bf(*s);
  }
  uint4 pk;
  pk.x = pk2(v[0], v[1]); pk.y = pk2(v[2], v[3]);
  pk.z = pk2(v[4], v[5]); pk.w = pk2(v[6], v[7]);
  *(uint4*)&wt[off + ((size_t)k8 * 128 + col) * 8] = pk;
}

// ---------------- active-set construction ----------------
__global__ __launch_bounds__(256) void mark1_kernel(
    const int* __restrict__ eids, int B,
    const int* __restrict__ offsets, const int* __restrict__ csr_src,
    int* __restrict__ flag1)
{
  const int b = blockIdx.x * 256 + threadIdx.x;
  if (b >= B) return;
  const int e = eids[b];
  flag1[e] = 1;
  const int beg = offsets[e], end = offsets[e + 1];
  for (int j = beg; j < end; ++j) flag1[csr_src[j]] = 1;
}

__global__ __launch_bounds__(256) void compact_kernel(
    const int* __restrict__ flag, int E,
    int* __restrict__ list, int* __restrict__ rank, int* __restrict__ cnt)
{
  const int v = blockIdx.x * 256 + threadIdx.x;
  if (v >= E || !flag[v]) return;
  const int pos = atomicAdd(cnt, 1);
  list[pos] = v;
  rank[v] = pos;
}

__global__ __launch_bounds__(256) void mark2_kernel(
    const int* __restrict__ cnt1p, const int* __restrict__ S1list,
    const int* __restrict__ offsets, const int* __restrict__ csr_src,
    int* __restrict__ flag2)
{
  const int n = *cnt1p;
  for (int i = blockIdx.x * 256 + threadIdx.x; i < n; i += gridDim.x * 256){
    const int v = S1list[i];
    const int beg = offsets[v], end = offsets[v + 1];
    for (int j = beg; j < end; ++j) flag2[csr_src[j]] = 1;
  }
}

// pad counts up to tile multiples (S1: 128, S2: 64), filling with list[0]
__global__ void pad_kernel(int* cnt1, int* S1list, int* cnt2, int* S2list)
{
  if (threadIdx.x == 0 && blockIdx.x == 0){
    int c1 = *cnt1;
    if (c1 > 0){
      const int p1 = (c1 + 127) & ~127;
      for (int i = c1; i < p1; ++i) S1list[i] = S1list[0];
      *cnt1 = p1;
    }
    int c2 = *cnt2;
    if (c2 > 0){
      const int p2 = (c2 + 63) & ~63;
      for (int i = c2; i < p2; ++i) S2list[i] = S2list[0];
      *cnt2 = p2;
    }
  }
}

// ---------------- persistent-W R-GEMM over S2 (compacted rows) -------------
// 64-row tiles, K-chunk 64; T14 split staging, ring-2 XOR-swizzled.
__global__ __launch_bounds__(512, 2) void gemm_r_kernel(
    const int* __restrict__ cnt2p, const int* __restrict__ S2list,
    const float* __restrict__ A1f,     // f_dst
    const float* __restrict__ A2f,     // msg
    const unsigned short* __restrict__ Wt,
    const float* __restrict__ bias,
    unsigned short* __restrict__ out,  // R16c (compacted)
    unsigned short* __restrict__ out2) // msg16c (compacted)
{
  __shared__ unsigned short Wl[32768];   // 64KB persistent W panel
  __shared__ unsigned short Ar[2][4096]; // 8KB slots: 64 rows x 8 granules (swz)
  const int t = threadIdx.x;
  const int lane = t & 63, wid = t >> 6;
  const int l15 = lane & 15, l4 = lane >> 4;
  const int wr = wid >> 1, wc = wid & 1;   // 4 row-grp x 2 col-grp

  const int tiles = (*cnt2p) >> 6;
  const int nT = (tiles - (int)blockIdx.x + (int)gridDim.x - 1) / (int)gridDim.x;
  if (nT <= 0) return;

  #pragma unroll
  for (int i = 0; i < 8; ++i)
    ((uint4*)Wl)[i * 512 + t] = ((const uint4*)Wt)[i * 512 + t];

  const int totalG = nT * 4;   // 4 K-chunks per tile

  float4 ra, rb;   // in-flight staged data (raw f32, all 512 threads)

  auto loadA = [&](int gs){
    const int tile = (int)blockIdx.x + (gs >> 2) * (int)gridDim.x;
    const int cs = gs & 3;
    const size_t grow = (size_t)S2list[tile * 64 + (t >> 3)];
    const int q8 = (t & 7) * 8;
    const float* src = (cs < 2) ? (A1f + grow * 128 + cs * 64 + q8)
                                : (A2f + grow * 128 + (cs - 2) * 64 + q8);
    ra = *(const float4*)(src);
    rb = *(const float4*)(src + 4);
  };
  auto writeA = [&](int slot, int gs){
    const uint4 o = cvt8v(ra, rb);
    const int rrow = t >> 3, qq = t & 7;
    *(uint4*)&Ar[slot][((rrow << 3) | (qq ^ (rrow & 7))) * 8] = o;
    const int cs = gs & 3;
    if (cs >= 2){
      const int tile = (int)blockIdx.x + (gs >> 2) * (int)gridDim.x;
      const size_t crow = (size_t)tile * 64 + rrow;
      *(uint4*)&out2[crow * 128 + (cs - 2) * 64 + qq * 8] = o;
    }
  };

  loadA(0); writeA(0, 0);
  if (totalG > 1) loadA(1);

  for (int m = 0; m < nT; ++m){
    const int tile = (int)blockIdx.x + m * (int)gridDim.x;
    f32x4 acc[4];
    #pragma unroll
    for (int cf = 0; cf < 4; ++cf) acc[cf] = (f32x4){0.f,0.f,0.f,0.f};
    #pragma unroll
    for (int cs = 0; cs < 4; ++cs){
      const int g = m * 4 + cs;
      __syncthreads();
      if (g + 1 < totalG) writeA((g + 1) & 1, g + 1);  // regs from prev load
      if (g + 2 < totalG) loadA(g + 2);                // issue ahead
      const unsigned short* S = Ar[g & 1];
      const int arow = wr * 16 + l15;
      #pragma unroll
      for (int kk = 0; kk < 2; ++kk){
        const int qq = (kk * 4 + l4) ^ (arow & 7);
        const bf16x8 a = *(const bf16x8*)&S[((arow << 3) | qq) * 8];
        #pragma unroll
        for (int cf = 0; cf < 4; ++cf){
          const int wg = (((cs * 2 + kk) * 4 + l4) * 128 + wc * 64 + cf * 16 + l15) * 8;
          acc[cf] = MFMA(a, *(const bf16x8*)&Wl[wg], acc[cf], 0, 0, 0);
        }
      }
    }
    int growv[4];
    #pragma unroll
    for (int i = 0; i < 4; ++i)
      growv[i] = S2list[tile * 64 + wr * 16 + l4 * 4 + i];
    #pragma unroll
    for (int cf = 0; cf < 4; ++cf){
      const int col = wc * 64 + cf * 16 + l15;
      const float bv = bias[col];
      #pragma unroll
      for (int i = 0; i < 4; ++i){
        const size_t oc = ((size_t)tile * 64 + wr * 16 + l4 * 4 + i) * 128 + col;
        out[oc] = f2bf(sigmoidf_(acc[cf][i] + bv) * A2f[(size_t)growv[i] * 128 + col]);
      }
    }
  }
}

// ---------------- persistent-W merged Z+H GEMM over S1 (compacted) ---------
// 128-row tiles. LDS: 128KB W + 2x16KB ring = 160KB.
__global__ __launch_bounds__(512, 2) void gemm_zh_kernel(
    const int* __restrict__ cnt1p, const int* __restrict__ S1list,
    const float* __restrict__ fsrc,
    const unsigned short* __restrict__ s16,    // compacted
    const unsigned short* __restrict__ srh16,  // compacted
    const unsigned short* __restrict__ Wz,
    const unsigned short* __restrict__ Wh,
    const float* __restrict__ bz, const float* __restrict__ bh,
    unsigned short* __restrict__ out)          // mn16c compacted
{
  __shared__ unsigned short Wl[65536];   // Wz | Wh, 128KB persistent
  __shared__ unsigned short Ar[2][8192]; // 16KB slots: [0:4096)=z, [4096:8192)=h
  const int t = threadIdx.x;
  const int lane = t & 63, wid = t >> 6;
  const int l15 = lane & 15, l4 = lane >> 4;
  const int wr = wid >> 1, wc = wid & 1;

  const int tiles = (*cnt1p) >> 7;
  const int nT = (tiles - (int)blockIdx.x + (int)gridDim.x - 1) / (int)gridDim.x;
  if (nT <= 0) return;

  #pragma unroll
  for (int i = 0; i < 8; ++i){
    ((uint4*)Wl)[i * 512 + t]        = ((const uint4*)Wz)[i * 512 + t];
    ((uint4*)Wl)[4096 + i * 512 + t] = ((const uint4*)Wh)[i * 512 + t];
  }

  const int totalG = nT * 8;

  float4 ra, rb;   // phase1: raw f32; phase2: ra=s16 bits, rb=srh16 bits

  auto loadA = [&](int gs){
    const int tile = (int)blockIdx.x + (gs >> 3) * (int)gridDim.x;
    const int ks = gs & 7;
    const int crow = tile * 128 + (t >> 2);
    const int q8 = (t & 3) * 8;
    if (ks < 4){
      const size_t grow = (size_t)S1list[crow];
      const float* src = fsrc + grow * 128 + ks * 32 + q8;
      ra = *(const float4*)(src);
      rb = *(const float4*)(src + 4);
    } else {
      const uint4 v1 = *(const uint4*)&s16[(size_t)crow * 128 + (ks - 4) * 32 + q8];
      const uint4 v2 = *(const uint4*)&srh16[(size_t)crow * 128 + (ks - 4) * 32 + q8];
      ra = *(const float4*)&v1;
      rb = *(const float4*)&v2;
    }
  };
  auto writeA = [&](int slot, int gs){
    const int ks = gs & 7;
    const int rrow = t >> 2, qq = t & 3;
    const int gsw = ((rrow << 2) | (qq ^ ((rrow >> 1) & 3))) * 8;
    if (ks < 4){
      *(uint4*)&Ar[slot][gsw] = cvt8v(ra, rb);
    } else {
      *(uint4*)&Ar[slot][gsw]        = *(const uint4*)&ra;
      *(uint4*)&Ar[slot][4096 + gsw] = *(const uint4*)&rb;
    }
  };

  loadA(0); writeA(0, 0);
  if (totalG > 1) loadA(1);

  for (int m = 0; m < nT; ++m){
    const int tile = (int)blockIdx.x + m * (int)gridDim.x;
    f32x4 az0[4], az1[4], ah0[4], ah1[4];
    #pragma unroll
    for (int cf = 0; cf < 4; ++cf){
      az0[cf] = (f32x4){0.f,0.f,0.f,0.f}; az1[cf] = (f32x4){0.f,0.f,0.f,0.f};
      ah0[cf] = (f32x4){0.f,0.f,0.f,0.f}; ah1[cf] = (f32x4){0.f,0.f,0.f,0.f};
    }
    #pragma unroll
    for (int ks = 0; ks < 8; ++ks){
      const int g = m * 8 + ks;
      __syncthreads();
      if (g + 1 < totalG) writeA((g + 1) & 1, g + 1);
      if (g + 2 < totalG) loadA(g + 2);
      const unsigned short* S = Ar[g & 1];
      const int r0 = wr * 32 + l15, r1 = wr * 32 + 16 + l15;
      const int ag0 = ((r0 << 2) | (l4 ^ ((r0 >> 1) & 3))) * 8;
      const int ag1 = ((r1 << 2) | (l4 ^ ((r1 >> 1) & 3))) * 8;
      const bf16x8 az_a0 = *(const bf16x8*)&S[ag0];
      const bf16x8 az_a1 = *(const bf16x8*)&S[ag1];
      const bf16x8 ah_a0 = (ks < 4) ? az_a0 : *(const bf16x8*)&S[4096 + ag0];
      const bf16x8 ah_a1 = (ks < 4) ? az_a1 : *(const bf16x8*)&S[4096 + ag1];
      #pragma unroll
      for (int cf = 0; cf < 4; ++cf){
        const int wg = ((ks * 4 + l4) * 128 + wc * 64 + cf * 16 + l15) * 8;
        const bf16x8 w1 = *(const bf16x8*)&Wl[wg];
        const bf16x8 w2 = *(const bf16x8*)&Wl[32768 + wg];
        az0[cf] = MFMA(az_a0, w1, az0[cf], 0, 0, 0);
        az1[cf] = MFMA(az_a1, w1, az1[cf], 0, 0, 0);
        ah0[cf] = MFMA(ah_a0, w2, ah0[cf], 0, 0, 0);
        ah1[cf] = MFMA(ah_a1, w2, ah1[cf], 0, 0, 0);
      }
    }
    #pragma unroll
    for (int cf = 0; cf < 4; ++cf){
      const int col = wc * 64 + cf * 16 + l15;
      const float bvz = bz[col], bvh = bh[col];
      #pragma unroll
      for (int rf = 0; rf < 2; ++rf){
        const f32x4 zc = rf ? az1[cf] : az0[cf];
        const f32x4 hc = rf ? ah1[cf] : ah0[cf];
        #pragma unroll
        for (int i = 0; i < 4; ++i){
          const size_t o = ((size_t)tile * 128 + wr * 32 + rf * 16 + l4 * 4 + i) * 128 + col;
          const float z = sigmoidf_(zc[i] + bvz);
          const float h = tanh_fast(hc[i] + bvh);
          out[o] = f2bf((1.f - z) * bf2f(s16[o]) + z * h);
        }
      }
    }
  }
}

// ---------------- B-path GEMMs (register-W, small) ----------------
template<int KS1, int KS2, int EPI, bool OB16>
__global__ __launch_bounds__(512) void gemm1_kernel(
    int tiles,
    const unsigned short* __restrict__ A1,
    const unsigned short* __restrict__ A2,
    const unsigned short* __restrict__ Wt,
    const float* __restrict__ bias,
    void* __restrict__ outv)
{
  const int t = threadIdx.x, wv = t >> 6, lane = t & 63;
  const int l15 = lane & 15, l4 = lane >> 4;
  constexpr int KS = KS1 + KS2;
  bf16x8 Wr[KS];
  #pragma unroll
  for (int ks = 0; ks < KS; ++ks)
    Wr[ks] = *(const bf16x8*)&Wt[((size_t)(ks * 4 + l4) * 128 + wv * 16 + l15) * 8];
  for (int tile = blockIdx.x; tile < tiles; tile += gridDim.x){
    const int rw = tile * 32;
    bf16x8 ar[KS][2];
    #pragma unroll
    for (int ks = 0; ks < KS1; ++ks)
      #pragma unroll
      for (int rf = 0; rf < 2; ++rf)
        ar[ks][rf] = *(const bf16x8*)&A1[(size_t)(rw + rf * 16 + l15) * (KS1 * 32) + ks * 32 + l4 * 8];
    #pragma unroll
    for (int ks = 0; ks < KS2; ++ks)
      #pragma unroll
      for (int rf = 0; rf < 2; ++rf)
        ar[KS1 + ks][rf] = *(const bf16x8*)&A2[(size_t)(rw + rf * 16 + l15) * (KS2 * 32) + ks * 32 + l4 * 8];
    f32x4 acc0 = {0.f,0.f,0.f,0.f}, acc1 = {0.f,0.f,0.f,0.f};
    #pragma unroll
    for (int ks = 0; ks < KS; ++ks){
      acc0 = MFMA(ar[ks][0], Wr[ks], acc0, 0, 0, 0);
      acc1 = MFMA(ar[ks][1], Wr[ks], acc1, 0, 0, 0);
    }
    const int col = wv * 16 + l15;
    const float bv = bias ? bias[col] : 0.f;
    #pragma unroll
    for (int rf = 0; rf < 2; ++rf){
      const f32x4 ac = rf ? acc1 : acc0;
      #pragma unroll
      for (int i = 0; i < 4; ++i){
        const size_t o = (size_t)(rw + rf * 16 + l4 * 4 + i) * 128 + col;
        float v = ac[i] + bv;
        if (EPI == EPI_RELU)         v = fmaxf(v, 0.f);
        else if (EPI == EPI_SIGMOID) v = sigmoidf_(v);
        if (OB16) ((unsigned short*)outv)[o] = f2bf(v);
        else      ((float*)outv)[o] = v;
      }
    }
  }
}

// Fused z_d + z_l: blocks [0,tiles) -> side a (f32 out), [tiles,2*tiles) -> b (bf16).
__global__ __launch_bounds__(512) void gemm1_dual_kernel(
    int tiles,
    const unsigned short* __restrict__ A1a, const unsigned short* __restrict__ A2a,
    const unsigned short* __restrict__ Wta, const float* __restrict__ ba,
    float* __restrict__ outa,
    const unsigned short* __restrict__ A1b, const unsigned short* __restrict__ A2b,
    const unsigned short* __restrict__ Wtb, const float* __restrict__ bb,
    unsigned short* __restrict__ outb)
{
  const int t = threadIdx.x, wv = t >> 6, lane = t & 63;
  const int l15 = lane & 15, l4 = lane >> 4;
  const bool sb = ((int)blockIdx.x >= tiles);
  const int tile = (int)blockIdx.x - (sb ? tiles : 0);
  const unsigned short* A1 = sb ? A1b : A1a;
  const unsigned short* A2 = sb ? A2b : A2a;
  const unsigned short* Wt = sb ? Wtb : Wta;
  const float* bias = sb ? bb : ba;
  bf16x8 Wr[12];
  #pragma unroll
  for (int ks = 0; ks < 12; ++ks)
    Wr[ks] = *(const bf16x8*)&Wt[((size_t)(ks * 4 + l4) * 128 + wv * 16 + l15) * 8];
  const int rw = tile * 32;
  bf16x8 ar[12][2];
  #pragma unroll
  for (int ks = 0; ks < 4; ++ks)
    #pragma unroll
    for (int rf = 0; rf < 2; ++rf)
      ar[ks][rf] = *(const bf16x8*)&A1[(size_t)(rw + rf * 16 + l15) * 128 + ks * 32 + l4 * 8];
  #pragma unroll
  for (int ks = 0; ks < 8; ++ks)
    #pragma unroll
    for (int rf = 0; rf < 2; ++rf)
      ar[4 + ks][rf] = *(const bf16x8*)&A2[(size_t)(rw + rf * 16 + l15) * 256 + ks * 32 + l4 * 8];
  f32x4 acc0 = {0.f,0.f,0.f,0.f}, acc1 = {0.f,0.f,0.f,0.f};
  #pragma unroll
  for (int ks = 0; ks < 12; ++ks){
    acc0 = MFMA(ar[ks][0], Wr[ks], acc0, 0, 0, 0);
    acc1 = MFMA(ar[ks][1], Wr[ks], acc1, 0, 0, 0);
  }
  const int col = wv * 16 + l15;
  const float bv = bias[col];
  #pragma unroll
  for (int rf = 0; rf < 2; ++rf){
    const f32x4 ac = rf ? acc1 : acc0;
    #pragma unroll
    for (int i = 0; i < 4; ++i){
      const size_t o = (size_t)(rw + rf * 16 + l4 * 4 + i) * 128 + col;
      const float v = fmaxf(ac[i] + bv, 0.f);
      if (sb) outb[o] = f2bf(v);
      else    outa[o] = v;
    }
  }
}

// Fused 4-way attention projection: blocks [0,tiles) -> topology head
// (ht16 @ a_dT|a_dG), [tiles,2*tiles) -> label head (me16 @ a_lT|a_lG).
__global__ __launch_bounds__(512) void gemm_proj4_kernel(
    int tiles,
    const unsigned short* __restrict__ Ad, const unsigned short* __restrict__ Al,
    const unsigned short* __restrict__ WdT, const unsigned short* __restrict__ WdG,
    const unsigned short* __restrict__ WlT, const unsigned short* __restrict__ WlG,
    float* __restrict__ oTd, float* __restrict__ oGd,
    float* __restrict__ oTl, float* __restrict__ oGl)
{
  const int t = threadIdx.x, wv = t >> 6, lane = t & 63;
  const int l15 = lane & 15, l4 = lane >> 4;
  const bool lab = ((int)blockIdx.x >= tiles);
  const int tile = (int)blockIdx.x - (lab ? tiles : 0);
  const unsigned short* A1  = lab ? Al  : Ad;
  const unsigned short* W1t = lab ? WlT : WdT;
  const unsigned short* W2t = lab ? WlG : WdG;
  float* out1 = lab ? oTl : oTd;
  float* out2 = lab ? oGl : oGd;
  bf16x8 W1r[4], W2r[4];
  #pragma unroll
  for (int ks = 0; ks < 4; ++ks){
    const size_t fo = ((size_t)(ks * 4 + l4) * 128 + wv * 16 + l15) * 8;
    W1r[ks] = *(const bf16x8*)&W1t[fo];
    W2r[ks] = *(const bf16x8*)&W2t[fo];
  }
  const int rw = tile * 32;
  bf16x8 a[4][2];
  #pragma unroll
  for (int ks = 0; ks < 4; ++ks)
    #pragma unroll
    for (int rf = 0; rf < 2; ++rf)
      a[ks][rf] = *(const bf16x8*)&A1[(size_t)(rw + rf * 16 + l15) * 128 + ks * 32 + l4 * 8];
  f32x4 p10 = {0.f,0.f,0.f,0.f}, p11 = {0.f,0.f,0.f,0.f};
  f32x4 p20 = {0.f,0.f,0.f,0.f}, p21 = {0.f,0.f,0.f,0.f};
  #pragma unroll
  for (int ks = 0; ks < 4; ++ks){
    p10 = MFMA(a[ks][0], W1r[ks], p10, 0, 0, 0);
    p20 = MFMA(a[ks][0], W2r[ks], p20, 0, 0, 0);
    p11 = MFMA(a[ks][1], W1r[ks], p11, 0, 0, 0);
    p21 = MFMA(a[ks][1], W2r[ks], p21, 0, 0, 0);
  }
  const int col = wv * 16 + l15;
  #pragma unroll
  for (int rf = 0; rf < 2; ++rf){
    const f32x4 c1 = rf ? p11 : p10;
    const f32x4 c2 = rf ? p21 : p20;
    #pragma unroll
    for (int i = 0; i < 4; ++i){
      const size_t o = (size_t)(rw + rf * 16 + l4 * 4 + i) * 128 + col;
      out1[o] = c1[i];
      out2[o] = c2[i];
    }
  }
}

// ---------------- CSR build (by lg_dst) ----------------

__global__ __launch_bounds__(256) void csr_count_kernel(
    const int* __restrict__ lg_dst, int ELG,
    int* __restrict__ cnt, int* __restrict__ ticket)
{
  const int e = blockIdx.x * 256 + threadIdx.x;
  if (e < ELG) ticket[e] = atomicAdd(&cnt[lg_dst[e]], 1);
}

#define SCAN_CHUNK 1024

__global__ __launch_bounds__(256) void scan_totals_kernel(
    const int* __restrict__ cnt, int n, int* __restrict__ bsum)
{
  __shared__ int red[256];
  const int base = blockIdx.x * SCAN_CHUNK;
  const int t = threadIdx.x;
  int s = 0;
  #pragma unroll
  for (int k = 0; k < 4; ++k){
    const int idx = base + t + k * 256;
    if (idx < n) s += cnt[idx];
  }
  red[t] = s; __syncthreads();
  for (int g = 128; g; g >>= 1){
    if (t < g) red[t] += red[t + g];
    __syncthreads();
  }
  if (t == 0) bsum[blockIdx.x] = red[0];
}

__global__ void scan_serial_kernel(int* bsum, int nb, int* offsets, int n)
{
  if (threadIdx.x == 0 && blockIdx.x == 0){
    int acc = 0;
    for (int i = 0; i < nb; ++i){ const int v = bsum[i]; bsum[i] = acc; acc += v; }
    offsets[n] = acc;
  }
}

__global__ __launch_bounds__(256) void scan_write_kernel(
    const int* __restrict__ cnt, int n,
    const int* __restrict__ bsum, int* __restrict__ offsets)
{
  __shared__ int wsum[4];
  const int base = blockIdx.x * SCAN_CHUNK;
  const int t = threadIdx.x;
  int v[4]; int lsum = 0;
  #pragma unroll
  for (int k = 0; k < 4; ++k){
    const int idx = base + t * 4 + k;
    v[k] = (idx < n) ? cnt[idx] : 0;
    lsum += v[k];
  }
  const int lane = t & 63, wv = t >> 6;
  int x = lsum;
  #pragma unroll
  for (int off = 1; off < 64; off <<= 1){
    const int y = __shfl_up(x, off, 64);
    if (lane >= off) x += y;
  }
  if (lane == 63) wsum[wv] = x;
  __syncthreads();
  int woff = 0;
  for (int i = 0; i < wv; ++i) woff += wsum[i];
  int run = x - lsum + woff + bsum[blockIdx.x];
  #pragma unroll
  for (int k = 0; k < 4; ++k){
    const int idx = base + t * 4 + k;
    if (idx < n) offsets[idx] = run;
    run += v[k];
  }
}

__global__ __launch_bounds__(256) void csr_fill_kernel(
    const int* __restrict__ lg_src, const int* __restrict__ lg_dst,
    const int* __restrict__ ticket, int ELG,
    const int* __restrict__ offsets, int* __restrict__ csr_src)
{
  const int e = blockIdx.x * 256 + threadIdx.x;
  if (e >= ELG) return;
  csr_src[offsets[lg_dst[e]] + ticket[e]] = lg_src[e];
}

// ---------------- CSR gathers (bf16 rows, f32 accumulate) ----------------

// compacted: s/srh at S1 rows only; sources via rank2 into compacted msg/R.
__global__ __launch_bounds__(256) void gather2_bf_kernel(
    const int* __restrict__ offsets, const int* __restrict__ csr_src,
    const int* __restrict__ cnt1p, const int* __restrict__ S1list,
    const int* __restrict__ rank2,
    const unsigned short* __restrict__ msg16c, const unsigned short* __restrict__ R16c,
    unsigned short* __restrict__ s16c, unsigned short* __restrict__ srh16c)
{
  const int total = (*cnt1p) * 16;
  for (int g = blockIdx.x * 256 + threadIdx.x; g < total; g += gridDim.x * 256){
    const int i = g >> 4, q = g & 15;
    const int v = S1list[i];
    const int beg = offsets[v], end = offsets[v + 1];
    float as[8] = {}, ar[8] = {};
    for (int j = beg; j < end; ++j){
      const int sc = rank2[csr_src[j]];
      acc8(as, *(const uint4*)&msg16c[(size_t)sc * 128 + q * 8]);
      acc8(ar, *(const uint4*)&R16c[(size_t)sc * 128 + q * 8]);
    }
    *(uint4*)&s16c[(size_t)i * 128 + q * 8] = pack8(as);
    *(uint4*)&srh16c[(size_t)i * 128 + q * 8] = pack8(ar);
  }
}

// eids gather: sum_h[eids] via CSR walk over compacted mn16c (rank1).
__global__ __launch_bounds__(256) void gather3_kernel(
    const int* __restrict__ eids, int B,
    const float* __restrict__ f_srcf, const unsigned short* __restrict__ mn16c,
    const int* __restrict__ rank1,
    const int* __restrict__ offsets, const int* __restrict__ csr_src,
    unsigned short* __restrict__ fs_e, unsigned short* __restrict__ sh_e,
    unsigned short* __restrict__ m_e)
{
  const int g = blockIdx.x * 256 + threadIdx.x;
  const int bI = g >> 4, q = g & 15;
  if (bI >= B) return;
  const int e = eids[bI];
  *(uint4*)&fs_e[(size_t)bI * 128 + q * 8] = cvt8(f_srcf + (size_t)e * 128 + q * 8);
  *(uint4*)&m_e [(size_t)bI * 128 + q * 8] =
      *(const uint4*)&mn16c[(size_t)rank1[e] * 128 + q * 8];
  const int beg = offsets[e], end = offsets[e + 1];
  float a[8] = {};
  for (int j = beg; j < end; ++j){
    const int sc = rank1[csr_src[j]];
    acc8(a, *(const uint4*)&mn16c[(size_t)sc * 128 + q * 8]);
  }
  *(uint4*)&sh_e[(size_t)bI * 128 + q * 8] = pack8(a);
}

// Fused per-graph attention (both heads, both node sets): blocks [0,B) -> x_T,
// [B,2B) -> x_G. Output stride 256; T cols [0,128), G cols [128,256).
// R28: pass2 reads one float2/lane (cols 2l,2l+1) and stores one packed u32.
__global__ __launch_bounds__(64) void attn2_kernel(
    const float* __restrict__ xT, int nTn,
    const float* __restrict__ xG, int nGn,
    const float* __restrict__ haTd, const float* __restrict__ haGd,
    const float* __restrict__ haTl, const float* __restrict__ haGl,
    unsigned short* __restrict__ out_d, unsigned short* __restrict__ out_l, int B)
{
  int b = blockIdx.x;
  const bool isG = (b >= B);
  if (isG) b -= B;
  const float* x  = isG ? xG : xT;
  const int n     = isG ? nGn : nTn;
  const float* ha_d = isG ? haGd : haTd;
  const float* ha_l = isG ? haGl : haTl;
  const int col_off = isG ? 128 : 0;
  const int l = threadIdx.x;
  __shared__ __align__(16) float hd[128], hl[128];
  __shared__ float pd[64], pl[64];
  hd[l]      = ha_d[(size_t)b * 128 + l];
  hd[l + 64] = ha_d[(size_t)b * 128 + 64 + l];
  hl[l]      = ha_l[(size_t)b * 128 + l];
  hl[l + 64] = ha_l[(size_t)b * 128 + 64 + l];
  __syncthreads();
  float ed = -1e30f, el = -1e30f;
  if (l < n){
    const float4* xr = (const float4*)(x + ((size_t)b * n + l) * 128);
    float sd = 0.f, sl = 0.f;
    #pragma unroll 8
    for (int k = 0; k < 32; ++k){
      const float4 xv = xr[k];
      const float4 hdv = *(const float4*)&hd[k * 4];
      const float4 hlv = *(const float4*)&hl[k * 4];
      sd += xv.x * hdv.x + xv.y * hdv.y + xv.z * hdv.z + xv.w * hdv.w;
      sl += xv.x * hlv.x + xv.y * hlv.y + xv.z * hlv.z + xv.w * hlv.w;
    }
    ed = sd; el = sl;
  }
  const float md = wave_max64(ed), ml = wave_max64(el);
  const float exd = (l < n) ? __expf(ed - md) : 0.f;
  const float exl = (l < n) ? __expf(el - ml) : 0.f;
  const float zd = wave_sum64(exd), zl = wave_sum64(exl);
  pd[l] = exd / zd;
  pl[l] = exl / zl;
  __syncthreads();
  float od0 = 0.f, od1 = 0.f, ol0 = 0.f, ol1 = 0.f;
  #pragma unroll 4
  for (int i = 0; i < n; ++i){
    const float2 xv = *(const float2*)(x + ((size_t)b * n + i) * 128 + 2 * l);
    const float wd = pd[i], wl = pl[i];
    od0 += wd * xv.x; od1 += wd * xv.y;
    ol0 += wl * xv.x; ol1 += wl * xv.y;
  }
  const size_t o = (size_t)b * 256 + col_off;
  *(unsigned*)&out_d[o + 2 * l] = pk2(f2bf(od0), f2bf(od1));
  *(unsigned*)&out_l[o + 2 * l] = pk2(f2bf(ol0), f2bf(ol1));
}

__global__ __launch_bounds__(256) void ce_topo_kernel(
    const float* __restrict__ z_d, const float* __restrict__ u_d,
    const float* __restrict__ b_d3, const float* __restrict__ expand,
    float* __restrict__ out, int B)
{
  const int r = blockIdx.x * 4 + (threadIdx.x >> 6);
  const int l = threadIdx.x & 63;
  if (r >= B) return;
  const float* row = z_d + (size_t)r * 128;
  float s = row[l] * u_d[l] + row[l + 64] * u_d[l + 64];
  s = wave_sum64(s);
  if (l == 0){
    const float p = s + b_d3[0];
    const float t = expand[r];
    const float loss = -(t * logsigf_(p) + (1.f - t) * logsigf_(1.f - p));
    atomicAdd(out, loss / (float)B);
  }
}

// ---------------- label CE via MFMA: 32 rows/block, all V cols ----------------
__global__ __launch_bounds__(512) void ce_label_mfma_kernel(
    const unsigned short* __restrict__ zl16,
    const unsigned short* __restrict__ ul,    // granule layout k8*V + col
    const float* __restrict__ b_l2, const int* __restrict__ wid,
    float* __restrict__ out, int B, int V)
{
  const int NF = V >> 4;
  const int t = threadIdx.x, wv = t >> 6, lane = t & 63;
  const int l15 = lane & 15, l4 = lane >> 4;
  const int rw = blockIdx.x * 32;
  __shared__ float redm[32][8];
  __shared__ float reds[32][8];
  __shared__ float rowm[32];
  __shared__ float tgt[32];

  bf16x8 a[4][2];
  #pragma unroll
  for (int ks = 0; ks < 4; ++ks)
    #pragma unroll
    for (int rf = 0; rf < 2; ++rf)
      a[ks][rf] = *(const bf16x8*)&zl16[(size_t)(rw + rf * 16 + l15) * 128 + ks * 32 + l4 * 8];

  f32x4 acc[7][2];
  #pragma unroll
  for (int j = 0; j < 7; ++j){
    acc[j][0] = (f32x4){0.f,0.f,0.f,0.f};
    acc[j][1] = (f32x4){0.f,0.f,0.f,0.f};
  }
  #pragma unroll
  for (int j = 0; j < 7; ++j){
    const int cf = wv + 8 * j;
    if (cf < NF){
      #pragma unroll
      for (int ks = 0; ks < 4; ++ks){
        const bf16x8 bf = *(const bf16x8*)&ul[((size_t)(ks * 4 + l4) * V + cf * 16 + l15) * 8];
        acc[j][0] = MFMA(a[ks][0], bf, acc[j][0], 0, 0, 0);
        acc[j][1] = MFMA(a[ks][1], bf, acc[j][1], 0, 0, 0);
      }
    }
  }
  float mloc[8];
  #pragma unroll
  for (int k = 0; k < 8; ++k) mloc[k] = -1e30f;
  #pragma unroll
  for (int j = 0; j < 7; ++j){
    const int cf = wv + 8 * j;
    if (cf < NF){
      const float bv = b_l2[cf * 16 + l15];
      #pragma unroll
      for (int rf = 0; rf < 2; ++rf)
        #pragma unroll
        for (int i = 0; i < 4; ++i){
          const float v = acc[j][rf][i] + bv;
          acc[j][rf][i] = v;
          mloc[rf * 4 + i] = fmaxf(mloc[rf * 4 + i], v);
        }
    }
  }
  #pragma unroll
  for (int m = 1; m < 16; m <<= 1)
    #pragma unroll
    for (int k = 0; k < 8; ++k)
      mloc[k] = fmaxf(mloc[k], __shfl_xor(mloc[k], m, 64));
  if (l15 == 0){
    #pragma unroll
    for (int rf = 0; rf < 2; ++rf)
      #pragma unroll
      for (int i = 0; i < 4; ++i)
        redm[rf * 16 + l4 * 4 + i][wv] = mloc[rf * 4 + i];
  }
  __syncthreads();
  if (t < 32){
    float m = redm[t][0];
    #pragma unroll
    for (int k = 1; k < 8; ++k) m = fmaxf(m, redm[t][k]);
    rowm[t] = m;
  }
  __syncthreads();
  float sloc[8];
  #pragma unroll
  for (int k = 0; k < 8; ++k) sloc[k] = 0.f;
  #pragma unroll
  for (int j = 0; j < 7; ++j){
    const int cf = wv + 8 * j;
    if (cf < NF){
      #pragma unroll
      for (int rf = 0; rf < 2; ++rf)
        #pragma unroll
        for (int i = 0; i < 4; ++i){
          const int lr = rf * 16 + l4 * 4 + i;
          const float v = acc[j][rf][i];
          sloc[rf * 4 + i] += __expf(v - rowm[lr]);
          if (cf * 16 + l15 == wid[rw + lr]) tgt[lr] = v;
        }
    }
  }
  #pragma unroll
  for (int m = 1; m < 16; m <<= 1)
    #pragma unroll
    for (int k = 0; k < 8; ++k)
      sloc[k] += __shfl_xor(sloc[k], m, 64);
  if (l15 == 0){
    #pragma unroll
    for (int rf = 0; rf < 2; ++rf)
      #pragma unroll
      for (int i = 0; i < 4; ++i)
        reds[rf * 16 + l4 * 4 + i][wv] = sloc[rf * 4 + i];
  }
  __syncthreads();
  if (t < 32){
    float s = 0.f;
    #pragma unroll
    for (int k = 0; k < 8; ++k) s += reds[t][k];
    const float lp = tgt[t] - rowm[t] - __logf(s);
    atomicAdd(out + 1, -lp / (float)B);
  }
}

extern "C" void kernel_launch(void* const* d_in, const int* in_sizes, int n_in,
                              void* d_out, int out_size, void* d_ws, size_t ws_size,
                              hipStream_t stream)
{
  const float* msg    = (const float*)d_in[0];
  const float* f_src  = (const float*)d_in[1];
  const float* f_dst  = (const float*)d_in[2];
  const float* x_T    = (const float*)d_in[3];
  const float* x_G    = (const float*)d_in[4];
  const float* expand = (const float*)d_in[5];
  const float* wz = (const float*)d_in[6];
  const float* uz = (const float*)d_in[7];
  const float* bz = (const float*)d_in[8];
  const float* wr = (const float*)d_in[9];
  const float* ur = (const float*)d_in[10];
  const float* br = (const float*)d_in[11];
  const float* w  = (const float*)d_in[12];
  const float* u  = (const float*)d_in[13];
  const float* b  = (const float*)d_in[14];
  const float* w_d1 = (const float*)d_in[15];
  const float* w_d2 = (const float*)d_in[16];
  const float* b_d1 = (const float*)d_in[17];
  const float* a_dT = (const float*)d_in[18];
  const float* a_dG = (const float*)d_in[19];
  const float* w_d3 = (const float*)d_in[20];
  const float* w_d4 = (const float*)d_in[21];
  const float* b_d2 = (const float*)d_in[22];
  const float* u_d  = (const float*)d_in[23];
  const float* b_d3 = (const float*)d_in[24];
  const float* w_l1 = (const float*)d_in[25];
  const float* w_l2 = (const float*)d_in[26];
  const float* b_l1 = (const float*)d_in[27];
  const float* a_lT = (const float*)d_in[28];
  const float* a_lG = (const float*)d_in[29];
  const float* u_l  = (const float*)d_in[30];
  const float* b_l2 = (const float*)d_in[31];
  const int* lg_src = (const int*)d_in[32];
  const int* lg_dst = (const int*)d_in[33];
  const int* eids   = (const int*)d_in[34];
  const int* wid    = (const int*)d_in[35];

  const int d = 128;
  const int E   = in_sizes[0] / d;
  const int ELG = in_sizes[32];
  const int B   = in_sizes[34];
  const int V   = in_sizes[31];
  const int nT  = (in_sizes[3] / d) / B;
  const int nG  = (in_sizes[4] / d) / B;

  const size_t EH = (size_t)E * d * sizeof(unsigned short);
  const size_t BH = (size_t)B * d * sizeof(unsigned short);
  const size_t BF = (size_t)B * d * sizeof(float);
  char* p = (char*)d_ws;
  unsigned short* bufA = (unsigned short*)p; p += EH;  // R16c -> mn16c
  unsigned short* bufB = (unsigned short*)p; p += EH;  // s16c
  unsigned short* srh16 = (unsigned short*)p; p += EH; // srh16c
  unsigned short* msg16 = (unsigned short*)p; p += EH; // msg16c
  unsigned short* R16 = bufA, *mn16 = bufA;
  unsigned short* s16 = bufB;
  unsigned short* fse16 = (unsigned short*)p; p += BH;
  unsigned short* she16 = (unsigned short*)p; p += BH;
  unsigned short* me16  = (unsigned short*)p; p += BH;
  unsigned short* ht16  = (unsigned short*)p; p += BH;
  unsigned short* cd16  = (unsigned short*)p; p += 2 * BH;
  unsigned short* cl16  = (unsigned short*)p; p += 2 * BH;
  unsigned short* zl16  = (unsigned short*)p; p += BH;
  float* haTd = (float*)p; p += BF;
  float* haGd = (float*)p; p += BF;
  float* haTl = (float*)p; p += BF;
  float* haGl = (float*)p; p += BF;
  float* z_d  = (float*)p; p += BF;
  // CSR scratch
  int* cnt     = (int*)p; p += (size_t)E * sizeof(int);
  int* offsets = (int*)p; p += (size_t)(E + 1) * sizeof(int);
  int* ticket  = (int*)p; p += (size_t)ELG * sizeof(int);
  int* csr_src = (int*)p; p += (size_t)ELG * sizeof(int);
  int* bsum    = (int*)p; p += (size_t)((E + SCAN_CHUNK - 1) / SCAN_CHUNK + 1) * sizeof(int);
  // active-set scratch (R26)
  int* flag1  = (int*)p; p += (size_t)E * sizeof(int);
  int* flag2  = (int*)p; p += (size_t)E * sizeof(int);
  int* cnts   = (int*)p; p += 2 * sizeof(int);
  int* S1list = (int*)p; p += (size_t)(E + 128) * sizeof(int);
  int* S2list = (int*)p; p += (size_t)(E + 128) * sizeof(int);
  int* rank1  = (int*)p; p += (size_t)E * sizeof(int);
  int* rank2  = (int*)p; p += (size_t)E * sizeof(int);
  // bf16 fragment-layout weights
  p = (char*)(((size_t)p + 255) & ~(size_t)255);
  unsigned short* wt = (unsigned short*)p; p += 294912 * sizeof(unsigned short);
  p = (char*)(((size_t)p + 255) & ~(size_t)255);
  unsigned short* wt_ul = (unsigned short*)p; p += (size_t)128 * V * sizeof(unsigned short);

  hipMemsetAsync(cnt, 0, (size_t)E * sizeof(int), stream);
  hipMemsetAsync(flag1, 0, 2 * (size_t)E * sizeof(int), stream);  // flag1+flag2
  hipMemsetAsync(cnts, 0, 2 * sizeof(int), stream);
  hipMemsetAsync(d_out, 0, 2 * sizeof(float), stream);

  const int nb = (E + SCAN_CHUNK - 1) / SCAN_CHUNK;
  const int tilesB = B / 32;
  const int ublocks = (16 * V + 255) / 256;
  const int wblocks = (ublocks > 24) ? ublocks : 24;

  // weights -> bf16 fragment layout (y<10: panels; y==10: u_l)
  wprep_kernel<<<dim3(wblocks, 11), 256, 0, stream>>>(
      wr, ur, wz, uz, w, u, w_d1, w_d2, a_dT, a_dG, a_lT, a_lG,
      w_d3, w_d4, w_l1, w_l2, wt, u_l, wt_ul, V);

  // ---- CSR build (by lg_dst) ----
  csr_count_kernel<<<(ELG + 255) / 256, 256, 0, stream>>>(lg_dst, ELG, cnt, ticket);
  scan_totals_kernel<<<nb, 256, 0, stream>>>(cnt, E, bsum);
  scan_serial_kernel<<<1, 64, 0, stream>>>(bsum, nb, offsets, E);
  scan_write_kernel<<<nb, 256, 0, stream>>>(cnt, E, bsum, offsets);
  csr_fill_kernel<<<(ELG + 255) / 256, 256, 0, stream>>>(lg_src, lg_dst, ticket, ELG, offsets, csr_src);

  // ---- active sets: S1 = eids + their sources; S2 = sources of S1 ----
  mark1_kernel<<<(B + 255) / 256, 256, 0, stream>>>(eids, B, offsets, csr_src, flag1);
  compact_kernel<<<(E + 255) / 256, 256, 0, stream>>>(flag1, E, S1list, rank1, cnts + 0);
  mark2_kernel<<<512, 256, 0, stream>>>(cnts + 0, S1list, offsets, csr_src, flag2);
  compact_kernel<<<(E + 255) / 256, 256, 0, stream>>>(flag2, E, S2list, rank2, cnts + 1);
  pad_kernel<<<1, 64, 0, stream>>>(cnts + 0, S1list, cnts + 1, S2list);

  // R = sigmoid(f_dst@wr + msg@ur + br) * msg at S2 rows -> R16c, msg16c
  gemm_r_kernel<<<512, 512, 0, stream>>>(
      cnts + 1, S2list, f_dst, msg, wt + 0, br, R16, msg16);
  // s/srh segsums at S1 rows (compacted, sources via rank2)
  gather2_bf_kernel<<<2048, 256, 0, stream>>>(
      offsets, csr_src, cnts + 0, S1list, rank2, msg16, R16, s16, srh16);
  // msg_new at S1 rows -> mn16c
  gemm_zh_kernel<<<256, 512, 0, stream>>>(
      cnts + 0, S1list, f_src, s16, srh16, wt + 32768, wt + 65536, bz, b, mn16);
  // eids gathers incl. sum_h[eids] via CSR walk over mn16c
  gather3_kernel<<<(B * 16 + 255) / 256, 256, 0, stream>>>(
      eids, B, f_src, mn16, rank1, offsets, csr_src, fse16, she16, me16);
  // h_t = relu(fs_e@w_d1 + sh_e@w_d2 + b_d1)   -> ht16
  gemm1_kernel<4, 4, EPI_RELU, true><<<tilesB, 512, 0, stream>>>(
      tilesB, fse16, she16, wt + 98304, b_d1, ht16);
  // all four attention projections in one full-CU launch
  gemm_proj4_kernel<<<2 * tilesB, 512, 0, stream>>>(
      tilesB, ht16, me16,
      wt + 131072, wt + 147456, wt + 163840, wt + 180224,
      haTd, haGd, haTl, haGl);
  // fused attention: 1 graph/block (R28 revert), float2 pass2
  attn2_kernel<<<2 * B, 64, 0, stream>>>(
      x_T, nT, x_G, nG, haTd, haGd, haTl, haGl, cd16, cl16, B);
  // z_d (f32) + z_l (bf16) in one full-CU launch
  gemm1_dual_kernel<<<2 * tilesB, 512, 0, stream>>>(
      tilesB,
      ht16, cd16, wt + 196608, b_d2, z_d,
      me16, cl16, wt + 245760, b_l1, zl16);
  // losses
  ce_topo_kernel<<<(B + 3) / 4, 256, 0, stream>>>(z_d, u_d, b_d3, expand, (float*)d_out, B);
  ce_label_mfma_kernel<<<B / 32, 512, 0, stream>>>(zl16, wt_ul, b_l2, wid,
                                                   (float*)d_out, B, V);
}

// Round 29
// 378.312 us; speedup vs baseline: 1.0795x; 1.0305x over previous
//
#include <hip/hip_runtime.h>
#include <math.h>

// G2GDecoder forward: TreeGRU over line graph + topology/label heads.
// R2: CSR gathers. R5: bf16 MFMA. R11: MFMA label-CE. R15-R21: persistent-W
// E-GEMMs, T14 split staging, XOR-swizzled A-rings. R24: tail fusion.
// R25/R26: active-set sparsification (S1/S2, ~5-10% of E).
// R29: attn2 via LDS. Phase 1 was a worst-case gather (lane=row: 64 cache
// lines per instr); phase 2 re-read x. Now stage x once, coalesced
// (phase-2 pattern), into xs[64][130] (stride 130: staging writes,
// phase-2 reads, and phase-1 2xfloat2 reads all ~2-way = free), and run
// both phases from LDS. One coalesced global pass; identical f32 math.

using bf16x8 = __attribute__((ext_vector_type(8))) short;
using f32x4  = __attribute__((ext_vector_type(4))) float;

#define MFMA __builtin_amdgcn_mfma_f32_16x16x32_bf16

__device__ inline float wave_sum64(float v){
  #pragma unroll
  for (int m = 32; m; m >>= 1) v += __shfl_xor(v, m, 64);
  return v;
}
__device__ inline float wave_max64(float v){
  #pragma unroll
  for (int m = 32; m; m >>= 1) v = fmaxf(v, __shfl_xor(v, m, 64));
  return v;
}
__device__ inline float sigmoidf_(float x){ return 1.f / (1.f + __expf(-x)); }
__device__ inline float tanh_fast(float x){
  x = fminf(fmaxf(x, -15.f), 15.f);
  float e = __expf(2.f * x);
  return (e - 1.f) / (e + 1.f);
}
__device__ inline float logsigf_(float x){
  return (x >= 0.f) ? -log1pf(__expf(-x)) : (x - log1pf(__expf(x)));
}
__device__ inline unsigned short f2bf(float f){
  union { float f; unsigned u; } v; v.f = f;
  const unsigned r = v.u + 0x7FFF + ((v.u >> 16) & 1);   // RNE
  return (unsigned short)(r >> 16);
}
__device__ inline float bf2f(unsigned short u){
  union { unsigned u; float f; } v; v.u = ((unsigned)u) << 16; return v.f;
}
__device__ inline unsigned pk2(unsigned short a, unsigned short b){
  return (unsigned)a | ((unsigned)b << 16);
}
__device__ inline uint4 cvt8v(float4 x0, float4 x1){
  uint4 o;
  o.x = pk2(f2bf(x0.x), f2bf(x0.y)); o.y = pk2(f2bf(x0.z), f2bf(x0.w));
  o.z = pk2(f2bf(x1.x), f2bf(x1.y)); o.w = pk2(f2bf(x1.z), f2bf(x1.w));
  return o;
}
__device__ inline uint4 cvt8(const float* __restrict__ p){
  return cvt8v(*(const float4*)(p), *(const float4*)(p + 4));
}
__device__ inline void acc8(float* a, uint4 v){
  a[0] += bf2f(v.x & 0xffff); a[1] += bf2f(v.x >> 16);
  a[2] += bf2f(v.y & 0xffff); a[3] += bf2f(v.y >> 16);
  a[4] += bf2f(v.z & 0xffff); a[5] += bf2f(v.z >> 16);
  a[6] += bf2f(v.w & 0xffff); a[7] += bf2f(v.w >> 16);
}
__device__ inline uint4 pack8(const float* a){
  uint4 o;
  o.x = pk2(f2bf(a[0]), f2bf(a[1])); o.y = pk2(f2bf(a[2]), f2bf(a[3]));
  o.z = pk2(f2bf(a[4]), f2bf(a[5])); o.w = pk2(f2bf(a[6]), f2bf(a[7]));
  return o;
}

enum { EPI_NONE = 0, EPI_SIGMOID = 1, EPI_RELU = 2 };

// ------- weight prep: f32 [k][col] -> bf16 fragment granule layout ---------
// blockIdx.y in [0,10): gate/head panels -> wt. blockIdx.y == 10: u_l -> wt_ul.
__global__ __launch_bounds__(256) void wprep_kernel(
    const float* wr, const float* ur, const float* wz, const float* uz,
    const float* w,  const float* u,  const float* w_d1, const float* w_d2,
    const float* a_dT, const float* a_dG, const float* a_lT, const float* a_lG,
    const float* w_d3, const float* w_d4, const float* w_l1, const float* w_l2,
    unsigned short* __restrict__ wt,
    const float* __restrict__ u_l, unsigned short* __restrict__ wt_ul, int V)
{
  const int m = blockIdx.y;
  const int tid = blockIdx.x * 256 + threadIdx.x;
  if (m == 10){
    if (tid >= 16 * V) return;
    const int col = tid % V, k8 = tid / V;
    unsigned short v[8];
    #pragma unroll
    for (int i = 0; i < 8; ++i)
      v[i] = f2bf(u_l[(size_t)(k8 * 8 + i) * V + col]);
    uint4 pk;
    pk.x = pk2(v[0], v[1]); pk.y = pk2(v[2], v[3]);
    pk.z = pk2(v[4], v[5]); pk.w = pk2(v[6], v[7]);
    *(uint4*)&wt_ul[((size_t)k8 * V + col) * 8] = pk;
    return;
  }
  const float* s1; const float* s2; int K1, Ktot; size_t off;
  switch (m){
    case 0: s1 = wr;   s2 = ur;   K1 = 128; Ktot = 256; off = 0;      break;
    case 1: s1 = wz;   s2 = uz;   K1 = 128; Ktot = 256; off = 32768;  break;
    case 2: s1 = w;    s2 = u;    K1 = 128; Ktot = 256; off = 65536;  break;
    case 3: s1 = w_d1; s2 = w_d2; K1 = 128; Ktot = 256; off = 98304;  break;
    case 4: s1 = a_dT; s2 = nullptr; K1 = 128; Ktot = 128; off = 131072; break;
    case 5: s1 = a_dG; s2 = nullptr; K1 = 128; Ktot = 128; off = 147456; break;
    case 6: s1 = a_lT; s2 = nullptr; K1 = 128; Ktot = 128; off = 163840; break;
    case 7: s1 = a_lG; s2 = nullptr; K1 = 128; Ktot = 128; off = 180224; break;
    case 8: s1 = w_d3; s2 = w_d4; K1 = 128; Ktot = 384; off = 196608; break;
    default:s1 = w_l1; s2 = w_l2; K1 = 128; Ktot = 384; off = 245760; break;
  }
  if (tid >= 16 * Ktot) return;
  const int col = tid & 127, k8 = tid >> 7;
  unsigned short v[8];
  #pragma unroll
  for (int i = 0; i < 8; ++i){
    const int k = k8 * 8 + i;
    const float* s = (k < K1) ? (s1 + (size_t)k * 128 + col)
                              : (s2 + (size_t)(k - K1) * 128 + col);
    v[i] = f2bf(*s);
  }
  uint4 pk;
  pk.x = pk2(v[0], v[1]); pk.y = pk2(v[2], v[3]);
  pk.z = pk2(v[4], v[5]); pk.w = pk2(v[6], v[7]);
  *(uint4*)&wt[off + ((size_t)k8 * 128 + col) * 8] = pk;
}

// ---------------- active-set construction ----------------
__global__ __launch_bounds__(256) void mark1_kernel(
    const int* __restrict__ eids, int B,
    const int* __restrict__ offsets, const int* __restrict__ csr_src,
    int* __restrict__ flag1)
{
  const int b = blockIdx.x * 256 + threadIdx.x;
  if (b >= B) return;
  const int e = eids[b];
  flag1[e] = 1;
  const int beg = offsets[e], end = offsets[e + 1];
  for (int j = beg; j < end; ++j) flag1[csr_src[j]] = 1;
}

__global__ __launch_bounds__(256) void compact_kernel(
    const int* __restrict__ flag, int E,
    int* __restrict__ list, int* __restrict__ rank, int* __restrict__ cnt)
{
  const int v = blockIdx.x * 256 + threadIdx.x;
  if (v >= E || !flag[v]) return;
  const int pos = atomicAdd(cnt, 1);
  list[pos] = v;
  rank[v] = pos;
}

__global__ __launch_bounds__(256) void mark2_kernel(
    const int* __restrict__ cnt1p, const int* __restrict__ S1list,
    const int* __restrict__ offsets, const int* __restrict__ csr_src,
    int* __restrict__ flag2)
{
  const int n = *cnt1p;
  for (int i = blockIdx.x * 256 + threadIdx.x; i < n; i += gridDim.x * 256){
    const int v = S1list[i];
    const int beg = offsets[v], end = offsets[v + 1];
    for (int j = beg; j < end; ++j) flag2[csr_src[j]] = 1;
  }
}

// pad counts up to tile multiples (S1: 128, S2: 64), filling with list[0]
__global__ void pad_kernel(int* cnt1, int* S1list, int* cnt2, int* S2list)
{
  if (threadIdx.x == 0 && blockIdx.x == 0){
    int c1 = *cnt1;
    if (c1 > 0){
      const int p1 = (c1 + 127) & ~127;
      for (int i = c1; i < p1; ++i) S1list[i] = S1list[0];
      *cnt1 = p1;
    }
    int c2 = *cnt2;
    if (c2 > 0){
      const int p2 = (c2 + 63) & ~63;
      for (int i = c2; i < p2; ++i) S2list[i] = S2list[0];
      *cnt2 = p2;
    }
  }
}

// ---------------- persistent-W R-GEMM over S2 (compacted rows) -------------
// 64-row tiles, K-chunk 64; T14 split staging, ring-2 XOR-swizzled.
__global__ __launch_bounds__(512, 2) void gemm_r_kernel(
    const int* __restrict__ cnt2p, const int* __restrict__ S2list,
    const float* __restrict__ A1f,     // f_dst
    const float* __restrict__ A2f,     // msg
    const unsigned short* __restrict__ Wt,
    const float* __restrict__ bias,
    unsigned short* __restrict__ out,  // R16c (compacted)
    unsigned short* __restrict__ out2) // msg16c (compacted)
{
  __shared__ unsigned short Wl[32768];   // 64KB persistent W panel
  __shared__ unsigned short Ar[2][4096]; // 8KB slots: 64 rows x 8 granules (swz)
  const int t = threadIdx.x;
  const int lane = t & 63, wid = t >> 6;
  const int l15 = lane & 15, l4 = lane >> 4;
  const int wr = wid >> 1, wc = wid & 1;   // 4 row-grp x 2 col-grp

  const int tiles = (*cnt2p) >> 6;
  const int nT = (tiles - (int)blockIdx.x + (int)gridDim.x - 1) / (int)gridDim.x;
  if (nT <= 0) return;

  #pragma unroll
  for (int i = 0; i < 8; ++i)
    ((uint4*)Wl)[i * 512 + t] = ((const uint4*)Wt)[i * 512 + t];

  const int totalG = nT * 4;   // 4 K-chunks per tile

  float4 ra, rb;   // in-flight staged data (raw f32, all 512 threads)

  auto loadA = [&](int gs){
    const int tile = (int)blockIdx.x + (gs >> 2) * (int)gridDim.x;
    const int cs = gs & 3;
    const size_t grow = (size_t)S2list[tile * 64 + (t >> 3)];
    const int q8 = (t & 7) * 8;
    const float* src = (cs < 2) ? (A1f + grow * 128 + cs * 64 + q8)
                                : (A2f + grow * 128 + (cs - 2) * 64 + q8);
    ra = *(const float4*)(src);
    rb = *(const float4*)(src + 4);
  };
  auto writeA = [&](int slot, int gs){
    const uint4 o = cvt8v(ra, rb);
    const int rrow = t >> 3, qq = t & 7;
    *(uint4*)&Ar[slot][((rrow << 3) | (qq ^ (rrow & 7))) * 8] = o;
    const int cs = gs & 3;
    if (cs >= 2){
      const int tile = (int)blockIdx.x + (gs >> 2) * (int)gridDim.x;
      const size_t crow = (size_t)tile * 64 + rrow;
      *(uint4*)&out2[crow * 128 + (cs - 2) * 64 + qq * 8] = o;
    }
  };

  loadA(0); writeA(0, 0);
  if (totalG > 1) loadA(1);

  for (int m = 0; m < nT; ++m){
    const int tile = (int)blockIdx.x + m * (int)gridDim.x;
    f32x4 acc[4];
    #pragma unroll
    for (int cf = 0; cf < 4; ++cf) acc[cf] = (f32x4){0.f,0.f,0.f,0.f};
    #pragma unroll
    for (int cs = 0; cs < 4; ++cs){
      const int g = m * 4 + cs;
      __syncthreads();
      if (g + 1 < totalG) writeA((g + 1) & 1, g + 1);  // regs from prev load
      if (g + 2 < totalG) loadA(g + 2);                // issue ahead
      const unsigned short* S = Ar[g & 1];
      const int arow = wr * 16 + l15;
      #pragma unroll
      for (int kk = 0; kk < 2; ++kk){
        const int qq = (kk * 4 + l4) ^ (arow & 7);
        const bf16x8 a = *(const bf16x8*)&S[((arow << 3) | qq) * 8];
        #pragma unroll
        for (int cf = 0; cf < 4; ++cf){
          const int wg = (((cs * 2 + kk) * 4 + l4) * 128 + wc * 64 + cf * 16 + l15) * 8;
          acc[cf] = MFMA(a, *(const bf16x8*)&Wl[wg], acc[cf], 0, 0, 0);
        }
      }
    }
    int growv[4];
    #pragma unroll
    for (int i = 0; i < 4; ++i)
      growv[i] = S2list[tile * 64 + wr * 16 + l4 * 4 + i];
    #pragma unroll
    for (int cf = 0; cf < 4; ++cf){
      const int col = wc * 64 + cf * 16 + l15;
      const float bv = bias[col];
      #pragma unroll
      for (int i = 0; i < 4; ++i){
        const size_t oc = ((size_t)tile * 64 + wr * 16 + l4 * 4 + i) * 128 + col;
        out[oc] = f2bf(sigmoidf_(acc[cf][i] + bv) * A2f[(size_t)growv[i] * 128 + col]);
      }
    }
  }
}

// ---------------- persistent-W merged Z+H GEMM over S1 (compacted) ---------
// 128-row tiles. LDS: 128KB W + 2x16KB ring = 160KB.
__global__ __launch_bounds__(512, 2) void gemm_zh_kernel(
    const int* __restrict__ cnt1p, const int* __restrict__ S1list,
    const float* __restrict__ fsrc,
    const unsigned short* __restrict__ s16,    // compacted
    const unsigned short* __restrict__ srh16,  // compacted
    const unsigned short* __restrict__ Wz,
    const unsigned short* __restrict__ Wh,
    const float* __restrict__ bz, const float* __restrict__ bh,
    unsigned short* __restrict__ out)          // mn16c compacted
{
  __shared__ unsigned short Wl[65536];   // Wz | Wh, 128KB persistent
  __shared__ unsigned short Ar[2][8192]; // 16KB slots: [0:4096)=z, [4096:8192)=h
  const int t = threadIdx.x;
  const int lane = t & 63, wid = t >> 6;
  const int l15 = lane & 15, l4 = lane >> 4;
  const int wr = wid >> 1, wc = wid & 1;

  const int tiles = (*cnt1p) >> 7;
  const int nT = (tiles - (int)blockIdx.x + (int)gridDim.x - 1) / (int)gridDim.x;
  if (nT <= 0) return;

  #pragma unroll
  for (int i = 0; i < 8; ++i){
    ((uint4*)Wl)[i * 512 + t]        = ((const uint4*)Wz)[i * 512 + t];
    ((uint4*)Wl)[4096 + i * 512 + t] = ((const uint4*)Wh)[i * 512 + t];
  }

  const int totalG = nT * 8;

  float4 ra, rb;   // phase1: raw f32; phase2: ra=s16 bits, rb=srh16 bits

  auto loadA = [&](int gs){
    const int tile = (int)blockIdx.x + (gs >> 3) * (int)gridDim.x;
    const int ks = gs & 7;
    const int crow = tile * 128 + (t >> 2);
    const int q8 = (t & 3) * 8;
    if (ks < 4){
      const size_t grow = (size_t)S1list[crow];
      const float* src = fsrc + grow * 128 + ks * 32 + q8;
      ra = *(const float4*)(src);
      rb = *(const float4*)(src + 4);
    } else {
      const uint4 v1 = *(const uint4*)&s16[(size_t)crow * 128 + (ks - 4) * 32 + q8];
      const uint4 v2 = *(const uint4*)&srh16[(size_t)crow * 128 + (ks - 4) * 32 + q8];
      ra = *(const float4*)&v1;
      rb = *(const float4*)&v2;
    }
  };
  auto writeA = [&](int slot, int gs){
    const int ks = gs & 7;
    const int rrow = t >> 2, qq = t & 3;
    const int gsw = ((rrow << 2) | (qq ^ ((rrow >> 1) & 3))) * 8;
    if (ks < 4){
      *(uint4*)&Ar[slot][gsw] = cvt8v(ra, rb);
    } else {
      *(uint4*)&Ar[slot][gsw]        = *(const uint4*)&ra;
      *(uint4*)&Ar[slot][4096 + gsw] = *(const uint4*)&rb;
    }
  };

  loadA(0); writeA(0, 0);
  if (totalG > 1) loadA(1);

  for (int m = 0; m < nT; ++m){
    const int tile = (int)blockIdx.x + m * (int)gridDim.x;
    f32x4 az0[4], az1[4], ah0[4], ah1[4];
    #pragma unroll
    for (int cf = 0; cf < 4; ++cf){
      az0[cf] = (f32x4){0.f,0.f,0.f,0.f}; az1[cf] = (f32x4){0.f,0.f,0.f,0.f};
      ah0[cf] = (f32x4){0.f,0.f,0.f,0.f}; ah1[cf] = (f32x4){0.f,0.f,0.f,0.f};
    }
    #pragma unroll
    for (int ks = 0; ks < 8; ++ks){
      const int g = m * 8 + ks;
      __syncthreads();
      if (g + 1 < totalG) writeA((g + 1) & 1, g + 1);
      if (g + 2 < totalG) loadA(g + 2);
      const unsigned short* S = Ar[g & 1];
      const int r0 = wr * 32 + l15, r1 = wr * 32 + 16 + l15;
      const int ag0 = ((r0 << 2) | (l4 ^ ((r0 >> 1) & 3))) * 8;
      const int ag1 = ((r1 << 2) | (l4 ^ ((r1 >> 1) & 3))) * 8;
      const bf16x8 az_a0 = *(const bf16x8*)&S[ag0];
      const bf16x8 az_a1 = *(const bf16x8*)&S[ag1];
      const bf16x8 ah_a0 = (ks < 4) ? az_a0 : *(const bf16x8*)&S[4096 + ag0];
      const bf16x8 ah_a1 = (ks < 4) ? az_a1 : *(const bf16x8*)&S[4096 + ag1];
      #pragma unroll
      for (int cf = 0; cf < 4; ++cf){
        const int wg = ((ks * 4 + l4) * 128 + wc * 64 + cf * 16 + l15) * 8;
        const bf16x8 w1 = *(const bf16x8*)&Wl[wg];
        const bf16x8 w2 = *(const bf16x8*)&Wl[32768 + wg];
        az0[cf] = MFMA(az_a0, w1, az0[cf], 0, 0, 0);
        az1[cf] = MFMA(az_a1, w1, az1[cf], 0, 0, 0);
        ah0[cf] = MFMA(ah_a0, w2, ah0[cf], 0, 0, 0);
        ah1[cf] = MFMA(ah_a1, w2, ah1[cf], 0, 0, 0);
      }
    }
    #pragma unroll
    for (int cf = 0; cf < 4; ++cf){
      const int col = wc * 64 + cf * 16 + l15;
      const float bvz = bz[col], bvh = bh[col];
      #pragma unroll
      for (int rf = 0; rf < 2; ++rf){
        const f32x4 zc = rf ? az1[cf] : az0[cf];
        const f32x4 hc = rf ? ah1[cf] : ah0[cf];
        #pragma unroll
        for (int i = 0; i < 4; ++i){
          const size_t o = ((size_t)tile * 128 + wr * 32 + rf * 16 + l4 * 4 + i) * 128 + col;
          const float z = sigmoidf_(zc[i] + bvz);
          const float h = tanh_fast(hc[i] + bvh);
          out[o] = f2bf((1.f - z) * bf2f(s16[o]) + z * h);
        }
      }
    }
  }
}

// ---------------- B-path GEMMs (register-W, small) ----------------
template<int KS1, int KS2, int EPI, bool OB16>
__global__ __launch_bounds__(512) void gemm1_kernel(
    int tiles,
    const unsigned short* __restrict__ A1,
    const unsigned short* __restrict__ A2,
    const unsigned short* __restrict__ Wt,
    const float* __restrict__ bias,
    void* __restrict__ outv)
{
  const int t = threadIdx.x, wv = t >> 6, lane = t & 63;
  const int l15 = lane & 15, l4 = lane >> 4;
  constexpr int KS = KS1 + KS2;
  bf16x8 Wr[KS];
  #pragma unroll
  for (int ks = 0; ks < KS; ++ks)
    Wr[ks] = *(const bf16x8*)&Wt[((size_t)(ks * 4 + l4) * 128 + wv * 16 + l15) * 8];
  for (int tile = blockIdx.x; tile < tiles; tile += gridDim.x){
    const int rw = tile * 32;
    bf16x8 ar[KS][2];
    #pragma unroll
    for (int ks = 0; ks < KS1; ++ks)
      #pragma unroll
      for (int rf = 0; rf < 2; ++rf)
        ar[ks][rf] = *(const bf16x8*)&A1[(size_t)(rw + rf * 16 + l15) * (KS1 * 32) + ks * 32 + l4 * 8];
    #pragma unroll
    for (int ks = 0; ks < KS2; ++ks)
      #pragma unroll
      for (int rf = 0; rf < 2; ++rf)
        ar[KS1 + ks][rf] = *(const bf16x8*)&A2[(size_t)(rw + rf * 16 + l15) * (KS2 * 32) + ks * 32 + l4 * 8];
    f32x4 acc0 = {0.f,0.f,0.f,0.f}, acc1 = {0.f,0.f,0.f,0.f};
    #pragma unroll
    for (int ks = 0; ks < KS; ++ks){
      acc0 = MFMA(ar[ks][0], Wr[ks], acc0, 0, 0, 0);
      acc1 = MFMA(ar[ks][1], Wr[ks], acc1, 0, 0, 0);
    }
    const int col = wv * 16 + l15;
    const float bv = bias ? bias[col] : 0.f;
    #pragma unroll
    for (int rf = 0; rf < 2; ++rf){
      const f32x4 ac = rf ? acc1 : acc0;
      #pragma unroll
      for (int i = 0; i < 4; ++i){
        const size_t o = (size_t)(rw + rf * 16 + l4 * 4 + i) * 128 + col;
        float v = ac[i] + bv;
        if (EPI == EPI_RELU)         v = fmaxf(v, 0.f);
        else if (EPI == EPI_SIGMOID) v = sigmoidf_(v);
        if (OB16) ((unsigned short*)outv)[o] = f2bf(v);
        else      ((float*)outv)[o] = v;
      }
    }
  }
}

// Fused z_d + z_l: blocks [0,tiles) -> side a (f32 out), [tiles,2*tiles) -> b (bf16).
__global__ __launch_bounds__(512) void gemm1_dual_kernel(
    int tiles,
    const unsigned short* __restrict__ A1a, const unsigned short* __restrict__ A2a,
    const unsigned short* __restrict__ Wta, const float* __restrict__ ba,
    float* __restrict__ outa,
    const unsigned short* __restrict__ A1b, const unsigned short* __restrict__ A2b,
    const unsigned short* __restrict__ Wtb, const float* __restrict__ bb,
    unsigned short* __restrict__ outb)
{
  const int t = threadIdx.x, wv = t >> 6, lane = t & 63;
  const int l15 = lane & 15, l4 = lane >> 4;
  const bool sb = ((int)blockIdx.x >= tiles);
  const int tile = (int)blockIdx.x - (sb ? tiles : 0);
  const unsigned short* A1 = sb ? A1b : A1a;
  const unsigned short* A2 = sb ? A2b : A2a;
  const unsigned short* Wt = sb ? Wtb : Wta;
  const float* bias = sb ? bb : ba;
  bf16x8 Wr[12];
  #pragma unroll
  for (int ks = 0; ks < 12; ++ks)
    Wr[ks] = *(const bf16x8*)&Wt[((size_t)(ks * 4 + l4) * 128 + wv * 16 + l15) * 8];
  const int rw = tile * 32;
  bf16x8 ar[12][2];
  #pragma unroll
  for (int ks = 0; ks < 4; ++ks)
    #pragma unroll
    for (int rf = 0; rf < 2; ++rf)
      ar[ks][rf] = *(const bf16x8*)&A1[(size_t)(rw + rf * 16 + l15) * 128 + ks * 32 + l4 * 8];
  #pragma unroll
  for (int ks = 0; ks < 8; ++ks)
    #pragma unroll
    for (int rf = 0; rf < 2; ++rf)
      ar[4 + ks][rf] = *(const bf16x8*)&A2[(size_t)(rw + rf * 16 + l15) * 256 + ks * 32 + l4 * 8];
  f32x4 acc0 = {0.f,0.f,0.f,0.f}, acc1 = {0.f,0.f,0.f,0.f};
  #pragma unroll
  for (int ks = 0; ks < 12; ++ks){
    acc0 = MFMA(ar[ks][0], Wr[ks], acc0, 0, 0, 0);
    acc1 = MFMA(ar[ks][1], Wr[ks], acc1, 0, 0, 0);
  }
  const int col = wv * 16 + l15;
  const float bv = bias[col];
  #pragma unroll
  for (int rf = 0; rf < 2; ++rf){
    const f32x4 ac = rf ? acc1 : acc0;
    #pragma unroll
    for (int i = 0; i < 4; ++i){
      const size_t o = (size_t)(rw + rf * 16 + l4 * 4 + i) * 128 + col;
      const float v = fmaxf(ac[i] + bv, 0.f);
      if (sb) outb[o] = f2bf(v);
      else    outa[o] = v;
    }
  }
}

// Fused 4-way attention projection: blocks [0,tiles) -> topology head
// (ht16 @ a_dT|a_dG), [tiles,2*tiles) -> label head (me16 @ a_lT|a_lG).
__global__ __launch_bounds__(512) void gemm_proj4_kernel(
    int tiles,
    const unsigned short* __restrict__ Ad, const unsigned short* __restrict__ Al,
    const unsigned short* __restrict__ WdT, const unsigned short* __restrict__ WdG,
    const unsigned short* __restrict__ WlT, const unsigned short* __restrict__ WlG,
    float* __restrict__ oTd, float* __restrict__ oGd,
    float* __restrict__ oTl, float* __restrict__ oGl)
{
  const int t = threadIdx.x, wv = t >> 6, lane = t & 63;
  const int l15 = lane & 15, l4 = lane >> 4;
  const bool lab = ((int)blockIdx.x >= tiles);
  const int tile = (int)blockIdx.x - (lab ? tiles : 0);
  const unsigned short* A1  = lab ? Al  : Ad;
  const unsigned short* W1t = lab ? WlT : WdT;
  const unsigned short* W2t = lab ? WlG : WdG;
  float* out1 = lab ? oTl : oTd;
  float* out2 = lab ? oGl : oGd;
  bf16x8 W1r[4], W2r[4];
  #pragma unroll
  for (int ks = 0; ks < 4; ++ks){
    const size_t fo = ((size_t)(ks * 4 + l4) * 128 + wv * 16 + l15) * 8;
    W1r[ks] = *(const bf16x8*)&W1t[fo];
    W2r[ks] = *(const bf16x8*)&W2t[fo];
  }
  const int rw = tile * 32;
  bf16x8 a[4][2];
  #pragma unroll
  for (int ks = 0; ks < 4; ++ks)
    #pragma unroll
    for (int rf = 0; rf < 2; ++rf)
      a[ks][rf] = *(const bf16x8*)&A1[(size_t)(rw + rf * 16 + l15) * 128 + ks * 32 + l4 * 8];
  f32x4 p10 = {0.f,0.f,0.f,0.f}, p11 = {0.f,0.f,0.f,0.f};
  f32x4 p20 = {0.f,0.f,0.f,0.f}, p21 = {0.f,0.f,0.f,0.f};
  #pragma unroll
  for (int ks = 0; ks < 4; ++ks){
    p10 = MFMA(a[ks][0], W1r[ks], p10, 0, 0, 0);
    p20 = MFMA(a[ks][0], W2r[ks], p20, 0, 0, 0);
    p11 = MFMA(a[ks][1], W1r[ks], p11, 0, 0, 0);
    p21 = MFMA(a[ks][1], W2r[ks], p21, 0, 0, 0);
  }
  const int col = wv * 16 + l15;
  #pragma unroll
  for (int rf = 0; rf < 2; ++rf){
    const f32x4 c1 = rf ? p11 : p10;
    const f32x4 c2 = rf ? p21 : p20;
    #pragma unroll
    for (int i = 0; i < 4; ++i){
      const size_t o = (size_t)(rw + rf * 16 + l4 * 4 + i) * 128 + col;
      out1[o] = c1[i];
      out2[o] = c2[i];
    }
  }
}

// ---------------- CSR build (by lg_dst) ----------------

__global__ __launch_bounds__(256) void csr_count_kernel(
    const int* __restrict__ lg_dst, int ELG,
    int* __restrict__ cnt, int* __restrict__ ticket)
{
  const int e = blockIdx.x * 256 + threadIdx.x;
  if (e < ELG) ticket[e] = atomicAdd(&cnt[lg_dst[e]], 1);
}

#define SCAN_CHUNK 1024

__global__ __launch_bounds__(256) void scan_totals_kernel(
    const int* __restrict__ cnt, int n, int* __restrict__ bsum)
{
  __shared__ int red[256];
  const int base = blockIdx.x * SCAN_CHUNK;
  const int t = threadIdx.x;
  int s = 0;
  #pragma unroll
  for (int k = 0; k < 4; ++k){
    const int idx = base + t + k * 256;
    if (idx < n) s += cnt[idx];
  }
  red[t] = s; __syncthreads();
  for (int g = 128; g; g >>= 1){
    if (t < g) red[t] += red[t + g];
    __syncthreads();
  }
  if (t == 0) bsum[blockIdx.x] = red[0];
}

__global__ void scan_serial_kernel(int* bsum, int nb, int* offsets, int n)
{
  if (threadIdx.x == 0 && blockIdx.x == 0){
    int acc = 0;
    for (int i = 0; i < nb; ++i){ const int v = bsum[i]; bsum[i] = acc; acc += v; }
    offsets[n] = acc;
  }
}

__global__ __launch_bounds__(256) void scan_write_kernel(
    const int* __restrict__ cnt, int n,
    const int* __restrict__ bsum, int* __restrict__ offsets)
{
  __shared__ int wsum[4];
  const int base = blockIdx.x * SCAN_CHUNK;
  const int t = threadIdx.x;
  int v[4]; int lsum = 0;
  #pragma unroll
  for (int k = 0; k < 4; ++k){
    const int idx = base + t * 4 + k;
    v[k] = (idx < n) ? cnt[idx] : 0;
    lsum += v[k];
  }
  const int lane = t & 63, wv = t >> 6;
  int x = lsum;
  #pragma unroll
  for (int off = 1; off < 64; off <<= 1){
    const int y = __shfl_up(x, off, 64);
    if (lane >= off) x += y;
  }
  if (lane == 63) wsum[wv] = x;
  __syncthreads();
  int woff = 0;
  for (int i = 0; i < wv; ++i) woff += wsum[i];
  int run = x - lsum + woff + bsum[blockIdx.x];
  #pragma unroll
  for (int k = 0; k < 4; ++k){
    const int idx = base + t * 4 + k;
    if (idx < n) offsets[idx] = run;
    run += v[k];
  }
}

__global__ __launch_bounds__(256) void csr_fill_kernel(
    const int* __restrict__ lg_src, const int* __restrict__ lg_dst,
    const int* __restrict__ ticket, int ELG,
    const int* __restrict__ offsets, int* __restrict__ csr_src)
{
  const int e = blockIdx.x * 256 + threadIdx.x;
  if (e >= ELG) return;
  csr_src[offsets[lg_dst[e]] + ticket[e]] = lg_src[e];
}

// ---------------- CSR gathers (bf16 rows, f32 accumulate) ----------------

// compacted: s/srh at S1 rows only; sources via rank2 into compacted msg/R.
__global__ __launch_bounds__(256) void gather2_bf_kernel(
    const int* __restrict__ offsets, const int* __restrict__ csr_src,
    const int* __restrict__ cnt1p, const int* __restrict__ S1list,
    const int* __restrict__ rank2,
    const unsigned short* __restrict__ msg16c, const unsigned short* __restrict__ R16c,
    unsigned short* __restrict__ s16c, unsigned short* __restrict__ srh16c)
{
  const int total = (*cnt1p) * 16;
  for (int g = blockIdx.x * 256 + threadIdx.x; g < total; g += gridDim.x * 256){
    const int i = g >> 4, q = g & 15;
    const int v = S1list[i];
    const int beg = offsets[v], end = offsets[v + 1];
    float as[8] = {}, ar[8] = {};
    for (int j = beg; j < end; ++j){
      const int sc = rank2[csr_src[j]];
      acc8(as, *(const uint4*)&msg16c[(size_t)sc * 128 + q * 8]);
      acc8(ar, *(const uint4*)&R16c[(size_t)sc * 128 + q * 8]);
    }
    *(uint4*)&s16c[(size_t)i * 128 + q * 8] = pack8(as);
    *(uint4*)&srh16c[(size_t)i * 128 + q * 8] = pack8(ar);
  }
}

// eids gather: sum_h[eids] via CSR walk over compacted mn16c (rank1).
__global__ __launch_bounds__(256) void gather3_kernel(
    const int* __restrict__ eids, int B,
    const float* __restrict__ f_srcf, const unsigned short* __restrict__ mn16c,
    const int* __restrict__ rank1,
    const int* __restrict__ offsets, const int* __restrict__ csr_src,
    unsigned short* __restrict__ fs_e, unsigned short* __restrict__ sh_e,
    unsigned short* __restrict__ m_e)
{
  const int g = blockIdx.x * 256 + threadIdx.x;
  const int bI = g >> 4, q = g & 15;
  if (bI >= B) return;
  const int e = eids[bI];
  *(uint4*)&fs_e[(size_t)bI * 128 + q * 8] = cvt8(f_srcf + (size_t)e * 128 + q * 8);
  *(uint4*)&m_e [(size_t)bI * 128 + q * 8] =
      *(const uint4*)&mn16c[(size_t)rank1[e] * 128 + q * 8];
  const int beg = offsets[e], end = offsets[e + 1];
  float a[8] = {};
  for (int j = beg; j < end; ++j){
    const int sc = rank1[csr_src[j]];
    acc8(a, *(const uint4*)&mn16c[(size_t)sc * 128 + q * 8]);
  }
  *(uint4*)&sh_e[(size_t)bI * 128 + q * 8] = pack8(a);
}

// Fused per-graph attention (both heads, both node sets): blocks [0,B) -> x_T,
// [B,2B) -> x_G. Output stride 256; T cols [0,128), G cols [128,256).
// R29: stage x tile into LDS once (coalesced float2 rows), both phases
// read LDS. xs stride 130 words: staging writes / phase-2 reads / phase-1
// 2xfloat2 reads all ~2-way bank (free).
__global__ __launch_bounds__(64) void attn2_kernel(
    const float* __restrict__ xT, int nTn,
    const float* __restrict__ xG, int nGn,
    const float* __restrict__ haTd, const float* __restrict__ haGd,
    const float* __restrict__ haTl, const float* __restrict__ haGl,
    unsigned short* __restrict__ out_d, unsigned short* __restrict__ out_l, int B)
{
  int b = blockIdx.x;
  const bool isG = (b >= B);
  if (isG) b -= B;
  const float* x  = isG ? xG : xT;
  const int n     = isG ? nGn : nTn;
  const float* ha_d = isG ? haGd : haTd;
  const float* ha_l = isG ? haGl : haTl;
  const int col_off = isG ? 128 : 0;
  const int l = threadIdx.x;
  __shared__ float xs[64][130];
  __shared__ float hd[128], hl[128];
  __shared__ float pd[64], pl[64];
  hd[l]      = ha_d[(size_t)b * 128 + l];
  hd[l + 64] = ha_d[(size_t)b * 128 + 64 + l];
  hl[l]      = ha_l[(size_t)b * 128 + l];
  hl[l + 64] = ha_l[(size_t)b * 128 + 64 + l];
  // stage x tile, coalesced: row i, lane reads cols 2l..2l+1
  const float* xb = x + (size_t)b * n * 128;
  #pragma unroll 8
  for (int i = 0; i < n; ++i){
    const float2 xv = *(const float2*)(xb + i * 128 + 2 * l);
    xs[i][2 * l]     = xv.x;
    xs[i][2 * l + 1] = xv.y;
  }
  __syncthreads();
  float ed = -1e30f, el = -1e30f;
  if (l < n){
    const float* xr = xs[l];
    float sd = 0.f, sl = 0.f;
    #pragma unroll 8
    for (int k = 0; k < 32; ++k){
      const float2 xa = *(const float2*)&xr[k * 4];
      const float2 xbv = *(const float2*)&xr[k * 4 + 2];
      sd += xa.x * hd[k*4] + xa.y * hd[k*4+1] + xbv.x * hd[k*4+2] + xbv.y * hd[k*4+3];
      sl += xa.x * hl[k*4] + xa.y * hl[k*4+1] + xbv.x * hl[k*4+2] + xbv.y * hl[k*4+3];
    }
    ed = sd; el = sl;
  }
  const float md = wave_max64(ed), ml = wave_max64(el);
  const float exd = (l < n) ? __expf(ed - md) : 0.f;
  const float exl = (l < n) ? __expf(el - ml) : 0.f;
  const float zd = wave_sum64(exd), zl = wave_sum64(exl);
  pd[l] = exd / zd;
  pl[l] = exl / zl;
  __syncthreads();
  float od0 = 0.f, od1 = 0.f, ol0 = 0.f, ol1 = 0.f;
  #pragma unroll 8
  for (int i = 0; i < n; ++i){
    const float x0 = xs[i][2 * l], x1 = xs[i][2 * l + 1];
    const float wd = pd[i], wl = pl[i];
    od0 += wd * x0; od1 += wd * x1;
    ol0 += wl * x0; ol1 += wl * x1;
  }
  const size_t o = (size_t)b * 256 + col_off;
  *(unsigned*)&out_d[o + 2 * l] = pk2(f2bf(od0), f2bf(od1));
  *(unsigned*)&out_l[o + 2 * l] = pk2(f2bf(ol0), f2bf(ol1));
}

__global__ __launch_bounds__(256) void ce_topo_kernel(
    const float* __restrict__ z_d, const float* __restrict__ u_d,
    const float* __restrict__ b_d3, const float* __restrict__ expand,
    float* __restrict__ out, int B)
{
  const int r = blockIdx.x * 4 + (threadIdx.x >> 6);
  const int l = threadIdx.x & 63;
  if (r >= B) return;
  const float* row = z_d + (size_t)r * 128;
  float s = row[l] * u_d[l] + row[l + 64] * u_d[l + 64];
  s = wave_sum64(s);
  if (l == 0){
    const float p = s + b_d3[0];
    const float t = expand[r];
    const float loss = -(t * logsigf_(p) + (1.f - t) * logsigf_(1.f - p));
    atomicAdd(out, loss / (float)B);
  }
}

// ---------------- label CE via MFMA: 32 rows/block, all V cols ----------------
__global__ __launch_bounds__(512) void ce_label_mfma_kernel(
    const unsigned short* __restrict__ zl16,
    const unsigned short* __restrict__ ul,    // granule layout k8*V + col
    const float* __restrict__ b_l2, const int* __restrict__ wid,
    float* __restrict__ out, int B, int V)
{
  const int NF = V >> 4;
  const int t = threadIdx.x, wv = t >> 6, lane = t & 63;
  const int l15 = lane & 15, l4 = lane >> 4;
  const int rw = blockIdx.x * 32;
  __shared__ float redm[32][8];
  __shared__ float reds[32][8];
  __shared__ float rowm[32];
  __shared__ float tgt[32];

  bf16x8 a[4][2];
  #pragma unroll
  for (int ks = 0; ks < 4; ++ks)
    #pragma unroll
    for (int rf = 0; rf < 2; ++rf)
      a[ks][rf] = *(const bf16x8*)&zl16[(size_t)(rw + rf * 16 + l15) * 128 + ks * 32 + l4 * 8];

  f32x4 acc[7][2];
  #pragma unroll
  for (int j = 0; j < 7; ++j){
    acc[j][0] = (f32x4){0.f,0.f,0.f,0.f};
    acc[j][1] = (f32x4){0.f,0.f,0.f,0.f};
  }
  #pragma unroll
  for (int j = 0; j < 7; ++j){
    const int cf = wv + 8 * j;
    if (cf < NF){
      #pragma unroll
      for (int ks = 0; ks < 4; ++ks){
        const bf16x8 bf = *(const bf16x8*)&ul[((size_t)(ks * 4 + l4) * V + cf * 16 + l15) * 8];
        acc[j][0] = MFMA(a[ks][0], bf, acc[j][0], 0, 0, 0);
        acc[j][1] = MFMA(a[ks][1], bf, acc[j][1], 0, 0, 0);
      }
    }
  }
  float mloc[8];
  #pragma unroll
  for (int k = 0; k < 8; ++k) mloc[k] = -1e30f;
  #pragma unroll
  for (int j = 0; j < 7; ++j){
    const int cf = wv + 8 * j;
    if (cf < NF){
      const float bv = b_l2[cf * 16 + l15];
      #pragma unroll
      for (int rf = 0; rf < 2; ++rf)
        #pragma unroll
        for (int i = 0; i < 4; ++i){
          const float v = acc[j][rf][i] + bv;
          acc[j][rf][i] = v;
          mloc[rf * 4 + i] = fmaxf(mloc[rf * 4 + i], v);
        }
    }
  }
  #pragma unroll
  for (int m = 1; m < 16; m <<= 1)
    #pragma unroll
    for (int k = 0; k < 8; ++k)
      mloc[k] = fmaxf(mloc[k], __shfl_xor(mloc[k], m, 64));
  if (l15 == 0){
    #pragma unroll
    for (int rf = 0; rf < 2; ++rf)
      #pragma unroll
      for (int i = 0; i < 4; ++i)
        redm[rf * 16 + l4 * 4 + i][wv] = mloc[rf * 4 + i];
  }
  __syncthreads();
  if (t < 32){
    float m = redm[t][0];
    #pragma unroll
    for (int k = 1; k < 8; ++k) m = fmaxf(m, redm[t][k]);
    rowm[t] = m;
  }
  __syncthreads();
  float sloc[8];
  #pragma unroll
  for (int k = 0; k < 8; ++k) sloc[k] = 0.f;
  #pragma unroll
  for (int j = 0; j < 7; ++j){
    const int cf = wv + 8 * j;
    if (cf < NF){
      #pragma unroll
      for (int rf = 0; rf < 2; ++rf)
        #pragma unroll
        for (int i = 0; i < 4; ++i){
          const int lr = rf * 16 + l4 * 4 + i;
          const float v = acc[j][rf][i];
          sloc[rf * 4 + i] += __expf(v - rowm[lr]);
          if (cf * 16 + l15 == wid[rw + lr]) tgt[lr] = v;
        }
    }
  }
  #pragma unroll
  for (int m = 1; m < 16; m <<= 1)
    #pragma unroll
    for (int k = 0; k < 8; ++k)
      sloc[k] += __shfl_xor(sloc[k], m, 64);
  if (l15 == 0){
    #pragma unroll
    for (int rf = 0; rf < 2; ++rf)
      #pragma unroll
      for (int i = 0; i < 4; ++i)
        reds[rf * 16 + l4 * 4 + i][wv] = sloc[rf * 4 + i];
  }
  __syncthreads();
  if (t < 32){
    float s = 0.f;
    #pragma unroll
    for (int k = 0; k < 8; ++k) s += reds[t][k];
    const float lp = tgt[t] - rowm[t] - __logf(s);
    atomicAdd(out + 1, -lp / (float)B);
  }
}

extern "C" void kernel_launch(void* const* d_in, const int* in_sizes, int n_in,
                              void* d_out, int out_size, void* d_ws, size_t ws_size,
                              hipStream_t stream)
{
  const float* msg    = (const float*)d_in[0];
  const float* f_src  = (const float*)d_in[1];
  const float* f_dst  = (const float*)d_in[2];
  const float* x_T    = (const float*)d_in[3];
  const float* x_G    = (const float*)d_in[4];
  const float* expand = (const float*)d_in[5];
  const float* wz = (const float*)d_in[6];
  const float* uz = (const float*)d_in[7];
  const float* bz = (const float*)d_in[8];
  const float* wr = (const float*)d_in[9];
  const float* ur = (const float*)d_in[10];
  const float* br = (const float*)d_in[11];
  const float* w  = (const float*)d_in[12];
  const float* u  = (const float*)d_in[13];
  const float* b  = (const float*)d_in[14];
  const float* w_d1 = (const float*)d_in[15];
  const float* w_d2 = (const float*)d_in[16];
  const float* b_d1 = (const float*)d_in[17];
  const float* a_dT = (const float*)d_in[18];
  const float* a_dG = (const float*)d_in[19];
  const float* w_d3 = (const float*)d_in[20];
  const float* w_d4 = (const float*)d_in[21];
  const float* b_d2 = (const float*)d_in[22];
  const float* u_d  = (const float*)d_in[23];
  const float* b_d3 = (const float*)d_in[24];
  const float* w_l1 = (const float*)d_in[25];
  const float* w_l2 = (const float*)d_in[26];
  const float* b_l1 = (const float*)d_in[27];
  const float* a_lT = (const float*)d_in[28];
  const float* a_lG = (const float*)d_in[29];
  const float* u_l  = (const float*)d_in[30];
  const float* b_l2 = (const float*)d_in[31];
  const int* lg_src = (const int*)d_in[32];
  const int* lg_dst = (const int*)d_in[33];
  const int* eids   = (const int*)d_in[34];
  const int* wid    = (const int*)d_in[35];

  const int d = 128;
  const int E   = in_sizes[0] / d;
  const int ELG = in_sizes[32];
  const int B   = in_sizes[34];
  const int V   = in_sizes[31];
  const int nT  = (in_sizes[3] / d) / B;
  const int nG  = (in_sizes[4] / d) / B;

  const size_t EH = (size_t)E * d * sizeof(unsigned short);
  const size_t BH = (size_t)B * d * sizeof(unsigned short);
  const size_t BF = (size_t)B * d * sizeof(float);
  char* p = (char*)d_ws;
  unsigned short* bufA = (unsigned short*)p; p += EH;  // R16c -> mn16c
  unsigned short* bufB = (unsigned short*)p; p += EH;  // s16c
  unsigned short* srh16 = (unsigned short*)p; p += EH; // srh16c
  unsigned short* msg16 = (unsigned short*)p; p += EH; // msg16c
  unsigned short* R16 = bufA, *mn16 = bufA;
  unsigned short* s16 = bufB;
  unsigned short* fse16 = (unsigned short*)p; p += BH;
  unsigned short* she16 = (unsigned short*)p; p += BH;
  unsigned short* me16  = (unsigned short*)p; p += BH;
  unsigned short* ht16  = (unsigned short*)p; p += BH;
  unsigned short* cd16  = (unsigned short*)p; p += 2 * BH;
  unsigned short* cl16  = (unsigned short*)p; p += 2 * BH;
  unsigned short* zl16  = (unsigned short*)p; p += BH;
  float* haTd = (float*)p; p += BF;
  float* haGd = (float*)p; p += BF;
  float* haTl = (float*)p; p += BF;
  float* haGl = (float*)p; p += BF;
  float* z_d  = (float*)p; p += BF;
  // CSR scratch
  int* cnt     = (int*)p; p += (size_t)E * sizeof(int);
  int* offsets = (int*)p; p += (size_t)(E + 1) * sizeof(int);
  int* ticket  = (int*)p; p += (size_t)ELG * sizeof(int);
  int* csr_src = (int*)p; p += (size_t)ELG * sizeof(int);
  int* bsum    = (int*)p; p += (size_t)((E + SCAN_CHUNK - 1) / SCAN_CHUNK + 1) * sizeof(int);
  // active-set scratch (R26)
  int* flag1  = (int*)p; p += (size_t)E * sizeof(int);
  int* flag2  = (int*)p; p += (size_t)E * sizeof(int);
  int* cnts   = (int*)p; p += 2 * sizeof(int);
  int* S1list = (int*)p; p += (size_t)(E + 128) * sizeof(int);
  int* S2list = (int*)p; p += (size_t)(E + 128) * sizeof(int);
  int* rank1  = (int*)p; p += (size_t)E * sizeof(int);
  int* rank2  = (int*)p; p += (size_t)E * sizeof(int);
  // bf16 fragment-layout weights
  p = (char*)(((size_t)p + 255) & ~(size_t)255);
  unsigned short* wt = (unsigned short*)p; p += 294912 * sizeof(unsigned short);
  p = (char*)(((size_t)p + 255) & ~(size_t)255);
  unsigned short* wt_ul = (unsigned short*)p; p += (size_t)128 * V * sizeof(unsigned short);

  hipMemsetAsync(cnt, 0, (size_t)E * sizeof(int), stream);
  hipMemsetAsync(flag1, 0, 2 * (size_t)E * sizeof(int), stream);  // flag1+flag2
  hipMemsetAsync(cnts, 0, 2 * sizeof(int), stream);
  hipMemsetAsync(d_out, 0, 2 * sizeof(float), stream);

  const int nb = (E + SCAN_CHUNK - 1) / SCAN_CHUNK;
  const int tilesB = B / 32;
  const int ublocks = (16 * V + 255) / 256;
  const int wblocks = (ublocks > 24) ? ublocks : 24;

  // weights -> bf16 fragment layout (y<10: panels; y==10: u_l)
  wprep_kernel<<<dim3(wblocks, 11), 256, 0, stream>>>(
      wr, ur, wz, uz, w, u, w_d1, w_d2, a_dT, a_dG, a_lT, a_lG,
      w_d3, w_d4, w_l1, w_l2, wt, u_l, wt_ul, V);

  // ---- CSR build (by lg_dst) ----
  csr_count_kernel<<<(ELG + 255) / 256, 256, 0, stream>>>(lg_dst, ELG, cnt, ticket);
  scan_totals_kernel<<<nb, 256, 0, stream>>>(cnt, E, bsum);
  scan_serial_kernel<<<1, 64, 0, stream>>>(bsum, nb, offsets, E);
  scan_write_kernel<<<nb, 256, 0, stream>>>(cnt, E, bsum, offsets);
  csr_fill_kernel<<<(ELG + 255) / 256, 256, 0, stream>>>(lg_src, lg_dst, ticket, ELG, offsets, csr_src);

  // ---- active sets: S1 = eids + their sources; S2 = sources of S1 ----
  mark1_kernel<<<(B + 255) / 256, 256, 0, stream>>>(eids, B, offsets, csr_src, flag1);
  compact_kernel<<<(E + 255) / 256, 256, 0, stream>>>(flag1, E, S1list, rank1, cnts + 0);
  mark2_kernel<<<512, 256, 0, stream>>>(cnts + 0, S1list, offsets, csr_src, flag2);
  compact_kernel<<<(E + 255) / 256, 256, 0, stream>>>(flag2, E, S2list, rank2, cnts + 1);
  pad_kernel<<<1, 64, 0, stream>>>(cnts + 0, S1list, cnts + 1, S2list);

  // R = sigmoid(f_dst@wr + msg@ur + br) * msg at S2 rows -> R16c, msg16c
  gemm_r_kernel<<<512, 512, 0, stream>>>(
      cnts + 1, S2list, f_dst, msg, wt + 0, br, R16, msg16);
  // s/srh segsums at S1 rows (compacted, sources via rank2)
  gather2_bf_kernel<<<2048, 256, 0, stream>>>(
      offsets, csr_src, cnts + 0, S1list, rank2, msg16, R16, s16, srh16);
  // msg_new at S1 rows -> mn16c
  gemm_zh_kernel<<<256, 512, 0, stream>>>(
      cnts + 0, S1list, f_src, s16, srh16, wt + 32768, wt + 65536, bz, b, mn16);
  // eids gathers incl. sum_h[eids] via CSR walk over mn16c
  gather3_kernel<<<(B * 16 + 255) / 256, 256, 0, stream>>>(
      eids, B, f_src, mn16, rank1, offsets, csr_src, fse16, she16, me16);
  // h_t = relu(fs_e@w_d1 + sh_e@w_d2 + b_d1)   -> ht16
  gemm1_kernel<4, 4, EPI_RELU, true><<<tilesB, 512, 0, stream>>>(
      tilesB, fse16, she16, wt + 98304, b_d1, ht16);
  // all four attention projections in one full-CU launch
  gemm_proj4_kernel<<<2 * tilesB, 512, 0, stream>>>(
      tilesB, ht16, me16,
      wt + 131072, wt + 147456, wt + 163840, wt + 180224,
      haTd, haGd, haTl, haGl);
  // fused attention: LDS-staged (R29), T+G in one launch
  attn2_kernel<<<2 * B, 64, 0, stream>>>(
      x_T, nT, x_G, nG, haTd, haGd, haTl, haGl, cd16, cl16, B);
  // z_d (f32) + z_l (bf16) in one full-CU launch
  gemm1_dual_kernel<<<2 * tilesB, 512, 0, stream>>>(
      tilesB,
      ht16, cd16, wt + 196608, b_d2, z_d,
      me16, cl16, wt + 245760, b_l1, zl16);
  // losses
  ce_topo_kernel<<<(B + 3) / 4, 256, 0, stream>>>(z_d, u_d, b_d3, expand, (float*)d_out, B);
  ce_label_mfma_kernel<<<B / 32, 512, 0, stream>>>(zl16, wt_ul, b_l2, wid,
                                                   (float*)d_out, B, V);
}

// Round 30
// 376.629 us; speedup vs baseline: 1.0843x; 1.0045x over previous
//
#include <hip/hip_runtime.h>
#include <math.h>

// G2GDecoder forward: TreeGRU over line graph + topology/label heads.
// R2: CSR gathers. R5: bf16 MFMA. R11: MFMA label-CE. R15-R21: persistent-W
// E-GEMMs, T14 split staging, XOR-swizzled A-rings. R24: tail fusion.
// R25/R26: active-set sparsification. R29: attn2 LDS staging (one coalesced
// global pass; won, attn2 left top-5).
// R30: attn2 template<N> split. n is 32 (x_T) or 64 (x_G): N=32 instance
// has xs[32][130]=18KB -> 8 blocks/CU (2x waves) for half the work; both
// instances get compile-time trip counts (full unroll, deeper load
// pipeline). Same per-row math as R29. Generic fallback kept.

using bf16x8 = __attribute__((ext_vector_type(8))) short;
using f32x4  = __attribute__((ext_vector_type(4))) float;

#define MFMA __builtin_amdgcn_mfma_f32_16x16x32_bf16

__device__ inline float wave_sum64(float v){
  #pragma unroll
  for (int m = 32; m; m >>= 1) v += __shfl_xor(v, m, 64);
  return v;
}
__device__ inline float wave_max64(float v){
  #pragma unroll
  for (int m = 32; m; m >>= 1) v = fmaxf(v, __shfl_xor(v, m, 64));
  return v;
}
__device__ inline float sigmoidf_(float x){ return 1.f / (1.f + __expf(-x)); }
__device__ inline float tanh_fast(float x){
  x = fminf(fmaxf(x, -15.f), 15.f);
  float e = __expf(2.f * x);
  return (e - 1.f) / (e + 1.f);
}
__device__ inline float logsigf_(float x){
  return (x >= 0.f) ? -log1pf(__expf(-x)) : (x - log1pf(__expf(x)));
}
__device__ inline unsigned short f2bf(float f){
  union { float f; unsigned u; } v; v.f = f;
  const unsigned r = v.u + 0x7FFF + ((v.u >> 16) & 1);   // RNE
  return (unsigned short)(r >> 16);
}
__device__ inline float bf2f(unsigned short u){
  union { unsigned u; float f; } v; v.u = ((unsigned)u) << 16; return v.f;
}
__device__ inline unsigned pk2(unsigned short a, unsigned short b){
  return (unsigned)a | ((unsigned)b << 16);
}
__device__ inline uint4 cvt8v(float4 x0, float4 x1){
  uint4 o;
  o.x = pk2(f2bf(x0.x), f2bf(x0.y)); o.y = pk2(f2bf(x0.z), f2bf(x0.w));
  o.z = pk2(f2bf(x1.x), f2bf(x1.y)); o.w = pk2(f2bf(x1.z), f2bf(x1.w));
  return o;
}
__device__ inline uint4 cvt8(const float* __restrict__ p){
  return cvt8v(*(const float4*)(p), *(const float4*)(p + 4));
}
__device__ inline void acc8(float* a, uint4 v){
  a[0] += bf2f(v.x & 0xffff); a[1] += bf2f(v.x >> 16);
  a[2] += bf2f(v.y & 0xffff); a[3] += bf2f(v.y >> 16);
  a[4] += bf2f(v.z & 0xffff); a[5] += bf2f(v.z >> 16);
  a[6] += bf2f(v.w & 0xffff); a[7] += bf2f(v.w >> 16);
}
__device__ inline uint4 pack8(const float* a){
  uint4 o;
  o.x = pk2(f2bf(a[0]), f2bf(a[1])); o.y = pk2(f2bf(a[2]), f2bf(a[3]));
  o.z = pk2(f2bf(a[4]), f2bf(a[5])); o.w = pk2(f2bf(a[6]), f2bf(a[7]));
  return o;
}

enum { EPI_NONE = 0, EPI_SIGMOID = 1, EPI_RELU = 2 };

// ------- weight prep: f32 [k][col] -> bf16 fragment granule layout ---------
// blockIdx.y in [0,10): gate/head panels -> wt. blockIdx.y == 10: u_l -> wt_ul.
__global__ __launch_bounds__(256) void wprep_kernel(
    const float* wr, const float* ur, const float* wz, const float* uz,
    const float* w,  const float* u,  const float* w_d1, const float* w_d2,
    const float* a_dT, const float* a_dG, const float* a_lT, const float* a_lG,
    const float* w_d3, const float* w_d4, const float* w_l1, const float* w_l2,
    unsigned short* __restrict__ wt,
    const float* __restrict__ u_l, unsigned short* __restrict__ wt_ul, int V)
{
  const int m = blockIdx.y;
  const int tid = blockIdx.x * 256 + threadIdx.x;
  if (m == 10){
    if (tid >= 16 * V) return;
    const int col = tid % V, k8 = tid / V;
    unsigned short v[8];
    #pragma unroll
    for (int i = 0; i < 8; ++i)
      v[i] = f2bf(u_l[(size_t)(k8 * 8 + i) * V + col]);
    uint4 pk;
    pk.x = pk2(v[0], v[1]); pk.y = pk2(v[2], v[3]);
    pk.z = pk2(v[4], v[5]); pk.w = pk2(v[6], v[7]);
    *(uint4*)&wt_ul[((size_t)k8 * V + col) * 8] = pk;
    return;
  }
  const float* s1; const float* s2; int K1, Ktot; size_t off;
  switch (m){
    case 0: s1 = wr;   s2 = ur;   K1 = 128; Ktot = 256; off = 0;      break;
    case 1: s1 = wz;   s2 = uz;   K1 = 128; Ktot = 256; off = 32768;  break;
    case 2: s1 = w;    s2 = u;    K1 = 128; Ktot = 256; off = 65536;  break;
    case 3: s1 = w_d1; s2 = w_d2; K1 = 128; Ktot = 256; off = 98304;  break;
    case 4: s1 = a_dT; s2 = nullptr; K1 = 128; Ktot = 128; off = 131072; break;
    case 5: s1 = a_dG; s2 = nullptr; K1 = 128; Ktot = 128; off = 147456; break;
    case 6: s1 = a_lT; s2 = nullptr; K1 = 128; Ktot = 128; off = 163840; break;
    case 7: s1 = a_lG; s2 = nullptr; K1 = 128; Ktot = 128; off = 180224; break;
    case 8: s1 = w_d3; s2 = w_d4; K1 = 128; Ktot = 384; off = 196608; break;
    default:s1 = w_l1; s2 = w_l2; K1 = 128; Ktot = 384; off = 245760; break;
  }
  if (tid >= 16 * Ktot) return;
  const int col = tid & 127, k8 = tid >> 7;
  unsigned short v[8];
  #pragma unroll
  for (int i = 0; i < 8; ++i){
    const int k = k8 * 8 + i;
    const float* s = (k < K1) ? (s1 + (size_t)k * 128 + col)
                              : (s2 + (size_t)(k - K1) * 128 + col);
    v[i] = f2bf(*s);
  }
  uint4 pk;
  pk.x = pk2(v[0], v[1]); pk.y = pk2(v[2], v[3]);
  pk.z = pk2(v[4], v[5]); pk.w = pk2(v[6], v[7]);
  *(uint4*)&wt[off + ((size_t)k8 * 128 + col) * 8] = pk;
}

// ---------------- active-set construction ----------------
__global__ __launch_bounds__(256) void mark1_kernel(
    const int* __restrict__ eids, int B,
    const int* __restrict__ offsets, const int* __restrict__ csr_src,
    int* __restrict__ flag1)
{
  const int b = blockIdx.x * 256 + threadIdx.x;
  if (b >= B) return;
  const int e = eids[b];
  flag1[e] = 1;
  const int beg = offsets[e], end = offsets[e + 1];
  for (int j = beg; j < end; ++j) flag1[csr_src[j]] = 1;
}

__global__ __launch_bounds__(256) void compact_kernel(
    const int* __restrict__ flag, int E,
    int* __restrict__ list, int* __restrict__ rank, int* __restrict__ cnt)
{
  const int v = blockIdx.x * 256 + threadIdx.x;
  if (v >= E || !flag[v]) return;
  const int pos = atomicAdd(cnt, 1);
  list[pos] = v;
  rank[v] = pos;
}

__global__ __launch_bounds__(256) void mark2_kernel(
    const int* __restrict__ cnt1p, const int* __restrict__ S1list,
    const int* __restrict__ offsets, const int* __restrict__ csr_src,
    int* __restrict__ flag2)
{
  const int n = *cnt1p;
  for (int i = blockIdx.x * 256 + threadIdx.x; i < n; i += gridDim.x * 256){
    const int v = S1list[i];
    const int beg = offsets[v], end = offsets[v + 1];
    for (int j = beg; j < end; ++j) flag2[csr_src[j]] = 1;
  }
}

// pad counts up to tile multiples (S1: 128, S2: 64), filling with list[0]
__global__ void pad_kernel(int* cnt1, int* S1list, int* cnt2, int* S2list)
{
  if (threadIdx.x == 0 && blockIdx.x == 0){
    int c1 = *cnt1;
    if (c1 > 0){
      const int p1 = (c1 + 127) & ~127;
      for (int i = c1; i < p1; ++i) S1list[i] = S1list[0];
      *cnt1 = p1;
    }
    int c2 = *cnt2;
    if (c2 > 0){
      const int p2 = (c2 + 63) & ~63;
      for (int i = c2; i < p2; ++i) S2list[i] = S2list[0];
      *cnt2 = p2;
    }
  }
}

// ---------------- persistent-W R-GEMM over S2 (compacted rows) -------------
// 64-row tiles, K-chunk 64; T14 split staging, ring-2 XOR-swizzled.
__global__ __launch_bounds__(512, 2) void gemm_r_kernel(
    const int* __restrict__ cnt2p, const int* __restrict__ S2list,
    const float* __restrict__ A1f,     // f_dst
    const float* __restrict__ A2f,     // msg
    const unsigned short* __restrict__ Wt,
    const float* __restrict__ bias,
    unsigned short* __restrict__ out,  // R16c (compacted)
    unsigned short* __restrict__ out2) // msg16c (compacted)
{
  __shared__ unsigned short Wl[32768];   // 64KB persistent W panel
  __shared__ unsigned short Ar[2][4096]; // 8KB slots: 64 rows x 8 granules (swz)
  const int t = threadIdx.x;
  const int lane = t & 63, wid = t >> 6;
  const int l15 = lane & 15, l4 = lane >> 4;
  const int wr = wid >> 1, wc = wid & 1;   // 4 row-grp x 2 col-grp

  const int tiles = (*cnt2p) >> 6;
  const int nT = (tiles - (int)blockIdx.x + (int)gridDim.x - 1) / (int)gridDim.x;
  if (nT <= 0) return;

  #pragma unroll
  for (int i = 0; i < 8; ++i)
    ((uint4*)Wl)[i * 512 + t] = ((const uint4*)Wt)[i * 512 + t];

  const int totalG = nT * 4;   // 4 K-chunks per tile

  float4 ra, rb;   // in-flight staged data (raw f32, all 512 threads)

  auto loadA = [&](int gs){
    const int tile = (int)blockIdx.x + (gs >> 2) * (int)gridDim.x;
    const int cs = gs & 3;
    const size_t grow = (size_t)S2list[tile * 64 + (t >> 3)];
    const int q8 = (t & 7) * 8;
    const float* src = (cs < 2) ? (A1f + grow * 128 + cs * 64 + q8)
                                : (A2f + grow * 128 + (cs - 2) * 64 + q8);
    ra = *(const float4*)(src);
    rb = *(const float4*)(src + 4);
  };
  auto writeA = [&](int slot, int gs){
    const uint4 o = cvt8v(ra, rb);
    const int rrow = t >> 3, qq = t & 7;
    *(uint4*)&Ar[slot][((rrow << 3) | (qq ^ (rrow & 7))) * 8] = o;
    const int cs = gs & 3;
    if (cs >= 2){
      const int tile = (int)blockIdx.x + (gs >> 2) * (int)gridDim.x;
      const size_t crow = (size_t)tile * 64 + rrow;
      *(uint4*)&out2[crow * 128 + (cs - 2) * 64 + qq * 8] = o;
    }
  };

  loadA(0); writeA(0, 0);
  if (totalG > 1) loadA(1);

  for (int m = 0; m < nT; ++m){
    const int tile = (int)blockIdx.x + m * (int)gridDim.x;
    f32x4 acc[4];
    #pragma unroll
    for (int cf = 0; cf < 4; ++cf) acc[cf] = (f32x4){0.f,0.f,0.f,0.f};
    #pragma unroll
    for (int cs = 0; cs < 4; ++cs){
      const int g = m * 4 + cs;
      __syncthreads();
      if (g + 1 < totalG) writeA((g + 1) & 1, g + 1);  // regs from prev load
      if (g + 2 < totalG) loadA(g + 2);                // issue ahead
      const unsigned short* S = Ar[g & 1];
      const int arow = wr * 16 + l15;
      #pragma unroll
      for (int kk = 0; kk < 2; ++kk){
        const int qq = (kk * 4 + l4) ^ (arow & 7);
        const bf16x8 a = *(const bf16x8*)&S[((arow << 3) | qq) * 8];
        #pragma unroll
        for (int cf = 0; cf < 4; ++cf){
          const int wg = (((cs * 2 + kk) * 4 + l4) * 128 + wc * 64 + cf * 16 + l15) * 8;
          acc[cf] = MFMA(a, *(const bf16x8*)&Wl[wg], acc[cf], 0, 0, 0);
        }
      }
    }
    int growv[4];
    #pragma unroll
    for (int i = 0; i < 4; ++i)
      growv[i] = S2list[tile * 64 + wr * 16 + l4 * 4 + i];
    #pragma unroll
    for (int cf = 0; cf < 4; ++cf){
      const int col = wc * 64 + cf * 16 + l15;
      const float bv = bias[col];
      #pragma unroll
      for (int i = 0; i < 4; ++i){
        const size_t oc = ((size_t)tile * 64 + wr * 16 + l4 * 4 + i) * 128 + col;
        out[oc] = f2bf(sigmoidf_(acc[cf][i] + bv) * A2f[(size_t)growv[i] * 128 + col]);
      }
    }
  }
}

// ---------------- persistent-W merged Z+H GEMM over S1 (compacted) ---------
// 128-row tiles. LDS: 128KB W + 2x16KB ring = 160KB.
__global__ __launch_bounds__(512, 2) void gemm_zh_kernel(
    const int* __restrict__ cnt1p, const int* __restrict__ S1list,
    const float* __restrict__ fsrc,
    const unsigned short* __restrict__ s16,    // compacted
    const unsigned short* __restrict__ srh16,  // compacted
    const unsigned short* __restrict__ Wz,
    const unsigned short* __restrict__ Wh,
    const float* __restrict__ bz, const float* __restrict__ bh,
    unsigned short* __restrict__ out)          // mn16c compacted
{
  __shared__ unsigned short Wl[65536];   // Wz | Wh, 128KB persistent
  __shared__ unsigned short Ar[2][8192]; // 16KB slots: [0:4096)=z, [4096:8192)=h
  const int t = threadIdx.x;
  const int lane = t & 63, wid = t >> 6;
  const int l15 = lane & 15, l4 = lane >> 4;
  const int wr = wid >> 1, wc = wid & 1;

  const int tiles = (*cnt1p) >> 7;
  const int nT = (tiles - (int)blockIdx.x + (int)gridDim.x - 1) / (int)gridDim.x;
  if (nT <= 0) return;

  #pragma unroll
  for (int i = 0; i < 8; ++i){
    ((uint4*)Wl)[i * 512 + t]        = ((const uint4*)Wz)[i * 512 + t];
    ((uint4*)Wl)[4096 + i * 512 + t] = ((const uint4*)Wh)[i * 512 + t];
  }

  const int totalG = nT * 8;

  float4 ra, rb;   // phase1: raw f32; phase2: ra=s16 bits, rb=srh16 bits

  auto loadA = [&](int gs){
    const int tile = (int)blockIdx.x + (gs >> 3) * (int)gridDim.x;
    const int ks = gs & 7;
    const int crow = tile * 128 + (t >> 2);
    const int q8 = (t & 3) * 8;
    if (ks < 4){
      const size_t grow = (size_t)S1list[crow];
      const float* src = fsrc + grow * 128 + ks * 32 + q8;
      ra = *(const float4*)(src);
      rb = *(const float4*)(src + 4);
    } else {
      const uint4 v1 = *(const uint4*)&s16[(size_t)crow * 128 + (ks - 4) * 32 + q8];
      const uint4 v2 = *(const uint4*)&srh16[(size_t)crow * 128 + (ks - 4) * 32 + q8];
      ra = *(const float4*)&v1;
      rb = *(const float4*)&v2;
    }
  };
  auto writeA = [&](int slot, int gs){
    const int ks = gs & 7;
    const int rrow = t >> 2, qq = t & 3;
    const int gsw = ((rrow << 2) | (qq ^ ((rrow >> 1) & 3))) * 8;
    if (ks < 4){
      *(uint4*)&Ar[slot][gsw] = cvt8v(ra, rb);
    } else {
      *(uint4*)&Ar[slot][gsw]        = *(const uint4*)&ra;
      *(uint4*)&Ar[slot][4096 + gsw] = *(const uint4*)&rb;
    }
  };

  loadA(0); writeA(0, 0);
  if (totalG > 1) loadA(1);

  for (int m = 0; m < nT; ++m){
    const int tile = (int)blockIdx.x + m * (int)gridDim.x;
    f32x4 az0[4], az1[4], ah0[4], ah1[4];
    #pragma unroll
    for (int cf = 0; cf < 4; ++cf){
      az0[cf] = (f32x4){0.f,0.f,0.f,0.f}; az1[cf] = (f32x4){0.f,0.f,0.f,0.f};
      ah0[cf] = (f32x4){0.f,0.f,0.f,0.f}; ah1[cf] = (f32x4){0.f,0.f,0.f,0.f};
    }
    #pragma unroll
    for (int ks = 0; ks < 8; ++ks){
      const int g = m * 8 + ks;
      __syncthreads();
      if (g + 1 < totalG) writeA((g + 1) & 1, g + 1);
      if (g + 2 < totalG) loadA(g + 2);
      const unsigned short* S = Ar[g & 1];
      const int r0 = wr * 32 + l15, r1 = wr * 32 + 16 + l15;
      const int ag0 = ((r0 << 2) | (l4 ^ ((r0 >> 1) & 3))) * 8;
      const int ag1 = ((r1 << 2) | (l4 ^ ((r1 >> 1) & 3))) * 8;
      const bf16x8 az_a0 = *(const bf16x8*)&S[ag0];
      const bf16x8 az_a1 = *(const bf16x8*)&S[ag1];
      const bf16x8 ah_a0 = (ks < 4) ? az_a0 : *(const bf16x8*)&S[4096 + ag0];
      const bf16x8 ah_a1 = (ks < 4) ? az_a1 : *(const bf16x8*)&S[4096 + ag1];
      #pragma unroll
      for (int cf = 0; cf < 4; ++cf){
        const int wg = ((ks * 4 + l4) * 128 + wc * 64 + cf * 16 + l15) * 8;
        const bf16x8 w1 = *(const bf16x8*)&Wl[wg];
        const bf16x8 w2 = *(const bf16x8*)&Wl[32768 + wg];
        az0[cf] = MFMA(az_a0, w1, az0[cf], 0, 0, 0);
        az1[cf] = MFMA(az_a1, w1, az1[cf], 0, 0, 0);
        ah0[cf] = MFMA(ah_a0, w2, ah0[cf], 0, 0, 0);
        ah1[cf] = MFMA(ah_a1, w2, ah1[cf], 0, 0, 0);
      }
    }
    #pragma unroll
    for (int cf = 0; cf < 4; ++cf){
      const int col = wc * 64 + cf * 16 + l15;
      const float bvz = bz[col], bvh = bh[col];
      #pragma unroll
      for (int rf = 0; rf < 2; ++rf){
        const f32x4 zc = rf ? az1[cf] : az0[cf];
        const f32x4 hc = rf ? ah1[cf] : ah0[cf];
        #pragma unroll
        for (int i = 0; i < 4; ++i){
          const size_t o = ((size_t)tile * 128 + wr * 32 + rf * 16 + l4 * 4 + i) * 128 + col;
          const float z = sigmoidf_(zc[i] + bvz);
          const float h = tanh_fast(hc[i] + bvh);
          out[o] = f2bf((1.f - z) * bf2f(s16[o]) + z * h);
        }
      }
    }
  }
}

// ---------------- B-path GEMMs (register-W, small) ----------------
template<int KS1, int KS2, int EPI, bool OB16>
__global__ __launch_bounds__(512) void gemm1_kernel(
    int tiles,
    const unsigned short* __restrict__ A1,
    const unsigned short* __restrict__ A2,
    const unsigned short* __restrict__ Wt,
    const float* __restrict__ bias,
    void* __restrict__ outv)
{
  const int t = threadIdx.x, wv = t >> 6, lane = t & 63;
  const int l15 = lane & 15, l4 = lane >> 4;
  constexpr int KS = KS1 + KS2;
  bf16x8 Wr[KS];
  #pragma unroll
  for (int ks = 0; ks < KS; ++ks)
    Wr[ks] = *(const bf16x8*)&Wt[((size_t)(ks * 4 + l4) * 128 + wv * 16 + l15) * 8];
  for (int tile = blockIdx.x; tile < tiles; tile += gridDim.x){
    const int rw = tile * 32;
    bf16x8 ar[KS][2];
    #pragma unroll
    for (int ks = 0; ks < KS1; ++ks)
      #pragma unroll
      for (int rf = 0; rf < 2; ++rf)
        ar[ks][rf] = *(const bf16x8*)&A1[(size_t)(rw + rf * 16 + l15) * (KS1 * 32) + ks * 32 + l4 * 8];
    #pragma unroll
    for (int ks = 0; ks < KS2; ++ks)
      #pragma unroll
      for (int rf = 0; rf < 2; ++rf)
        ar[KS1 + ks][rf] = *(const bf16x8*)&A2[(size_t)(rw + rf * 16 + l15) * (KS2 * 32) + ks * 32 + l4 * 8];
    f32x4 acc0 = {0.f,0.f,0.f,0.f}, acc1 = {0.f,0.f,0.f,0.f};
    #pragma unroll
    for (int ks = 0; ks < KS; ++ks){
      acc0 = MFMA(ar[ks][0], Wr[ks], acc0, 0, 0, 0);
      acc1 = MFMA(ar[ks][1], Wr[ks], acc1, 0, 0, 0);
    }
    const int col = wv * 16 + l15;
    const float bv = bias ? bias[col] : 0.f;
    #pragma unroll
    for (int rf = 0; rf < 2; ++rf){
      const f32x4 ac = rf ? acc1 : acc0;
      #pragma unroll
      for (int i = 0; i < 4; ++i){
        const size_t o = (size_t)(rw + rf * 16 + l4 * 4 + i) * 128 + col;
        float v = ac[i] + bv;
        if (EPI == EPI_RELU)         v = fmaxf(v, 0.f);
        else if (EPI == EPI_SIGMOID) v = sigmoidf_(v);
        if (OB16) ((unsigned short*)outv)[o] = f2bf(v);
        else      ((float*)outv)[o] = v;
      }
    }
  }
}

// Fused z_d + z_l: blocks [0,tiles) -> side a (f32 out), [tiles,2*tiles) -> b (bf16).
__global__ __launch_bounds__(512) void gemm1_dual_kernel(
    int tiles,
    const unsigned short* __restrict__ A1a, const unsigned short* __restrict__ A2a,
    const unsigned short* __restrict__ Wta, const float* __restrict__ ba,
    float* __restrict__ outa,
    const unsigned short* __restrict__ A1b, const unsigned short* __restrict__ A2b,
    const unsigned short* __restrict__ Wtb, const float* __restrict__ bb,
    unsigned short* __restrict__ outb)
{
  const int t = threadIdx.x, wv = t >> 6, lane = t & 63;
  const int l15 = lane & 15, l4 = lane >> 4;
  const bool sb = ((int)blockIdx.x >= tiles);
  const int tile = (int)blockIdx.x - (sb ? tiles : 0);
  const unsigned short* A1 = sb ? A1b : A1a;
  const unsigned short* A2 = sb ? A2b : A2a;
  const unsigned short* Wt = sb ? Wtb : Wta;
  const float* bias = sb ? bb : ba;
  bf16x8 Wr[12];
  #pragma unroll
  for (int ks = 0; ks < 12; ++ks)
    Wr[ks] = *(const bf16x8*)&Wt[((size_t)(ks * 4 + l4) * 128 + wv * 16 + l15) * 8];
  const int rw = tile * 32;
  bf16x8 ar[12][2];
  #pragma unroll
  for (int ks = 0; ks < 4; ++ks)
    #pragma unroll
    for (int rf = 0; rf < 2; ++rf)
      ar[ks][rf] = *(const bf16x8*)&A1[(size_t)(rw + rf * 16 + l15) * 128 + ks * 32 + l4 * 8];
  #pragma unroll
  for (int ks = 0; ks < 8; ++ks)
    #pragma unroll
    for (int rf = 0; rf < 2; ++rf)
      ar[4 + ks][rf] = *(const bf16x8*)&A2[(size_t)(rw + rf * 16 + l15) * 256 + ks * 32 + l4 * 8];
  f32x4 acc0 = {0.f,0.f,0.f,0.f}, acc1 = {0.f,0.f,0.f,0.f};
  #pragma unroll
  for (int ks = 0; ks < 12; ++ks){
    acc0 = MFMA(ar[ks][0], Wr[ks], acc0, 0, 0, 0);
    acc1 = MFMA(ar[ks][1], Wr[ks], acc1, 0, 0, 0);
  }
  const int col = wv * 16 + l15;
  const float bv = bias[col];
  #pragma unroll
  for (int rf = 0; rf < 2; ++rf){
    const f32x4 ac = rf ? acc1 : acc0;
    #pragma unroll
    for (int i = 0; i < 4; ++i){
      const size_t o = (size_t)(rw + rf * 16 + l4 * 4 + i) * 128 + col;
      const float v = fmaxf(ac[i] + bv, 0.f);
      if (sb) outb[o] = f2bf(v);
      else    outa[o] = v;
    }
  }
}

// Fused 4-way attention projection: blocks [0,tiles) -> topology head
// (ht16 @ a_dT|a_dG), [tiles,2*tiles) -> label head (me16 @ a_lT|a_lG).
__global__ __launch_bounds__(512) void gemm_proj4_kernel(
    int tiles,
    const unsigned short* __restrict__ Ad, const unsigned short* __restrict__ Al,
    const unsigned short* __restrict__ WdT, const unsigned short* __restrict__ WdG,
    const unsigned short* __restrict__ WlT, const unsigned short* __restrict__ WlG,
    float* __restrict__ oTd, float* __restrict__ oGd,
    float* __restrict__ oTl, float* __restrict__ oGl)
{
  const int t = threadIdx.x, wv = t >> 6, lane = t & 63;
  const int l15 = lane & 15, l4 = lane >> 4;
  const bool lab = ((int)blockIdx.x >= tiles);
  const int tile = (int)blockIdx.x - (lab ? tiles : 0);
  const unsigned short* A1  = lab ? Al  : Ad;
  const unsigned short* W1t = lab ? WlT : WdT;
  const unsigned short* W2t = lab ? WlG : WdG;
  float* out1 = lab ? oTl : oTd;
  float* out2 = lab ? oGl : oGd;
  bf16x8 W1r[4], W2r[4];
  #pragma unroll
  for (int ks = 0; ks < 4; ++ks){
    const size_t fo = ((size_t)(ks * 4 + l4) * 128 + wv * 16 + l15) * 8;
    W1r[ks] = *(const bf16x8*)&W1t[fo];
    W2r[ks] = *(const bf16x8*)&W2t[fo];
  }
  const int rw = tile * 32;
  bf16x8 a[4][2];
  #pragma unroll
  for (int ks = 0; ks < 4; ++ks)
    #pragma unroll
    for (int rf = 0; rf < 2; ++rf)
      a[ks][rf] = *(const bf16x8*)&A1[(size_t)(rw + rf * 16 + l15) * 128 + ks * 32 + l4 * 8];
  f32x4 p10 = {0.f,0.f,0.f,0.f}, p11 = {0.f,0.f,0.f,0.f};
  f32x4 p20 = {0.f,0.f,0.f,0.f}, p21 = {0.f,0.f,0.f,0.f};
  #pragma unroll
  for (int ks = 0; ks < 4; ++ks){
    p10 = MFMA(a[ks][0], W1r[ks], p10, 0, 0, 0);
    p20 = MFMA(a[ks][0], W2r[ks], p20, 0, 0, 0);
    p11 = MFMA(a[ks][1], W1r[ks], p11, 0, 0, 0);
    p21 = MFMA(a[ks][1], W2r[ks], p21, 0, 0, 0);
  }
  const int col = wv * 16 + l15;
  #pragma unroll
  for (int rf = 0; rf < 2; ++rf){
    const f32x4 c1 = rf ? p11 : p10;
    const f32x4 c2 = rf ? p21 : p20;
    #pragma unroll
    for (int i = 0; i < 4; ++i){
      const size_t o = (size_t)(rw + rf * 16 + l4 * 4 + i) * 128 + col;
      out1[o] = c1[i];
      out2[o] = c2[i];
    }
  }
}

// ---------------- CSR build (by lg_dst) ----------------

__global__ __launch_bounds__(256) void csr_count_kernel(
    const int* __restrict__ lg_dst, int ELG,
    int* __restrict__ cnt, int* __restrict__ ticket)
{
  const int e = blockIdx.x * 256 + threadIdx.x;
  if (e < ELG) ticket[e] = atomicAdd(&cnt[lg_dst[e]], 1);
}

#define SCAN_CHUNK 1024

__global__ __launch_bounds__(256) void scan_totals_kernel(
    const int* __restrict__ cnt, int n, int* __restrict__ bsum)
{
  __shared__ int red[256];
  const int base = blockIdx.x * SCAN_CHUNK;
  const int t = threadIdx.x;
  int s = 0;
  #pragma unroll
  for (int k = 0; k < 4; ++k){
    const int idx = base + t + k * 256;
    if (idx < n) s += cnt[idx];
  }
  red[t] = s; __syncthreads();
  for (int g = 128; g; g >>= 1){
    if (t < g) red[t] += red[t + g];
    __syncthreads();
  }
  if (t == 0) bsum[blockIdx.x] = red[0];
}

__global__ void scan_serial_kernel(int* bsum, int nb, int* offsets, int n)
{
  if (threadIdx.x == 0 && blockIdx.x == 0){
    int acc = 0;
    for (int i = 0; i < nb; ++i){ const int v = bsum[i]; bsum[i] = acc; acc += v; }
    offsets[n] = acc;
  }
}

__global__ __launch_bounds__(256) void scan_write_kernel(
    const int* __restrict__ cnt, int n,
    const int* __restrict__ bsum, int* __restrict__ offsets)
{
  __shared__ int wsum[4];
  const int base = blockIdx.x * SCAN_CHUNK;
  const int t = threadIdx.x;
  int v[4]; int lsum = 0;
  #pragma unroll
  for (int k = 0; k < 4; ++k){
    const int idx = base + t * 4 + k;
    v[k] = (idx < n) ? cnt[idx] : 0;
    lsum += v[k];
  }
  const int lane = t & 63, wv = t >> 6;
  int x = lsum;
  #pragma unroll
  for (int off = 1; off < 64; off <<= 1){
    const int y = __shfl_up(x, off, 64);
    if (lane >= off) x += y;
  }
  if (lane == 63) wsum[wv] = x;
  __syncthreads();
  int woff = 0;
  for (int i = 0; i < wv; ++i) woff += wsum[i];
  int run = x - lsum + woff + bsum[blockIdx.x];
  #pragma unroll
  for (int k = 0; k < 4; ++k){
    const int idx = base + t * 4 + k;
    if (idx < n) offsets[idx] = run;
    run += v[k];
  }
}

__global__ __launch_bounds__(256) void csr_fill_kernel(
    const int* __restrict__ lg_src, const int* __restrict__ lg_dst,
    const int* __restrict__ ticket, int ELG,
    const int* __restrict__ offsets, int* __restrict__ csr_src)
{
  const int e = blockIdx.x * 256 + threadIdx.x;
  if (e >= ELG) return;
  csr_src[offsets[lg_dst[e]] + ticket[e]] = lg_src[e];
}

// ---------------- CSR gathers (bf16 rows, f32 accumulate) ----------------

// compacted: s/srh at S1 rows only; sources via rank2 into compacted msg/R.
__global__ __launch_bounds__(256) void gather2_bf_kernel(
    const int* __restrict__ offsets, const int* __restrict__ csr_src,
    const int* __restrict__ cnt1p, const int* __restrict__ S1list,
    const int* __restrict__ rank2,
    const unsigned short* __restrict__ msg16c, const unsigned short* __restrict__ R16c,
    unsigned short* __restrict__ s16c, unsigned short* __restrict__ srh16c)
{
  const int total = (*cnt1p) * 16;
  for (int g = blockIdx.x * 256 + threadIdx.x; g < total; g += gridDim.x * 256){
    const int i = g >> 4, q = g & 15;
    const int v = S1list[i];
    const int beg = offsets[v], end = offsets[v + 1];
    float as[8] = {}, ar[8] = {};
    for (int j = beg; j < end; ++j){
      const int sc = rank2[csr_src[j]];
      acc8(as, *(const uint4*)&msg16c[(size_t)sc * 128 + q * 8]);
      acc8(ar, *(const uint4*)&R16c[(size_t)sc * 128 + q * 8]);
    }
    *(uint4*)&s16c[(size_t)i * 128 + q * 8] = pack8(as);
    *(uint4*)&srh16c[(size_t)i * 128 + q * 8] = pack8(ar);
  }
}

// eids gather: sum_h[eids] via CSR walk over compacted mn16c (rank1).
__global__ __launch_bounds__(256) void gather3_kernel(
    const int* __restrict__ eids, int B,
    const float* __restrict__ f_srcf, const unsigned short* __restrict__ mn16c,
    const int* __restrict__ rank1,
    const int* __restrict__ offsets, const int* __restrict__ csr_src,
    unsigned short* __restrict__ fs_e, unsigned short* __restrict__ sh_e,
    unsigned short* __restrict__ m_e)
{
  const int g = blockIdx.x * 256 + threadIdx.x;
  const int bI = g >> 4, q = g & 15;
  if (bI >= B) return;
  const int e = eids[bI];
  *(uint4*)&fs_e[(size_t)bI * 128 + q * 8] = cvt8(f_srcf + (size_t)e * 128 + q * 8);
  *(uint4*)&m_e [(size_t)bI * 128 + q * 8] =
      *(const uint4*)&mn16c[(size_t)rank1[e] * 128 + q * 8];
  const int beg = offsets[e], end = offsets[e + 1];
  float a[8] = {};
  for (int j = beg; j < end; ++j){
    const int sc = rank1[csr_src[j]];
    acc8(a, *(const uint4*)&mn16c[(size_t)sc * 128 + q * 8]);
  }
  *(uint4*)&sh_e[(size_t)bI * 128 + q * 8] = pack8(a);
}

// R30: templated per-graph attention (N = tile rows, compile-time).
// One graph/block, 64 threads; x staged once via LDS (R29), full unroll.
template<int N>
__global__ __launch_bounds__(64) void attn2t_kernel(
    const float* __restrict__ x,
    const float* __restrict__ ha_d, const float* __restrict__ ha_l,
    unsigned short* __restrict__ out_d, unsigned short* __restrict__ out_l,
    int col_off)
{
  const int b = blockIdx.x;
  const int l = threadIdx.x;
  __shared__ float xs[N][130];
  __shared__ float hd[128], hl[128];
  __shared__ float pd[64], pl[64];
  hd[l]      = ha_d[(size_t)b * 128 + l];
  hd[l + 64] = ha_d[(size_t)b * 128 + 64 + l];
  hl[l]      = ha_l[(size_t)b * 128 + l];
  hl[l + 64] = ha_l[(size_t)b * 128 + 64 + l];
  const float* xb = x + (size_t)b * N * 128;
  #pragma unroll
  for (int i = 0; i < N; ++i){
    const float2 xv = *(const float2*)(xb + i * 128 + 2 * l);
    xs[i][2 * l]     = xv.x;
    xs[i][2 * l + 1] = xv.y;
  }
  __syncthreads();
  float ed = -1e30f, el = -1e30f;
  if (l < N){
    const float* xr = xs[l];
    float sd = 0.f, sl = 0.f;
    #pragma unroll
    for (int k = 0; k < 32; ++k){
      const float2 xa = *(const float2*)&xr[k * 4];
      const float2 xbv = *(const float2*)&xr[k * 4 + 2];
      sd += xa.x * hd[k*4] + xa.y * hd[k*4+1] + xbv.x * hd[k*4+2] + xbv.y * hd[k*4+3];
      sl += xa.x * hl[k*4] + xa.y * hl[k*4+1] + xbv.x * hl[k*4+2] + xbv.y * hl[k*4+3];
    }
    ed = sd; el = sl;
  }
  const float md = wave_max64(ed), ml = wave_max64(el);
  const float exd = (l < N) ? __expf(ed - md) : 0.f;
  const float exl = (l < N) ? __expf(el - ml) : 0.f;
  const float zd = wave_sum64(exd), zl = wave_sum64(exl);
  pd[l] = exd / zd;
  pl[l] = exl / zl;
  __syncthreads();
  float od0 = 0.f, od1 = 0.f, ol0 = 0.f, ol1 = 0.f;
  #pragma unroll
  for (int i = 0; i < N; ++i){
    const float x0 = xs[i][2 * l], x1 = xs[i][2 * l + 1];
    const float wd = pd[i], wl = pl[i];
    od0 += wd * x0; od1 += wd * x1;
    ol0 += wl * x0; ol1 += wl * x1;
  }
  const size_t o = (size_t)b * 256 + col_off;
  *(unsigned*)&out_d[o + 2 * l] = pk2(f2bf(od0), f2bf(od1));
  *(unsigned*)&out_l[o + 2 * l] = pk2(f2bf(ol0), f2bf(ol1));
}

// generic fallback (runtime n <= 64), R29 structure
__global__ __launch_bounds__(64) void attn2_kernel(
    const float* __restrict__ xT, int nTn,
    const float* __restrict__ xG, int nGn,
    const float* __restrict__ haTd, const float* __restrict__ haGd,
    const float* __restrict__ haTl, const float* __restrict__ haGl,
    unsigned short* __restrict__ out_d, unsigned short* __restrict__ out_l, int B)
{
  int b = blockIdx.x;
  const bool isG = (b >= B);
  if (isG) b -= B;
  const float* x  = isG ? xG : xT;
  const int n     = isG ? nGn : nTn;
  const float* ha_d = isG ? haGd : haTd;
  const float* ha_l = isG ? haGl : haTl;
  const int col_off = isG ? 128 : 0;
  const int l = threadIdx.x;
  __shared__ float xs[64][130];
  __shared__ float hd[128], hl[128];
  __shared__ float pd[64], pl[64];
  hd[l]      = ha_d[(size_t)b * 128 + l];
  hd[l + 64] = ha_d[(size_t)b * 128 + 64 + l];
  hl[l]      = ha_l[(size_t)b * 128 + l];
  hl[l + 64] = ha_l[(size_t)b * 128 + 64 + l];
  const float* xb = x + (size_t)b * n * 128;
  #pragma unroll 8
  for (int i = 0; i < n; ++i){
    const float2 xv = *(const float2*)(xb + i * 128 + 2 * l);
    xs[i][2 * l]     = xv.x;
    xs[i][2 * l + 1] = xv.y;
  }
  __syncthreads();
  float ed = -1e30f, el = -1e30f;
  if (l < n){
    const float* xr = xs[l];
    float sd = 0.f, sl = 0.f;
    #pragma unroll 8
    for (int k = 0; k < 32; ++k){
      const float2 xa = *(const float2*)&xr[k * 4];
      const float2 xbv = *(const float2*)&xr[k * 4 + 2];
      sd += xa.x * hd[k*4] + xa.y * hd[k*4+1] + xbv.x * hd[k*4+2] + xbv.y * hd[k*4+3];
      sl += xa.x * hl[k*4] + xa.y * hl[k*4+1] + xbv.x * hl[k*4+2] + xbv.y * hl[k*4+3];
    }
    ed = sd; el = sl;
  }
  const float md = wave_max64(ed), ml = wave_max64(el);
  const float exd = (l < n) ? __expf(ed - md) : 0.f;
  const float exl = (l < n) ? __expf(el - ml) : 0.f;
  const float zd = wave_sum64(exd), zl = wave_sum64(exl);
  pd[l] = exd / zd;
  pl[l] = exl / zl;
  __syncthreads();
  float od0 = 0.f, od1 = 0.f, ol0 = 0.f, ol1 = 0.f;
  #pragma unroll 8
  for (int i = 0; i < n; ++i){
    const float x0 = xs[i][2 * l], x1 = xs[i][2 * l + 1];
    const float wd = pd[i], wl = pl[i];
    od0 += wd * x0; od1 += wd * x1;
    ol0 += wl * x0; ol1 += wl * x1;
  }
  const size_t o = (size_t)b * 256 + col_off;
  *(unsigned*)&out_d[o + 2 * l] = pk2(f2bf(od0), f2bf(od1));
  *(unsigned*)&out_l[o + 2 * l] = pk2(f2bf(ol0), f2bf(ol1));
}

__global__ __launch_bounds__(256) void ce_topo_kernel(
    const float* __restrict__ z_d, const float* __restrict__ u_d,
    const float* __restrict__ b_d3, const float* __restrict__ expand,
    float* __restrict__ out, int B)
{
  const int r = blockIdx.x * 4 + (threadIdx.x >> 6);
  const int l = threadIdx.x & 63;
  if (r >= B) return;
  const float* row = z_d + (size_t)r * 128;
  float s = row[l] * u_d[l] + row[l + 64] * u_d[l + 64];
  s = wave_sum64(s);
  if (l == 0){
    const float p = s + b_d3[0];
    const float t = expand[r];
    const float loss = -(t * logsigf_(p) + (1.f - t) * logsigf_(1.f - p));
    atomicAdd(out, loss / (float)B);
  }
}

// ---------------- label CE via MFMA: 32 rows/block, all V cols ----------------
__global__ __launch_bounds__(512) void ce_label_mfma_kernel(
    const unsigned short* __restrict__ zl16,
    const unsigned short* __restrict__ ul,    // granule layout k8*V + col
    const float* __restrict__ b_l2, const int* __restrict__ wid,
    float* __restrict__ out, int B, int V)
{
  const int NF = V >> 4;
  const int t = threadIdx.x, wv = t >> 6, lane = t & 63;
  const int l15 = lane & 15, l4 = lane >> 4;
  const int rw = blockIdx.x * 32;
  __shared__ float redm[32][8];
  __shared__ float reds[32][8];
  __shared__ float rowm[32];
  __shared__ float tgt[32];

  bf16x8 a[4][2];
  #pragma unroll
  for (int ks = 0; ks < 4; ++ks)
    #pragma unroll
    for (int rf = 0; rf < 2; ++rf)
      a[ks][rf] = *(const bf16x8*)&zl16[(size_t)(rw + rf * 16 + l15) * 128 + ks * 32 + l4 * 8];

  f32x4 acc[7][2];
  #pragma unroll
  for (int j = 0; j < 7; ++j){
    acc[j][0] = (f32x4){0.f,0.f,0.f,0.f};
    acc[j][1] = (f32x4){0.f,0.f,0.f,0.f};
  }
  #pragma unroll
  for (int j = 0; j < 7; ++j){
    const int cf = wv + 8 * j;
    if (cf < NF){
      #pragma unroll
      for (int ks = 0; ks < 4; ++ks){
        const bf16x8 bf = *(const bf16x8*)&ul[((size_t)(ks * 4 + l4) * V + cf * 16 + l15) * 8];
        acc[j][0] = MFMA(a[ks][0], bf, acc[j][0], 0, 0, 0);
        acc[j][1] = MFMA(a[ks][1], bf, acc[j][1], 0, 0, 0);
      }
    }
  }
  float mloc[8];
  #pragma unroll
  for (int k = 0; k < 8; ++k) mloc[k] = -1e30f;
  #pragma unroll
  for (int j = 0; j < 7; ++j){
    const int cf = wv + 8 * j;
    if (cf < NF){
      const float bv = b_l2[cf * 16 + l15];
      #pragma unroll
      for (int rf = 0; rf < 2; ++rf)
        #pragma unroll
        for (int i = 0; i < 4; ++i){
          const float v = acc[j][rf][i] + bv;
          acc[j][rf][i] = v;
          mloc[rf * 4 + i] = fmaxf(mloc[rf * 4 + i], v);
        }
    }
  }
  #pragma unroll
  for (int m = 1; m < 16; m <<= 1)
    #pragma unroll
    for (int k = 0; k < 8; ++k)
      mloc[k] = fmaxf(mloc[k], __shfl_xor(mloc[k], m, 64));
  if (l15 == 0){
    #pragma unroll
    for (int rf = 0; rf < 2; ++rf)
      #pragma unroll
      for (int i = 0; i < 4; ++i)
        redm[rf * 16 + l4 * 4 + i][wv] = mloc[rf * 4 + i];
  }
  __syncthreads();
  if (t < 32){
    float m = redm[t][0];
    #pragma unroll
    for (int k = 1; k < 8; ++k) m = fmaxf(m, redm[t][k]);
    rowm[t] = m;
  }
  __syncthreads();
  float sloc[8];
  #pragma unroll
  for (int k = 0; k < 8; ++k) sloc[k] = 0.f;
  #pragma unroll
  for (int j = 0; j < 7; ++j){
    const int cf = wv + 8 * j;
    if (cf < NF){
      #pragma unroll
      for (int rf = 0; rf < 2; ++rf)
        #pragma unroll
        for (int i = 0; i < 4; ++i){
          const int lr = rf * 16 + l4 * 4 + i;
          const float v = acc[j][rf][i];
          sloc[rf * 4 + i] += __expf(v - rowm[lr]);
          if (cf * 16 + l15 == wid[rw + lr]) tgt[lr] = v;
        }
    }
  }
  #pragma unroll
  for (int m = 1; m < 16; m <<= 1)
    #pragma unroll
    for (int k = 0; k < 8; ++k)
      sloc[k] += __shfl_xor(sloc[k], m, 64);
  if (l15 == 0){
    #pragma unroll
    for (int rf = 0; rf < 2; ++rf)
      #pragma unroll
      for (int i = 0; i < 4; ++i)
        reds[rf * 16 + l4 * 4 + i][wv] = sloc[rf * 4 + i];
  }
  __syncthreads();
  if (t < 32){
    float s = 0.f;
    #pragma unroll
    for (int k = 0; k < 8; ++k) s += reds[t][k];
    const float lp = tgt[t] - rowm[t] - __logf(s);
    atomicAdd(out + 1, -lp / (float)B);
  }
}

extern "C" void kernel_launch(void* const* d_in, const int* in_sizes, int n_in,
                              void* d_out, int out_size, void* d_ws, size_t ws_size,
                              hipStream_t stream)
{
  const float* msg    = (const float*)d_in[0];
  const float* f_src  = (const float*)d_in[1];
  const float* f_dst  = (const float*)d_in[2];
  const float* x_T    = (const float*)d_in[3];
  const float* x_G    = (const float*)d_in[4];
  const float* expand = (const float*)d_in[5];
  const float* wz = (const float*)d_in[6];
  const float* uz = (const float*)d_in[7];
  const float* bz = (const float*)d_in[8];
  const float* wr = (const float*)d_in[9];
  const float* ur = (const float*)d_in[10];
  const float* br = (const float*)d_in[11];
  const float* w  = (const float*)d_in[12];
  const float* u  = (const float*)d_in[13];
  const float* b  = (const float*)d_in[14];
  const float* w_d1 = (const float*)d_in[15];
  const float* w_d2 = (const float*)d_in[16];
  const float* b_d1 = (const float*)d_in[17];
  const float* a_dT = (const float*)d_in[18];
  const float* a_dG = (const float*)d_in[19];
  const float* w_d3 = (const float*)d_in[20];
  const float* w_d4 = (const float*)d_in[21];
  const float* b_d2 = (const float*)d_in[22];
  const float* u_d  = (const float*)d_in[23];
  const float* b_d3 = (const float*)d_in[24];
  const float* w_l1 = (const float*)d_in[25];
  const float* w_l2 = (const float*)d_in[26];
  const float* b_l1 = (const float*)d_in[27];
  const float* a_lT = (const float*)d_in[28];
  const float* a_lG = (const float*)d_in[29];
  const float* u_l  = (const float*)d_in[30];
  const float* b_l2 = (const float*)d_in[31];
  const int* lg_src = (const int*)d_in[32];
  const int* lg_dst = (const int*)d_in[33];
  const int* eids   = (const int*)d_in[34];
  const int* wid    = (const int*)d_in[35];

  const int d = 128;
  const int E   = in_sizes[0] / d;
  const int ELG = in_sizes[32];
  const int B   = in_sizes[34];
  const int V   = in_sizes[31];
  const int nT  = (in_sizes[3] / d) / B;
  const int nG  = (in_sizes[4] / d) / B;

  const size_t EH = (size_t)E * d * sizeof(unsigned short);
  const size_t BH = (size_t)B * d * sizeof(unsigned short);
  const size_t BF = (size_t)B * d * sizeof(float);
  char* p = (char*)d_ws;
  unsigned short* bufA = (unsigned short*)p; p += EH;  // R16c -> mn16c
  unsigned short* bufB = (unsigned short*)p; p += EH;  // s16c
  unsigned short* srh16 = (unsigned short*)p; p += EH; // srh16c
  unsigned short* msg16 = (unsigned short*)p; p += EH; // msg16c
  unsigned short* R16 = bufA, *mn16 = bufA;
  unsigned short* s16 = bufB;
  unsigned short* fse16 = (unsigned short*)p; p += BH;
  unsigned short* she16 = (unsigned short*)p; p += BH;
  unsigned short* me16  = (unsigned short*)p; p += BH;
  unsigned short* ht16  = (unsigned short*)p; p += BH;
  unsigned short* cd16  = (unsigned short*)p; p += 2 * BH;
  unsigned short* cl16  = (unsigned short*)p; p += 2 * BH;
  unsigned short* zl16  = (unsigned short*)p; p += BH;
  float* haTd = (float*)p; p += BF;
  float* haGd = (float*)p; p += BF;
  float* haTl = (float*)p; p += BF;
  float* haGl = (float*)p; p += BF;
  float* z_d  = (float*)p; p += BF;
  // CSR scratch
  int* cnt     = (int*)p; p += (size_t)E * sizeof(int);
  int* offsets = (int*)p; p += (size_t)(E + 1) * sizeof(int);
  int* ticket  = (int*)p; p += (size_t)ELG * sizeof(int);
  int* csr_src = (int*)p; p += (size_t)ELG * sizeof(int);
  int* bsum    = (int*)p; p += (size_t)((E + SCAN_CHUNK - 1) / SCAN_CHUNK + 1) * sizeof(int);
  // active-set scratch (R26)
  int* flag1  = (int*)p; p += (size_t)E * sizeof(int);
  int* flag2  = (int*)p; p += (size_t)E * sizeof(int);
  int* cnts   = (int*)p; p += 2 * sizeof(int);
  int* S1list = (int*)p; p += (size_t)(E + 128) * sizeof(int);
  int* S2list = (int*)p; p += (size_t)(E + 128) * sizeof(int);
  int* rank1  = (int*)p; p += (size_t)E * sizeof(int);
  int* rank2  = (int*)p; p += (size_t)E * sizeof(int);
  // bf16 fragment-layout weights
  p = (char*)(((size_t)p + 255) & ~(size_t)255);
  unsigned short* wt = (unsigned short*)p; p += 294912 * sizeof(unsigned short);
  p = (char*)(((size_t)p + 255) & ~(size_t)255);
  unsigned short* wt_ul = (unsigned short*)p; p += (size_t)128 * V * sizeof(unsigned short);

  hipMemsetAsync(cnt, 0, (size_t)E * sizeof(int), stream);
  hipMemsetAsync(flag1, 0, 2 * (size_t)E * sizeof(int), stream);  // flag1+flag2
  hipMemsetAsync(cnts, 0, 2 * sizeof(int), stream);
  hipMemsetAsync(d_out, 0, 2 * sizeof(float), stream);

  const int nb = (E + SCAN_CHUNK - 1) / SCAN_CHUNK;
  const int tilesB = B / 32;
  const int ublocks = (16 * V + 255) / 256;
  const int wblocks = (ublocks > 24) ? ublocks : 24;

  // weights -> bf16 fragment layout (y<10: panels; y==10: u_l)
  wprep_kernel<<<dim3(wblocks, 11), 256, 0, stream>>>(
      wr, ur, wz, uz, w, u, w_d1, w_d2, a_dT, a_dG, a_lT, a_lG,
      w_d3, w_d4, w_l1, w_l2, wt, u_l, wt_ul, V);

  // ---- CSR build (by lg_dst) ----
  csr_count_kernel<<<(ELG + 255) / 256, 256, 0, stream>>>(lg_dst, ELG, cnt, ticket);
  scan_totals_kernel<<<nb, 256, 0, stream>>>(cnt, E, bsum);
  scan_serial_kernel<<<1, 64, 0, stream>>>(bsum, nb, offsets, E);
  scan_write_kernel<<<nb, 256, 0, stream>>>(cnt, E, bsum, offsets);
  csr_fill_kernel<<<(ELG + 255) / 256, 256, 0, stream>>>(lg_src, lg_dst, ticket, ELG, offsets, csr_src);

  // ---- active sets: S1 = eids + their sources; S2 = sources of S1 ----
  mark1_kernel<<<(B + 255) / 256, 256, 0, stream>>>(eids, B, offsets, csr_src, flag1);
  compact_kernel<<<(E + 255) / 256, 256, 0, stream>>>(flag1, E, S1list, rank1, cnts + 0);
  mark2_kernel<<<512, 256, 0, stream>>>(cnts + 0, S1list, offsets, csr_src, flag2);
  compact_kernel<<<(E + 255) / 256, 256, 0, stream>>>(flag2, E, S2list, rank2, cnts + 1);
  pad_kernel<<<1, 64, 0, stream>>>(cnts + 0, S1list, cnts + 1, S2list);

  // R = sigmoid(f_dst@wr + msg@ur + br) * msg at S2 rows -> R16c, msg16c
  gemm_r_kernel<<<512, 512, 0, stream>>>(
      cnts + 1, S2list, f_dst, msg, wt + 0, br, R16, msg16);
  // s/srh segsums at S1 rows (compacted, sources via rank2)
  gather2_bf_kernel<<<2048, 256, 0, stream>>>(
      offsets, csr_src, cnts + 0, S1list, rank2, msg16, R16, s16, srh16);
  // msg_new at S1 rows -> mn16c
  gemm_zh_kernel<<<256, 512, 0, stream>>>(
      cnts + 0, S1list, f_src, s16, srh16, wt + 32768, wt + 65536, bz, b, mn16);
  // eids gathers incl. sum_h[eids] via CSR walk over mn16c
  gather3_kernel<<<(B * 16 + 255) / 256, 256, 0, stream>>>(
      eids, B, f_src, mn16, rank1, offsets, csr_src, fse16, she16, me16);
  // h_t = relu(fs_e@w_d1 + sh_e@w_d2 + b_d1)   -> ht16
  gemm1_kernel<4, 4, EPI_RELU, true><<<tilesB, 512, 0, stream>>>(
      tilesB, fse16, she16, wt + 98304, b_d1, ht16);
  // all four attention projections in one full-CU launch
  gemm_proj4_kernel<<<2 * tilesB, 512, 0, stream>>>(
      tilesB, ht16, me16,
      wt + 131072, wt + 147456, wt + 163840, wt + 180224,
      haTd, haGd, haTl, haGl);
  // fused attention (R30): templated fast path when tile heights are 32/64
  if (nT == 32 && nG == 64){
    attn2t_kernel<32><<<B, 64, 0, stream>>>(x_T, haTd, haTl, cd16, cl16, 0);
    attn2t_kernel<64><<<B, 64, 0, stream>>>(x_G, haGd, haGl, cd16, cl16, 128);
  } else {
    attn2_kernel<<<2 * B, 64, 0, stream>>>(
        x_T, nT, x_G, nG, haTd, haGd, haTl, haGl, cd16, cl16, B);
  }
  // z_d (f32) + z_l (bf16) in one full-CU launch
  gemm1_dual_kernel<<<2 * tilesB, 512, 0, stream>>>(
      tilesB,
      ht16, cd16, wt + 196608, b_d2, z_d,
      me16, cl16, wt + 245760, b_l1, zl16);
  // losses
  ce_topo_kernel<<<(B + 3) / 4, 256, 0, stream>>>(z_d, u_d, b_d3, expand, (float*)d_out, B);
  ce_label_mfma_kernel<<<B / 32, 512, 0, stream>>>(zl16, wt_ul, b_l2, wid,
                                                   (float*)d_out, B, V);
}